// Round 8
// baseline (4937.531 us; speedup 1.0000x reference)
//
#include <hip/hip_runtime.h>
#include <hip/hip_cooperative_groups.h>

namespace cg = cooperative_groups;

#define BB   64
#define PP   196
#define ENCD 2048
#define DECD 512
#define VV   10000
#define TT   21
#define KIH  2560   // (EMB + ENC) rows of W_ih

typedef __attribute__((ext_vector_type(8))) short bf16x8;
typedef __attribute__((ext_vector_type(4))) float f32x4;

__device__ __forceinline__ float sigm(float x)   { return 1.f / (1.f + __expf(-x)); }
__device__ __forceinline__ float tanh_f(float x) { return 1.f - 2.f / (1.f + __expf(2.f * x)); }
__device__ __forceinline__ ushort f2bf(float x) {
    unsigned u = __float_as_uint(x);
    unsigned r = (u + 0x7FFFu + ((u >> 16) & 1u)) >> 16;
    return (ushort)r;
}
__device__ __forceinline__ float bf2f(ushort u) {
    return __uint_as_float(((unsigned)u) << 16);
}
union U8 { float4 f4; ushort u[8]; };

// ---------------- setup kernels ----------------

__global__ void k_cvt(const float* __restrict__ in, ushort* __restrict__ out, int n4) {
    int i = blockIdx.x * 256 + threadIdx.x;
    if (i >= n4) return;
    float4 v = ((const float4*)in)[i];
    ushort4 o; o.x = f2bf(v.x); o.y = f2bf(v.y); o.z = f2bf(v.z); o.w = f2bf(v.w);
    ((ushort4*)out)[i] = o;
}

__global__ void k_mean16(const ushort* __restrict__ encB, float* __restrict__ mean) {
    int idx = blockIdx.x * 256 + threadIdx.x;
    int b = idx >> 10, e2 = idx & 1023;
    const uint* p = (const uint*)encB + (size_t)b * PP * 1024 + e2;
    float s0 = 0.f, s1 = 0.f;
    #pragma unroll 7
    for (int i = 0; i < PP; ++i) {
        uint v = p[(size_t)i * 1024];
        s0 += __uint_as_float(v << 16);
        s1 += __uint_as_float(v & 0xffff0000u);
    }
    mean[b * 2048 + e2 * 2]     = s0 * (1.f / 196.f);
    mean[b * 2048 + e2 * 2 + 1] = s1 * (1.f / 196.f);
}

__global__ __launch_bounds__(256) void k_ipart(const float* __restrict__ mean,
        const float* __restrict__ Wh, const float* __restrict__ Wc,
        float* __restrict__ ipart) {
    __shared__ alignas(16) float As[32][68];
    __shared__ alignas(16) float Bs[32][68];
    const int n0 = blockIdx.x * 64;
    const int kc = blockIdx.y;
    const int mat = blockIdx.z;
    const float* Bp = mat ? Wc : Wh;
    const int tid = threadIdx.x, tx = tid & 15, ty = tid >> 4;
    float acc[4][4] = {};
    for (int k0 = 0; k0 < 512; k0 += 32) {
        #pragma unroll
        for (int p = 0; p < 2; ++p) {
            int c = p * 256 + tid;
            int m = c >> 3, k4 = (c & 7) * 4;
            float4 v = *(const float4*)(mean + m * 2048 + kc * 512 + k0 + k4);
            As[k4 + 0][m] = v.x; As[k4 + 1][m] = v.y; As[k4 + 2][m] = v.z; As[k4 + 3][m] = v.w;
            int kb = c >> 4, n4 = (c & 15) * 4;
            float4 w = *(const float4*)(Bp + (size_t)(kc * 512 + k0 + kb) * 512 + n0 + n4);
            *(float4*)&Bs[kb][n4] = w;
        }
        __syncthreads();
        #pragma unroll 8
        for (int k = 0; k < 32; ++k) {
            float4 a = *(const float4*)&As[k][ty * 4];
            float4 b = *(const float4*)&Bs[k][tx * 4];
            float av[4] = {a.x, a.y, a.z, a.w}, bv[4] = {b.x, b.y, b.z, b.w};
            #pragma unroll
            for (int i = 0; i < 4; ++i)
                #pragma unroll
                for (int j = 0; j < 4; ++j) acc[i][j] += av[i] * bv[j];
        }
        __syncthreads();
    }
    #pragma unroll
    for (int i = 0; i < 4; ++i) {
        int m = ty * 4 + i;
        #pragma unroll
        for (int j = 0; j < 4; ++j) {
            int n = n0 + tx * 4 + j;
            ipart[((size_t)(mat * 4 + kc) * BB + m) * 512 + n] = acc[i][j];
        }
    }
}

__global__ void k_ifin(const float* __restrict__ ipart,
                       const float* __restrict__ bh, const float* __restrict__ bc,
                       float* __restrict__ h, float* __restrict__ c, ushort* __restrict__ hB) {
    int idx = blockIdx.x * 256 + threadIdx.x;
    int mat = idx >> 15, rem = idx & 32767;
    int b = rem >> 9, d = rem & 511;
    float s = 0.f;
    #pragma unroll
    for (int kc = 0; kc < 4; ++kc) s += ipart[((size_t)(mat * 4 + kc) * BB + b) * 512 + d];
    if (mat) c[rem] = s + bc[d];
    else { float v = s + bh[d]; h[rem] = v; hB[rem] = f2bf(v); }
}

__global__ __launch_bounds__(256) void k_tcvt_all(
        const float* __restrict__ Wenc, const float* __restrict__ Wdec,
        const float* __restrict__ Wbeta, const float* __restrict__ Whh,
        const float* __restrict__ Wih, const float* __restrict__ Wfc,
        ushort* __restrict__ WencT, ushort* __restrict__ WdecT,
        ushort* __restrict__ WbetaT, ushort* __restrict__ WhhT,
        ushort* __restrict__ WihT, ushort* __restrict__ WfcT) {
    __shared__ float lds[64 * 65];
    int l = blockIdx.x;
    const float* in; ushort* out; int K, N, KT;
    if (l < 256)       { in = Wenc;  out = WencT;  K = 2048; N = 512;   KT = 32; }
    else if (l < 320)  { l -= 256;  in = Wdec;  out = WdecT;  K = 512;  N = 512;   KT = 8; }
    else if (l < 576)  { l -= 320;  in = Wbeta; out = WbetaT; K = 512;  N = 2048;  KT = 8; }
    else if (l < 832)  { l -= 576;  in = Whh;   out = WhhT;   K = 512;  N = 2048;  KT = 8; }
    else if (l < 2112) { l -= 832;  in = Wih;   out = WihT;   K = KIH;  N = 2048;  KT = 40; }
    else               { l -= 2112; in = Wfc;   out = WfcT;   K = 512;  N = 10000; KT = 8; }
    const int k0 = (l % KT) * 64, n0 = (l / KT) * 64;
    const int tid = threadIdx.x;
    for (int i = tid; i < 4096; i += 256) {
        int kk = i >> 6, nn = i & 63;
        float v = 0.f;
        if (n0 + nn < N) v = in[(size_t)(k0 + kk) * N + n0 + nn];
        lds[nn * 65 + kk] = v;
    }
    __syncthreads();
    for (int i = tid; i < 4096; i += 256) {
        int nn = i >> 6, kk = i & 63;
        out[(size_t)(n0 + nn) * K + k0 + kk] = f2bf(lds[nn * 65 + kk]);
    }
}

// att1T[b][col][p] bf16 = bf16(enc @ W_enc + b_enc) transposed per b. grid (2, 196)
__global__ __launch_bounds__(256) void k_att1T(const ushort* __restrict__ A,
        const ushort* __restrict__ Bt, const float* __restrict__ bias,
        ushort* __restrict__ att1T) {
    __shared__ alignas(16) ushort As[64 * 64];
    __shared__ alignas(16) ushort Bs[256 * 64];
    const int n0 = blockIdx.x * 256;
    const int m0 = blockIdx.y * 64;
    const int tid = threadIdx.x, wid = tid >> 6, lane = tid & 63;
    f32x4 acc[4][4] = {};
    for (int k0 = 0; k0 < 2048; k0 += 64) {
        #pragma unroll
        for (int p = 0; p < 2; ++p) {
            int c = p * 256 + tid;
            int r = c >> 3, cc = c & 7;
            float4 v = *(const float4*)(A + (size_t)(m0 + r) * 2048 + k0 + cc * 8);
            *(float4*)(As + r * 64 + ((cc ^ (r & 7)) * 8)) = v;
        }
        #pragma unroll
        for (int p = 0; p < 8; ++p) {
            int c = p * 256 + tid;
            int r = c >> 3, cc = c & 7;
            float4 v = *(const float4*)(Bt + (size_t)(n0 + r) * 2048 + k0 + cc * 8);
            *(float4*)(Bs + r * 64 + ((cc ^ (r & 7)) * 8)) = v;
        }
        __syncthreads();
        #pragma unroll
        for (int kk = 0; kk < 2; ++kk) {
            int ci = kk * 4 + (lane >> 4);
            bf16x8 afrag[4], bfrag[4];
            #pragma unroll
            for (int m = 0; m < 4; ++m) {
                int row = m * 16 + (lane & 15);
                afrag[m] = *(const bf16x8*)(As + row * 64 + ((ci ^ (row & 7)) * 8));
            }
            #pragma unroll
            for (int n = 0; n < 4; ++n) {
                int col = wid * 64 + n * 16 + (lane & 15);
                bfrag[n] = *(const bf16x8*)(Bs + col * 64 + ((ci ^ (col & 7)) * 8));
            }
            #pragma unroll
            for (int m = 0; m < 4; ++m)
                #pragma unroll
                for (int n = 0; n < 4; ++n)
                    acc[m][n] = __builtin_amdgcn_mfma_f32_16x16x32_bf16(afrag[m], bfrag[n], acc[m][n], 0, 0, 0);
        }
        __syncthreads();
    }
    #pragma unroll
    for (int m = 0; m < 4; ++m) {
        int rb = m0 + m * 16 + (lane >> 4) * 4;   // mult of 4; 196%4==0 so no b straddle
        int b = rb / 196;
        int p = rb - b * 196;
        #pragma unroll
        for (int n = 0; n < 4; ++n) {
            int col = n0 + wid * 64 + n * 16 + (lane & 15);
            float bv = bias[col];
            ushort4 o;
            o.x = f2bf(acc[m][n][0] + bv);
            o.y = f2bf(acc[m][n][1] + bv);
            o.z = f2bf(acc[m][n][2] + bv);
            o.w = f2bf(acc[m][n][3] + bv);
            *(ushort4*)(att1T + ((size_t)(b * 512 + col)) * 200 + p) = o;
        }
    }
}

// xpre[t][b][2048] = emb[caps[b,t]] @ W_ih[0:512]. grid (8, 21)
__global__ __launch_bounds__(256) void k_xpre(const float* __restrict__ emb,
        const int* __restrict__ caps, const ushort* __restrict__ WihT,
        float* __restrict__ xpre) {
    __shared__ alignas(16) ushort As[64 * 64];
    __shared__ alignas(16) ushort Bs[256 * 64];
    __shared__ int capsh[64];
    const int n0 = blockIdx.x * 256;
    const int t = blockIdx.y;
    const int tid = threadIdx.x, wid = tid >> 6, lane = tid & 63;
    if (tid < 64) capsh[tid] = caps[tid * 22 + t];
    __syncthreads();
    f32x4 acc[4][4] = {};
    for (int k0 = 0; k0 < 512; k0 += 64) {
        #pragma unroll
        for (int p = 0; p < 2; ++p) {
            int c = p * 256 + tid;
            int r = c >> 3, cc = c & 7;
            const float* er = emb + (size_t)capsh[r] * 512 + k0 + cc * 8;
            float4 v0 = *(const float4*)er;
            float4 v1 = *(const float4*)(er + 4);
            U8 pk;
            pk.u[0] = f2bf(v0.x); pk.u[1] = f2bf(v0.y); pk.u[2] = f2bf(v0.z); pk.u[3] = f2bf(v0.w);
            pk.u[4] = f2bf(v1.x); pk.u[5] = f2bf(v1.y); pk.u[6] = f2bf(v1.z); pk.u[7] = f2bf(v1.w);
            *(float4*)(As + r * 64 + ((cc ^ (r & 7)) * 8)) = pk.f4;
        }
        #pragma unroll
        for (int p = 0; p < 8; ++p) {
            int c = p * 256 + tid;
            int r = c >> 3, cc = c & 7;
            float4 v = *(const float4*)(WihT + (size_t)(n0 + r) * KIH + k0 + cc * 8);
            *(float4*)(Bs + r * 64 + ((cc ^ (r & 7)) * 8)) = v;
        }
        __syncthreads();
        #pragma unroll
        for (int kk = 0; kk < 2; ++kk) {
            int ci = kk * 4 + (lane >> 4);
            bf16x8 afrag[4], bfrag[4];
            #pragma unroll
            for (int m = 0; m < 4; ++m) {
                int row = m * 16 + (lane & 15);
                afrag[m] = *(const bf16x8*)(As + row * 64 + ((ci ^ (row & 7)) * 8));
            }
            #pragma unroll
            for (int n = 0; n < 4; ++n) {
                int col = wid * 64 + n * 16 + (lane & 15);
                bfrag[n] = *(const bf16x8*)(Bs + col * 64 + ((ci ^ (col & 7)) * 8));
            }
            #pragma unroll
            for (int m = 0; m < 4; ++m)
                #pragma unroll
                for (int n = 0; n < 4; ++n)
                    acc[m][n] = __builtin_amdgcn_mfma_f32_16x16x32_bf16(afrag[m], bfrag[n], acc[m][n], 0, 0, 0);
        }
        __syncthreads();
    }
    #pragma unroll
    for (int m = 0; m < 4; ++m) {
        int rb = m * 16 + (lane >> 4) * 4;
        #pragma unroll
        for (int n = 0; n < 4; ++n) {
            int col = n0 + wid * 64 + n * 16 + (lane & 15);
            #pragma unroll
            for (int r = 0; r < 4; ++r)
                xpre[((size_t)t * BB + rb + r) * 2048 + col] = acc[m][n][r];
        }
    }
}

__global__ void k_declen(const int* __restrict__ lens, float* __restrict__ out) {
    int b = threadIdx.x;
    if (b < BB) out[b] = (float)(lens[b] - 1);
}

// ---------------- step phases (shared by coop + fallback paths) ----------------

struct SArgs {
    ushort* hB; float* h; float* c;
    const ushort* WcatT; const float* bd; const float* bb;
    const ushort* WihT; const float* xpre; const ushort* att1T;
    const float* Wf; const ushort* encB;
    const float* bih; const float* bhh;
    const int* lens; const float* memB;
    float* att2; float* gate; float* hhp;
    uint* aweB; float* pawe;
    ushort* histB; float* alpha_out;
};

struct SMem {
    ushort As[64 * 64];
    ushort Bs[64 * 64];
    float a2s[512], wfs[512], reds[256], als[224];
    float hss[512], simss[128], pss[128];
};

// P1: att2|gate|hhp = hB @ WcatT (72 tiles of 64 cols, K=512)
__device__ __forceinline__ void phase1(const SArgs& a, int bid, int tid, SMem& sm) {
    const int lane = tid & 63, wid = tid >> 6;
    const int n0 = bid * 64;
    f32x4 acc[4] = {};
    for (int k0 = 0; k0 < 512; k0 += 64) {
        #pragma unroll
        for (int p = 0; p < 2; ++p) {
            int c8 = p * 256 + tid;
            int r = c8 >> 3, cc = c8 & 7;
            float4 v = *(const float4*)(a.hB + r * 512 + k0 + cc * 8);
            *(float4*)(sm.As + r * 64 + ((cc ^ (r & 7)) * 8)) = v;
            float4 w = *(const float4*)(a.WcatT + (size_t)(n0 + r) * 512 + k0 + cc * 8);
            *(float4*)(sm.Bs + r * 64 + ((cc ^ (r & 7)) * 8)) = w;
        }
        __syncthreads();
        #pragma unroll
        for (int kk = 0; kk < 2; ++kk) {
            int ci = kk * 4 + (lane >> 4);
            int colL = wid * 16 + (lane & 15);
            bf16x8 bfrag = *(const bf16x8*)(sm.Bs + colL * 64 + ((ci ^ (colL & 7)) * 8));
            #pragma unroll
            for (int m = 0; m < 4; ++m) {
                int row = m * 16 + (lane & 15);
                bf16x8 afrag = *(const bf16x8*)(sm.As + row * 64 + ((ci ^ (row & 7)) * 8));
                acc[m] = __builtin_amdgcn_mfma_f32_16x16x32_bf16(afrag, bfrag, acc[m], 0, 0, 0);
            }
        }
        __syncthreads();
    }
    int col = n0 + wid * 16 + (lane & 15);
    #pragma unroll
    for (int m = 0; m < 4; ++m) {
        int rb = m * 16 + (lane >> 4) * 4;
        #pragma unroll
        for (int r = 0; r < 4; ++r) {
            int row = rb + r;
            float v = acc[m][r];
            if (col < 512)       a.att2[row * 512 + col] = v + a.bd[col];
            else if (col < 2560) a.gate[row * 2048 + (col - 512)] = sigm(v + a.bb[col - 512]);
            else                 a.hhp[(size_t)row * 2048 + (col - 2560)] = v;
        }
    }
}

// P2: e-scores + softmax + awe; bid in [0,256): b=bid>>2, pc=bid&3
__device__ __forceinline__ void phase2(const SArgs& a, int t, int bid, int tid, SMem& sm) {
    const int b = bid >> 2, pc = bid & 3;
    for (int i = tid; i < 512; i += 256) { sm.a2s[i] = a.att2[b * 512 + i]; sm.wfs[i] = a.Wf[i]; }
    __syncthreads();
    float es = -3.4e38f;
    if (tid < PP) {
        const ushort* rp = a.att1T + (size_t)b * 512 * 200 + tid;
        float s = 0.f;
        #pragma unroll 4
        for (int k = 0; k < 512; ++k) {
            float v = bf2f(rp[(size_t)k * 200]) + sm.a2s[k];
            s += (v > 0.f ? v : 0.f) * sm.wfs[k];
        }
        es = s;
    }
    sm.reds[tid] = es; __syncthreads();
    for (int s = 128; s; s >>= 1) { if (tid < s) sm.reds[tid] = fmaxf(sm.reds[tid], sm.reds[tid + s]); __syncthreads(); }
    float mx = sm.reds[0]; __syncthreads();
    float ev = (tid < PP) ? __expf(es - mx) : 0.f;
    sm.reds[tid] = ev; __syncthreads();
    for (int s = 128; s; s >>= 1) { if (tid < s) sm.reds[tid] += sm.reds[tid + s]; __syncthreads(); }
    float inv = 1.f / sm.reds[0];
    if (tid < PP) {
        float al = ev * inv;
        sm.als[tid] = al;
        if (pc == 0) {
            bool m = t < (a.lens[b] - 1);
            a.alpha_out[((size_t)b * TT + t) * PP + tid] = m ? al : 0.f;
        }
    }
    __syncthreads();
    int pair = pc * 256 + tid;
    const uint* pp = (const uint*)a.encB + (size_t)b * PP * 1024 + pair;
    float s0 = 0.f, s1 = 0.f;
    #pragma unroll 4
    for (int i = 0; i < PP; ++i) {
        uint vv = pp[(size_t)i * 1024];
        float al = sm.als[i];
        s0 += al * __uint_as_float(vv << 16);
        s1 += al * __uint_as_float(vv & 0xffff0000u);
    }
    int e = pair * 2;
    float g0 = s0 * a.gate[b * 2048 + e];
    float g1 = s1 * a.gate[b * 2048 + e + 1];
    a.aweB[b * 1024 + pair] = (uint)f2bf(g0) | ((uint)f2bf(g1) << 16);
}

// P3: pawe[kc] = aweB slice @ W_ih slice; bid in [0,128)
__device__ __forceinline__ void phase3(const SArgs& a, int bid, int tid, SMem& sm) {
    const int lane = tid & 63, wid = tid >> 6;
    const int n0 = (bid & 31) * 64, kc = bid >> 5;
    const ushort* aweU = (const ushort*)a.aweB;
    f32x4 acc[4] = {};
    for (int k0 = 0; k0 < 512; k0 += 64) {
        #pragma unroll
        for (int p = 0; p < 2; ++p) {
            int c8 = p * 256 + tid;
            int r = c8 >> 3, cc = c8 & 7;
            float4 v = *(const float4*)(aweU + r * 2048 + kc * 512 + k0 + cc * 8);
            *(float4*)(sm.As + r * 64 + ((cc ^ (r & 7)) * 8)) = v;
            float4 w = *(const float4*)(a.WihT + (size_t)(n0 + r) * KIH + 512 + kc * 512 + k0 + cc * 8);
            *(float4*)(sm.Bs + r * 64 + ((cc ^ (r & 7)) * 8)) = w;
        }
        __syncthreads();
        #pragma unroll
        for (int kk = 0; kk < 2; ++kk) {
            int ci = kk * 4 + (lane >> 4);
            int colL = wid * 16 + (lane & 15);
            bf16x8 bfrag = *(const bf16x8*)(sm.Bs + colL * 64 + ((ci ^ (colL & 7)) * 8));
            #pragma unroll
            for (int m = 0; m < 4; ++m) {
                int row = m * 16 + (lane & 15);
                bf16x8 afrag = *(const bf16x8*)(sm.As + row * 64 + ((ci ^ (row & 7)) * 8));
                acc[m] = __builtin_amdgcn_mfma_f32_16x16x32_bf16(afrag, bfrag, acc[m], 0, 0, 0);
            }
        }
        __syncthreads();
    }
    int col = n0 + wid * 16 + (lane & 15);
    #pragma unroll
    for (int m = 0; m < 4; ++m) {
        int rb = m * 16 + (lane >> 4) * 4;
        #pragma unroll
        for (int r = 0; r < 4; ++r)
            a.pawe[((size_t)kc * BB + rb + r) * 2048 + col] = acc[m][r];
    }
}

// P4: LSTM pointwise + memory attention + carry; bid in [0,64)
__device__ __forceinline__ void phase4(const SArgs& a, int t, int bid, int tid, SMem& sm) {
    const int lane = tid & 63, wid = tid >> 6;
    const int b = bid;
    bool msk = t < (a.lens[b] - 1);
    for (int j = tid; j < 512; j += 256) {
        float g[4];
        #pragma unroll
        for (int q = 0; q < 4; ++q) {
            int col = q * 512 + j;
            float s = a.bih[col] + a.bhh[col]
                    + a.hhp[(size_t)b * 2048 + col]
                    + a.xpre[((size_t)t * BB + b) * 2048 + col];
            #pragma unroll
            for (int kc = 0; kc < 4; ++kc) s += a.pawe[((size_t)kc * BB + b) * 2048 + col];
            g[q] = s;
        }
        float gi = sigm(g[0]), gf = sigm(g[1]), gg = tanh_f(g[2]), go = sigm(g[3]);
        float cold = a.c[b * 512 + j];
        float cn = gf * cold + gi * gg;
        a.c[b * 512 + j] = msk ? cn : cold;
        sm.hss[j] = go * tanh_f(cn);
    }
    __syncthreads();
    for (int m = wid * 32; m < wid * 32 + 32; ++m) {
        const float* r = a.memB + (size_t)m * 512 + lane * 8;
        float4 r0 = *(const float4*)(r);
        float4 r1 = *(const float4*)(r + 4);
        float4 h0 = *(const float4*)(&sm.hss[lane * 8]);
        float4 h1 = *(const float4*)(&sm.hss[lane * 8 + 4]);
        float s = r0.x * h0.x + r0.y * h0.y + r0.z * h0.z + r0.w * h0.w
                + r1.x * h1.x + r1.y * h1.y + r1.z * h1.z + r1.w * h1.w;
        #pragma unroll
        for (int off = 32; off; off >>= 1) s += __shfl_down(s, off);
        if (lane == 0) sm.simss[m] = s;
    }
    __syncthreads();
    float v = (tid < 128) ? sm.simss[tid] : -3.4e38f;
    sm.reds[tid] = v; __syncthreads();
    for (int s = 128; s; s >>= 1) { if (tid < s) sm.reds[tid] = fmaxf(sm.reds[tid], sm.reds[tid + s]); __syncthreads(); }
    float mx = sm.reds[0]; __syncthreads();
    float ev = (tid < 128) ? __expf(v - mx) : 0.f;
    sm.reds[tid] = ev; __syncthreads();
    for (int s = 128; s; s >>= 1) { if (tid < s) sm.reds[tid] += sm.reds[tid + s]; __syncthreads(); }
    if (tid < 128) sm.pss[tid] = ev / sm.reds[0];
    __syncthreads();
    for (int d = tid; d < 512; d += 256) {
        float s = 0.f;
        #pragma unroll 4
        for (int m = 0; m < 128; ++m) s += sm.pss[m] * a.memB[(size_t)m * 512 + d];
        float hn = sm.hss[d] + s;
        a.histB[((size_t)t * BB + b) * 512 + d] = f2bf(hn);
        float hold = a.h[b * 512 + d];
        float hv = msk ? hn : hold;
        a.h[b * 512 + d] = hv;
        a.hB[b * 512 + d] = f2bf(hv);
    }
}

// persistent cooperative kernel: all 21 steps, grid 256 x 256
__global__ __launch_bounds__(256) void k_steps(SArgs a) {
    cg::grid_group grid = cg::this_grid();
    __shared__ SMem sm;
    const int bid = blockIdx.x, tid = threadIdx.x;
    for (int t = 0; t < TT; ++t) {
        if (bid < 72) phase1(a, bid, tid, sm);
        grid.sync();
        phase2(a, t, bid, tid, sm);
        grid.sync();
        if (bid < 128) phase3(a, bid, tid, sm);
        grid.sync();
        if (bid < 64) phase4(a, t, bid, tid, sm);
        grid.sync();
    }
}

// fallback per-phase kernels (identical math)
__global__ __launch_bounds__(256) void k_p1(SArgs a) {
    __shared__ SMem sm; phase1(a, blockIdx.x, threadIdx.x, sm);
}
__global__ __launch_bounds__(256) void k_p2(SArgs a, int t) {
    __shared__ SMem sm; phase2(a, t, blockIdx.x, threadIdx.x, sm);
}
__global__ __launch_bounds__(256) void k_p3(SArgs a) {
    __shared__ SMem sm; phase3(a, blockIdx.x, threadIdx.x, sm);
}
__global__ __launch_bounds__(256) void k_p4(SArgs a, int t) {
    __shared__ SMem sm; phase4(a, t, blockIdx.x, threadIdx.x, sm);
}

// batched preds: hist(21*64 x 512) @ WfcT^T + bfc, masked. grid (40, 21)
__global__ __launch_bounds__(256) void k_preds_batch(const ushort* __restrict__ histB,
        const ushort* __restrict__ WfcT, const float* __restrict__ bfc,
        const int* __restrict__ lens, float* __restrict__ out) {
    __shared__ alignas(16) ushort As[64 * 64];
    __shared__ alignas(16) ushort Bs[256 * 64];
    const int n0 = blockIdx.x * 256;
    const int t = blockIdx.y;
    const ushort* A = histB + (size_t)t * BB * 512;
    const int tid = threadIdx.x, wid = tid >> 6, lane = tid & 63;
    f32x4 acc[4][4] = {};
    for (int k0 = 0; k0 < 512; k0 += 64) {
        #pragma unroll
        for (int p = 0; p < 2; ++p) {
            int c = p * 256 + tid;
            int r = c >> 3, cc = c & 7;
            float4 v = *(const float4*)(A + r * 512 + k0 + cc * 8);
            *(float4*)(As + r * 64 + ((cc ^ (r & 7)) * 8)) = v;
        }
        #pragma unroll
        for (int p = 0; p < 8; ++p) {
            int c = p * 256 + tid;
            int r = c >> 3, cc = c & 7;
            float4 v = *(const float4*)(WfcT + (size_t)(n0 + r) * 512 + k0 + cc * 8);
            *(float4*)(Bs + r * 64 + ((cc ^ (r & 7)) * 8)) = v;
        }
        __syncthreads();
        #pragma unroll
        for (int kk = 0; kk < 2; ++kk) {
            int ci = kk * 4 + (lane >> 4);
            bf16x8 afrag[4], bfrag[4];
            #pragma unroll
            for (int m = 0; m < 4; ++m) {
                int row = m * 16 + (lane & 15);
                afrag[m] = *(const bf16x8*)(As + row * 64 + ((ci ^ (row & 7)) * 8));
            }
            #pragma unroll
            for (int n = 0; n < 4; ++n) {
                int col = wid * 64 + n * 16 + (lane & 15);
                bfrag[n] = *(const bf16x8*)(Bs + col * 64 + ((ci ^ (col & 7)) * 8));
            }
            #pragma unroll
            for (int m = 0; m < 4; ++m)
                #pragma unroll
                for (int n = 0; n < 4; ++n)
                    acc[m][n] = __builtin_amdgcn_mfma_f32_16x16x32_bf16(afrag[m], bfrag[n], acc[m][n], 0, 0, 0);
        }
        __syncthreads();
    }
    #pragma unroll
    for (int m = 0; m < 4; ++m) {
        int rb = m * 16 + (lane >> 4) * 4;
        #pragma unroll
        for (int n = 0; n < 4; ++n) {
            int col = n0 + wid * 64 + n * 16 + (lane & 15);
            if (col < VV) {
                float bv = bfc[col];
                #pragma unroll
                for (int r = 0; r < 4; ++r) {
                    int b = rb + r;
                    bool msk = t < (lens[b] - 1);
                    out[((size_t)b * TT + t) * VV + col] = msk ? (acc[m][n][r] + bv) : 0.f;
                }
            }
        }
    }
}

// ---------------- launch ----------------

extern "C" void kernel_launch(void* const* d_in, const int* in_sizes, int n_in,
                              void* d_out, int out_size, void* d_ws, size_t ws_size,
                              hipStream_t stream) {
    const float* enc     = (const float*)d_in[0];
    const int*   caps    = (const int*)d_in[1];
    const int*   lens    = (const int*)d_in[2];
    const float* emb     = (const float*)d_in[3];
    const float* W_enc   = (const float*)d_in[4];
    const float* b_enc   = (const float*)d_in[5];
    const float* W_dec   = (const float*)d_in[6];
    const float* b_dec   = (const float*)d_in[7];
    const float* W_full  = (const float*)d_in[8];
    const float* W_inith = (const float*)d_in[10];
    const float* b_inith = (const float*)d_in[11];
    const float* W_initc = (const float*)d_in[12];
    const float* b_initc = (const float*)d_in[13];
    const float* W_beta  = (const float*)d_in[14];
    const float* b_beta  = (const float*)d_in[15];
    const float* W_ih    = (const float*)d_in[16];
    const float* b_ih    = (const float*)d_in[17];
    const float* W_hh    = (const float*)d_in[18];
    const float* b_hh    = (const float*)d_in[19];
    const float* memB    = (const float*)d_in[20];
    const float* W_fc    = (const float*)d_in[21];
    const float* b_fc    = (const float*)d_in[22];

    float* out = (float*)d_out;
    float* preds_out  = out;
    float* declen_out = out + (size_t)BB * TT * VV;
    float* alpha_out  = declen_out + BB;

    float* ws    = (float*)d_ws;
    ushort* att1T = (ushort*)ws;  ws += (size_t)64 * 512 * 200 / 2;
    float* h     = ws;  ws += BB * DECD;
    float* c     = ws;  ws += BB * DECD;
    float* att2  = ws;  ws += BB * 512;
    float* gate  = ws;  ws += BB * 2048;
    float* hhp   = ws;  ws += BB * 2048;
    float* pawe  = ws;  ws += (size_t)4 * BB * 2048;
    float* xpre  = ws;  ws += (size_t)TT * BB * 2048;
    ushort* hB   = (ushort*)ws;  ws += BB * DECD / 2;
    uint*  aweB  = (uint*)ws;    ws += BB * 1024;
    ushort* histB = (ushort*)ws; ws += (size_t)TT * BB * DECD / 2;
    ushort* encB  = (ushort*)ws; ws += (size_t)12544 * 2048 / 2;
    ushort* WencT = (ushort*)ws; ws += (size_t)512 * 2048 / 2;
    ushort* WfcT  = (ushort*)ws; ws += (size_t)10240 * 512 / 2;
    ushort* WcatT = (ushort*)ws; ws += (size_t)4608 * 512 / 2;
    ushort* WihT  = (ushort*)ws; ws += (size_t)2048 * KIH / 2;
    // aliases (setup-only, dead before their regions are written)
    float* mean  = (float*)att1T;   // dead before k_att1T
    float* ipart = xpre;            // dead before k_xpre

    k_cvt<<<(12544 * 2048 / 4 + 255) / 256, 256, 0, stream>>>(enc, encB, 12544 * 2048 / 4);
    k_mean16<<<256, 256, 0, stream>>>(encB, mean);
    k_ipart<<<dim3(8, 4, 2), 256, 0, stream>>>(mean, W_inith, W_initc, ipart);
    k_ifin<<<256, 256, 0, stream>>>(ipart, b_inith, b_initc, h, c, hB);
    k_declen<<<1, 64, 0, stream>>>(lens, declen_out);
    k_tcvt_all<<<3392, 256, 0, stream>>>(W_enc, W_dec, W_beta, W_hh, W_ih, W_fc,
                                         WencT, WcatT, WcatT + (size_t)512 * 512,
                                         WcatT + (size_t)2560 * 512, WihT, WfcT);
    k_att1T<<<dim3(2, 196), 256, 0, stream>>>(encB, WencT, b_enc, att1T);
    k_xpre<<<dim3(8, TT), 256, 0, stream>>>(emb, caps, WihT, xpre);

    SArgs sa;
    sa.hB = hB; sa.h = h; sa.c = c;
    sa.WcatT = WcatT; sa.bd = b_dec; sa.bb = b_beta;
    sa.WihT = WihT; sa.xpre = xpre; sa.att1T = att1T;
    sa.Wf = W_full; sa.encB = encB;
    sa.bih = b_ih; sa.bhh = b_hh;
    sa.lens = lens; sa.memB = memB;
    sa.att2 = att2; sa.gate = gate; sa.hhp = hhp;
    sa.aweB = aweB; sa.pawe = pawe;
    sa.histB = histB; sa.alpha_out = alpha_out;

    void* kargs[] = { (void*)&sa };
    hipError_t ce = hipLaunchCooperativeKernel((const void*)k_steps, dim3(256), dim3(256),
                                               kargs, 0, stream);
    if (ce != hipSuccess) {
        (void)hipGetLastError();   // clear sticky error; fall back to per-phase launches
        for (int t = 0; t < TT; ++t) {
            k_p1<<<72,  256, 0, stream>>>(sa);
            k_p2<<<256, 256, 0, stream>>>(sa, t);
            k_p3<<<128, 256, 0, stream>>>(sa);
            k_p4<<<64,  256, 0, stream>>>(sa, t);
        }
    }

    k_preds_batch<<<dim3(40, TT), 256, 0, stream>>>(histB, WfcT, b_fc, lens, preds_out);
}

// Round 9
// 4314.903 us; speedup vs baseline: 1.1443x; 1.1443x over previous
//
#include <hip/hip_runtime.h>
#include <hip/hip_cooperative_groups.h>

namespace cg = cooperative_groups;

#define BB   64
#define PP   196
#define ENCD 2048
#define DECD 512
#define VV   10000
#define TT   21
#define KIH  2560   // (EMB + ENC) rows of W_ih

typedef __attribute__((ext_vector_type(8))) short bf16x8;
typedef __attribute__((ext_vector_type(4))) float f32x4;

__device__ __forceinline__ float sigm(float x)   { return 1.f / (1.f + __expf(-x)); }
__device__ __forceinline__ float tanh_f(float x) { return 1.f - 2.f / (1.f + __expf(2.f * x)); }
__device__ __forceinline__ ushort f2bf(float x) {
    unsigned u = __float_as_uint(x);
    unsigned r = (u + 0x7FFFu + ((u >> 16) & 1u)) >> 16;
    return (ushort)r;
}
__device__ __forceinline__ float bf2f(ushort u) {
    return __uint_as_float(((unsigned)u) << 16);
}
union U8 { float4 f4; ushort u[8]; };

// ---------------- setup kernels ----------------

__global__ void k_cvt(const float* __restrict__ in, ushort* __restrict__ out, int n4) {
    int i = blockIdx.x * 256 + threadIdx.x;
    if (i >= n4) return;
    float4 v = ((const float4*)in)[i];
    ushort4 o; o.x = f2bf(v.x); o.y = f2bf(v.y); o.z = f2bf(v.z); o.w = f2bf(v.w);
    ((ushort4*)out)[i] = o;
}

__global__ void k_mean16(const ushort* __restrict__ encB, float* __restrict__ mean) {
    int idx = blockIdx.x * 256 + threadIdx.x;
    int b = idx >> 10, e2 = idx & 1023;
    const uint* p = (const uint*)encB + (size_t)b * PP * 1024 + e2;
    float s0 = 0.f, s1 = 0.f;
    #pragma unroll 7
    for (int i = 0; i < PP; ++i) {
        uint v = p[(size_t)i * 1024];
        s0 += __uint_as_float(v << 16);
        s1 += __uint_as_float(v & 0xffff0000u);
    }
    mean[b * 2048 + e2 * 2]     = s0 * (1.f / 196.f);
    mean[b * 2048 + e2 * 2 + 1] = s1 * (1.f / 196.f);
}

__global__ __launch_bounds__(256) void k_ipart(const float* __restrict__ mean,
        const float* __restrict__ Wh, const float* __restrict__ Wc,
        float* __restrict__ ipart) {
    __shared__ alignas(16) float As[32][68];
    __shared__ alignas(16) float Bs[32][68];
    const int n0 = blockIdx.x * 64;
    const int kc = blockIdx.y;
    const int mat = blockIdx.z;
    const float* Bp = mat ? Wc : Wh;
    const int tid = threadIdx.x, tx = tid & 15, ty = tid >> 4;
    float acc[4][4] = {};
    for (int k0 = 0; k0 < 512; k0 += 32) {
        #pragma unroll
        for (int p = 0; p < 2; ++p) {
            int c = p * 256 + tid;
            int m = c >> 3, k4 = (c & 7) * 4;
            float4 v = *(const float4*)(mean + m * 2048 + kc * 512 + k0 + k4);
            As[k4 + 0][m] = v.x; As[k4 + 1][m] = v.y; As[k4 + 2][m] = v.z; As[k4 + 3][m] = v.w;
            int kb = c >> 4, n4 = (c & 15) * 4;
            float4 w = *(const float4*)(Bp + (size_t)(kc * 512 + k0 + kb) * 512 + n0 + n4);
            *(float4*)&Bs[kb][n4] = w;
        }
        __syncthreads();
        #pragma unroll 8
        for (int k = 0; k < 32; ++k) {
            float4 a = *(const float4*)&As[k][ty * 4];
            float4 b = *(const float4*)&Bs[k][tx * 4];
            float av[4] = {a.x, a.y, a.z, a.w}, bv[4] = {b.x, b.y, b.z, b.w};
            #pragma unroll
            for (int i = 0; i < 4; ++i)
                #pragma unroll
                for (int j = 0; j < 4; ++j) acc[i][j] += av[i] * bv[j];
        }
        __syncthreads();
    }
    #pragma unroll
    for (int i = 0; i < 4; ++i) {
        int m = ty * 4 + i;
        #pragma unroll
        for (int j = 0; j < 4; ++j) {
            int n = n0 + tx * 4 + j;
            ipart[((size_t)(mat * 4 + kc) * BB + m) * 512 + n] = acc[i][j];
        }
    }
}

__global__ void k_ifin(const float* __restrict__ ipart,
                       const float* __restrict__ bh, const float* __restrict__ bc,
                       float* __restrict__ h, float* __restrict__ c, ushort* __restrict__ hB) {
    int idx = blockIdx.x * 256 + threadIdx.x;
    int mat = idx >> 15, rem = idx & 32767;
    int b = rem >> 9, d = rem & 511;
    float s = 0.f;
    #pragma unroll
    for (int kc = 0; kc < 4; ++kc) s += ipart[((size_t)(mat * 4 + kc) * BB + b) * 512 + d];
    if (mat) c[rem] = s + bc[d];
    else { float v = s + bh[d]; h[rem] = v; hB[rem] = f2bf(v); }
}

__global__ __launch_bounds__(256) void k_tcvt_all(
        const float* __restrict__ Wenc, const float* __restrict__ Wdec,
        const float* __restrict__ Wbeta, const float* __restrict__ Whh,
        const float* __restrict__ Wih, const float* __restrict__ Wfc,
        ushort* __restrict__ WencT, ushort* __restrict__ WdecT,
        ushort* __restrict__ WbetaT, ushort* __restrict__ WhhT,
        ushort* __restrict__ WihT, ushort* __restrict__ WfcT) {
    __shared__ float lds[64 * 65];
    int l = blockIdx.x;
    const float* in; ushort* out; int K, N, KT;
    if (l < 256)       { in = Wenc;  out = WencT;  K = 2048; N = 512;   KT = 32; }
    else if (l < 320)  { l -= 256;  in = Wdec;  out = WdecT;  K = 512;  N = 512;   KT = 8; }
    else if (l < 576)  { l -= 320;  in = Wbeta; out = WbetaT; K = 512;  N = 2048;  KT = 8; }
    else if (l < 832)  { l -= 576;  in = Whh;   out = WhhT;   K = 512;  N = 2048;  KT = 8; }
    else if (l < 2112) { l -= 832;  in = Wih;   out = WihT;   K = KIH;  N = 2048;  KT = 40; }
    else               { l -= 2112; in = Wfc;   out = WfcT;   K = 512;  N = 10000; KT = 8; }
    const int k0 = (l % KT) * 64, n0 = (l / KT) * 64;
    const int tid = threadIdx.x;
    for (int i = tid; i < 4096; i += 256) {
        int kk = i >> 6, nn = i & 63;
        float v = 0.f;
        if (n0 + nn < N) v = in[(size_t)(k0 + kk) * N + n0 + nn];
        lds[nn * 65 + kk] = v;
    }
    __syncthreads();
    for (int i = tid; i < 4096; i += 256) {
        int nn = i >> 6, kk = i & 63;
        out[(size_t)(n0 + nn) * K + k0 + kk] = f2bf(lds[nn * 65 + kk]);
    }
}

// att1T[b][col][p] bf16 = bf16(enc @ W_enc + b_enc) transposed per b. grid (2, 196)
__global__ __launch_bounds__(256) void k_att1T(const ushort* __restrict__ A,
        const ushort* __restrict__ Bt, const float* __restrict__ bias,
        ushort* __restrict__ att1T) {
    __shared__ alignas(16) ushort As[64 * 64];
    __shared__ alignas(16) ushort Bs[256 * 64];
    const int n0 = blockIdx.x * 256;
    const int m0 = blockIdx.y * 64;
    const int tid = threadIdx.x, wid = tid >> 6, lane = tid & 63;
    f32x4 acc[4][4] = {};
    for (int k0 = 0; k0 < 2048; k0 += 64) {
        #pragma unroll
        for (int p = 0; p < 2; ++p) {
            int c = p * 256 + tid;
            int r = c >> 3, cc = c & 7;
            float4 v = *(const float4*)(A + (size_t)(m0 + r) * 2048 + k0 + cc * 8);
            *(float4*)(As + r * 64 + ((cc ^ (r & 7)) * 8)) = v;
        }
        #pragma unroll
        for (int p = 0; p < 8; ++p) {
            int c = p * 256 + tid;
            int r = c >> 3, cc = c & 7;
            float4 v = *(const float4*)(Bt + (size_t)(n0 + r) * 2048 + k0 + cc * 8);
            *(float4*)(Bs + r * 64 + ((cc ^ (r & 7)) * 8)) = v;
        }
        __syncthreads();
        #pragma unroll
        for (int kk = 0; kk < 2; ++kk) {
            int ci = kk * 4 + (lane >> 4);
            bf16x8 afrag[4], bfrag[4];
            #pragma unroll
            for (int m = 0; m < 4; ++m) {
                int row = m * 16 + (lane & 15);
                afrag[m] = *(const bf16x8*)(As + row * 64 + ((ci ^ (row & 7)) * 8));
            }
            #pragma unroll
            for (int n = 0; n < 4; ++n) {
                int col = wid * 64 + n * 16 + (lane & 15);
                bfrag[n] = *(const bf16x8*)(Bs + col * 64 + ((ci ^ (col & 7)) * 8));
            }
            #pragma unroll
            for (int m = 0; m < 4; ++m)
                #pragma unroll
                for (int n = 0; n < 4; ++n)
                    acc[m][n] = __builtin_amdgcn_mfma_f32_16x16x32_bf16(afrag[m], bfrag[n], acc[m][n], 0, 0, 0);
        }
        __syncthreads();
    }
    #pragma unroll
    for (int m = 0; m < 4; ++m) {
        int rb = m0 + m * 16 + (lane >> 4) * 4;   // mult of 4; 196%4==0 so no b straddle
        int b = rb / 196;
        int p = rb - b * 196;
        #pragma unroll
        for (int n = 0; n < 4; ++n) {
            int col = n0 + wid * 64 + n * 16 + (lane & 15);
            float bv = bias[col];
            ushort4 o;
            o.x = f2bf(acc[m][n][0] + bv);
            o.y = f2bf(acc[m][n][1] + bv);
            o.z = f2bf(acc[m][n][2] + bv);
            o.w = f2bf(acc[m][n][3] + bv);
            *(ushort4*)(att1T + ((size_t)(b * 512 + col)) * 200 + p) = o;
        }
    }
}

// xpre[t][b][2048] = emb[caps[b,t]] @ W_ih[0:512]. grid (8, 21)
__global__ __launch_bounds__(256) void k_xpre(const float* __restrict__ emb,
        const int* __restrict__ caps, const ushort* __restrict__ WihT,
        float* __restrict__ xpre) {
    __shared__ alignas(16) ushort As[64 * 64];
    __shared__ alignas(16) ushort Bs[256 * 64];
    __shared__ int capsh[64];
    const int n0 = blockIdx.x * 256;
    const int t = blockIdx.y;
    const int tid = threadIdx.x, wid = tid >> 6, lane = tid & 63;
    if (tid < 64) capsh[tid] = caps[tid * 22 + t];
    __syncthreads();
    f32x4 acc[4][4] = {};
    for (int k0 = 0; k0 < 512; k0 += 64) {
        #pragma unroll
        for (int p = 0; p < 2; ++p) {
            int c = p * 256 + tid;
            int r = c >> 3, cc = c & 7;
            const float* er = emb + (size_t)capsh[r] * 512 + k0 + cc * 8;
            float4 v0 = *(const float4*)er;
            float4 v1 = *(const float4*)(er + 4);
            U8 pk;
            pk.u[0] = f2bf(v0.x); pk.u[1] = f2bf(v0.y); pk.u[2] = f2bf(v0.z); pk.u[3] = f2bf(v0.w);
            pk.u[4] = f2bf(v1.x); pk.u[5] = f2bf(v1.y); pk.u[6] = f2bf(v1.z); pk.u[7] = f2bf(v1.w);
            *(float4*)(As + r * 64 + ((cc ^ (r & 7)) * 8)) = pk.f4;
        }
        #pragma unroll
        for (int p = 0; p < 8; ++p) {
            int c = p * 256 + tid;
            int r = c >> 3, cc = c & 7;
            float4 v = *(const float4*)(WihT + (size_t)(n0 + r) * KIH + k0 + cc * 8);
            *(float4*)(Bs + r * 64 + ((cc ^ (r & 7)) * 8)) = v;
        }
        __syncthreads();
        #pragma unroll
        for (int kk = 0; kk < 2; ++kk) {
            int ci = kk * 4 + (lane >> 4);
            bf16x8 afrag[4], bfrag[4];
            #pragma unroll
            for (int m = 0; m < 4; ++m) {
                int row = m * 16 + (lane & 15);
                afrag[m] = *(const bf16x8*)(As + row * 64 + ((ci ^ (row & 7)) * 8));
            }
            #pragma unroll
            for (int n = 0; n < 4; ++n) {
                int col = wid * 64 + n * 16 + (lane & 15);
                bfrag[n] = *(const bf16x8*)(Bs + col * 64 + ((ci ^ (col & 7)) * 8));
            }
            #pragma unroll
            for (int m = 0; m < 4; ++m)
                #pragma unroll
                for (int n = 0; n < 4; ++n)
                    acc[m][n] = __builtin_amdgcn_mfma_f32_16x16x32_bf16(afrag[m], bfrag[n], acc[m][n], 0, 0, 0);
        }
        __syncthreads();
    }
    #pragma unroll
    for (int m = 0; m < 4; ++m) {
        int rb = m * 16 + (lane >> 4) * 4;
        #pragma unroll
        for (int n = 0; n < 4; ++n) {
            int col = n0 + wid * 64 + n * 16 + (lane & 15);
            #pragma unroll
            for (int r = 0; r < 4; ++r)
                xpre[((size_t)t * BB + rb + r) * 2048 + col] = acc[m][n][r];
        }
    }
}

__global__ void k_declen(const int* __restrict__ lens, float* __restrict__ out) {
    int b = threadIdx.x;
    if (b < BB) out[b] = (float)(lens[b] - 1);
}

// ---------------- step phases (shared by coop + fallback paths) ----------------

struct SArgs {
    ushort* hB; float* h; float* c;
    const ushort* WcatT; const float* bd; const float* bb;
    const ushort* WihT; const float* xpre; const ushort* att1T;
    const float* Wf; const ushort* encB;
    const float* bih; const float* bhh;
    const int* lens; const float* memB;
    float* att2; float* gate; float* hhp;
    uint* aweB; float* pawe;
    ushort* histB; float* alpha_out;
    int* bar;
};

struct SMem {
    ushort As[64 * 64];
    ushort Bs[64 * 64];
    float a2s[512], wfs[512], reds[256], als[224];
    float hss[512], simss[128], pss[128];
};

// hand-rolled grid barrier: per-block slots (128B apart) + block-0 scan + go flag.
// bar[i*32] = arrival slot of block i (i=1..255); bar[256*32] = go.
__device__ __forceinline__ void gbar(int* bar, int gen) {
    const int bid = blockIdx.x, tid = threadIdx.x;
    __syncthreads();
    __builtin_amdgcn_fence(__ATOMIC_RELEASE, "agent");
    if (bid == 0) {
        if (tid > 0) {
            while (__hip_atomic_load(&bar[tid * 32], __ATOMIC_RELAXED, __HIP_MEMORY_SCOPE_AGENT) < gen)
                __builtin_amdgcn_s_sleep(1);
        }
        __syncthreads();
        if (tid == 0)
            __hip_atomic_store(&bar[256 * 32], gen, __ATOMIC_RELAXED, __HIP_MEMORY_SCOPE_AGENT);
    } else if (tid == 0) {
        __hip_atomic_store(&bar[bid * 32], gen, __ATOMIC_RELAXED, __HIP_MEMORY_SCOPE_AGENT);
        while (__hip_atomic_load(&bar[256 * 32], __ATOMIC_RELAXED, __HIP_MEMORY_SCOPE_AGENT) < gen)
            __builtin_amdgcn_s_sleep(1);
    }
    __builtin_amdgcn_fence(__ATOMIC_ACQUIRE, "agent");
    __syncthreads();
}

// P1: att2|gate|hhp = hB @ WcatT (72 tiles of 64 cols, K=512)
__device__ __forceinline__ void phase1(const SArgs& a, int bid, int tid, SMem& sm) {
    const int lane = tid & 63, wid = tid >> 6;
    const int n0 = bid * 64;
    f32x4 acc[4] = {};
    for (int k0 = 0; k0 < 512; k0 += 64) {
        #pragma unroll
        for (int p = 0; p < 2; ++p) {
            int c8 = p * 256 + tid;
            int r = c8 >> 3, cc = c8 & 7;
            float4 v = *(const float4*)(a.hB + r * 512 + k0 + cc * 8);
            *(float4*)(sm.As + r * 64 + ((cc ^ (r & 7)) * 8)) = v;
            float4 w = *(const float4*)(a.WcatT + (size_t)(n0 + r) * 512 + k0 + cc * 8);
            *(float4*)(sm.Bs + r * 64 + ((cc ^ (r & 7)) * 8)) = w;
        }
        __syncthreads();
        #pragma unroll
        for (int kk = 0; kk < 2; ++kk) {
            int ci = kk * 4 + (lane >> 4);
            int colL = wid * 16 + (lane & 15);
            bf16x8 bfrag = *(const bf16x8*)(sm.Bs + colL * 64 + ((ci ^ (colL & 7)) * 8));
            #pragma unroll
            for (int m = 0; m < 4; ++m) {
                int row = m * 16 + (lane & 15);
                bf16x8 afrag = *(const bf16x8*)(sm.As + row * 64 + ((ci ^ (row & 7)) * 8));
                acc[m] = __builtin_amdgcn_mfma_f32_16x16x32_bf16(afrag, bfrag, acc[m], 0, 0, 0);
            }
        }
        __syncthreads();
    }
    int col = n0 + wid * 16 + (lane & 15);
    #pragma unroll
    for (int m = 0; m < 4; ++m) {
        int rb = m * 16 + (lane >> 4) * 4;
        #pragma unroll
        for (int r = 0; r < 4; ++r) {
            int row = rb + r;
            float v = acc[m][r];
            if (col < 512)       a.att2[row * 512 + col] = v + a.bd[col];
            else if (col < 2560) a.gate[row * 2048 + (col - 512)] = sigm(v + a.bb[col - 512]);
            else                 a.hhp[(size_t)row * 2048 + (col - 2560)] = v;
        }
    }
}

// P2: e-scores + softmax + awe; bid in [0,256): b=bid>>2, pc=bid&3
__device__ __forceinline__ void phase2(const SArgs& a, int t, int bid, int tid, SMem& sm) {
    const int b = bid >> 2, pc = bid & 3;
    for (int i = tid; i < 512; i += 256) { sm.a2s[i] = a.att2[b * 512 + i]; sm.wfs[i] = a.Wf[i]; }
    __syncthreads();
    float es = -3.4e38f;
    if (tid < PP) {
        const ushort* rp = a.att1T + (size_t)b * 512 * 200 + tid;
        float s = 0.f;
        #pragma unroll 4
        for (int k = 0; k < 512; ++k) {
            float v = bf2f(rp[(size_t)k * 200]) + sm.a2s[k];
            s += (v > 0.f ? v : 0.f) * sm.wfs[k];
        }
        es = s;
    }
    sm.reds[tid] = es; __syncthreads();
    for (int s = 128; s; s >>= 1) { if (tid < s) sm.reds[tid] = fmaxf(sm.reds[tid], sm.reds[tid + s]); __syncthreads(); }
    float mx = sm.reds[0]; __syncthreads();
    float ev = (tid < PP) ? __expf(es - mx) : 0.f;
    sm.reds[tid] = ev; __syncthreads();
    for (int s = 128; s; s >>= 1) { if (tid < s) sm.reds[tid] += sm.reds[tid + s]; __syncthreads(); }
    float inv = 1.f / sm.reds[0];
    if (tid < PP) {
        float al = ev * inv;
        sm.als[tid] = al;
        if (pc == 0) {
            bool m = t < (a.lens[b] - 1);
            a.alpha_out[((size_t)b * TT + t) * PP + tid] = m ? al : 0.f;
        }
    }
    __syncthreads();
    int pair = pc * 256 + tid;
    const uint* pp = (const uint*)a.encB + (size_t)b * PP * 1024 + pair;
    float s0 = 0.f, s1 = 0.f;
    #pragma unroll 4
    for (int i = 0; i < PP; ++i) {
        uint vv = pp[(size_t)i * 1024];
        float al = sm.als[i];
        s0 += al * __uint_as_float(vv << 16);
        s1 += al * __uint_as_float(vv & 0xffff0000u);
    }
    int e = pair * 2;
    float g0 = s0 * a.gate[b * 2048 + e];
    float g1 = s1 * a.gate[b * 2048 + e + 1];
    a.aweB[b * 1024 + pair] = (uint)f2bf(g0) | ((uint)f2bf(g1) << 16);
}

// P3: pawe[kc] = aweB slice @ W_ih slice; bid in [0,128)
__device__ __forceinline__ void phase3(const SArgs& a, int bid, int tid, SMem& sm) {
    const int lane = tid & 63, wid = tid >> 6;
    const int n0 = (bid & 31) * 64, kc = bid >> 5;
    const ushort* aweU = (const ushort*)a.aweB;
    f32x4 acc[4] = {};
    for (int k0 = 0; k0 < 512; k0 += 64) {
        #pragma unroll
        for (int p = 0; p < 2; ++p) {
            int c8 = p * 256 + tid;
            int r = c8 >> 3, cc = c8 & 7;
            float4 v = *(const float4*)(aweU + r * 2048 + kc * 512 + k0 + cc * 8);
            *(float4*)(sm.As + r * 64 + ((cc ^ (r & 7)) * 8)) = v;
            float4 w = *(const float4*)(a.WihT + (size_t)(n0 + r) * KIH + 512 + kc * 512 + k0 + cc * 8);
            *(float4*)(sm.Bs + r * 64 + ((cc ^ (r & 7)) * 8)) = w;
        }
        __syncthreads();
        #pragma unroll
        for (int kk = 0; kk < 2; ++kk) {
            int ci = kk * 4 + (lane >> 4);
            int colL = wid * 16 + (lane & 15);
            bf16x8 bfrag = *(const bf16x8*)(sm.Bs + colL * 64 + ((ci ^ (colL & 7)) * 8));
            #pragma unroll
            for (int m = 0; m < 4; ++m) {
                int row = m * 16 + (lane & 15);
                bf16x8 afrag = *(const bf16x8*)(sm.As + row * 64 + ((ci ^ (row & 7)) * 8));
                acc[m] = __builtin_amdgcn_mfma_f32_16x16x32_bf16(afrag, bfrag, acc[m], 0, 0, 0);
            }
        }
        __syncthreads();
    }
    int col = n0 + wid * 16 + (lane & 15);
    #pragma unroll
    for (int m = 0; m < 4; ++m) {
        int rb = m * 16 + (lane >> 4) * 4;
        #pragma unroll
        for (int r = 0; r < 4; ++r)
            a.pawe[((size_t)kc * BB + rb + r) * 2048 + col] = acc[m][r];
    }
}

// P4: LSTM pointwise + memory attention + carry; bid in [0,64)
__device__ __forceinline__ void phase4(const SArgs& a, int t, int bid, int tid, SMem& sm) {
    const int lane = tid & 63, wid = tid >> 6;
    const int b = bid;
    bool msk = t < (a.lens[b] - 1);
    for (int j = tid; j < 512; j += 256) {
        float g[4];
        #pragma unroll
        for (int q = 0; q < 4; ++q) {
            int col = q * 512 + j;
            float s = a.bih[col] + a.bhh[col]
                    + a.hhp[(size_t)b * 2048 + col]
                    + a.xpre[((size_t)t * BB + b) * 2048 + col];
            #pragma unroll
            for (int kc = 0; kc < 4; ++kc) s += a.pawe[((size_t)kc * BB + b) * 2048 + col];
            g[q] = s;
        }
        float gi = sigm(g[0]), gf = sigm(g[1]), gg = tanh_f(g[2]), go = sigm(g[3]);
        float cold = a.c[b * 512 + j];
        float cn = gf * cold + gi * gg;
        a.c[b * 512 + j] = msk ? cn : cold;
        sm.hss[j] = go * tanh_f(cn);
    }
    __syncthreads();
    for (int m = wid * 32; m < wid * 32 + 32; ++m) {
        const float* r = a.memB + (size_t)m * 512 + lane * 8;
        float4 r0 = *(const float4*)(r);
        float4 r1 = *(const float4*)(r + 4);
        float4 h0 = *(const float4*)(&sm.hss[lane * 8]);
        float4 h1 = *(const float4*)(&sm.hss[lane * 8 + 4]);
        float s = r0.x * h0.x + r0.y * h0.y + r0.z * h0.z + r0.w * h0.w
                + r1.x * h1.x + r1.y * h1.y + r1.z * h1.z + r1.w * h1.w;
        #pragma unroll
        for (int off = 32; off; off >>= 1) s += __shfl_down(s, off);
        if (lane == 0) sm.simss[m] = s;
    }
    __syncthreads();
    float v = (tid < 128) ? sm.simss[tid] : -3.4e38f;
    sm.reds[tid] = v; __syncthreads();
    for (int s = 128; s; s >>= 1) { if (tid < s) sm.reds[tid] = fmaxf(sm.reds[tid], sm.reds[tid + s]); __syncthreads(); }
    float mx = sm.reds[0]; __syncthreads();
    float ev = (tid < 128) ? __expf(v - mx) : 0.f;
    sm.reds[tid] = ev; __syncthreads();
    for (int s = 128; s; s >>= 1) { if (tid < s) sm.reds[tid] += sm.reds[tid + s]; __syncthreads(); }
    if (tid < 128) sm.pss[tid] = ev / sm.reds[0];
    __syncthreads();
    for (int d = tid; d < 512; d += 256) {
        float s = 0.f;
        #pragma unroll 4
        for (int m = 0; m < 128; ++m) s += sm.pss[m] * a.memB[(size_t)m * 512 + d];
        float hn = sm.hss[d] + s;
        a.histB[((size_t)t * BB + b) * 512 + d] = f2bf(hn);
        float hold = a.h[b * 512 + d];
        float hv = msk ? hn : hold;
        a.h[b * 512 + d] = hv;
        a.hB[b * 512 + d] = f2bf(hv);
    }
}

// persistent kernel: all 21 steps, grid 256 x 256, hand-rolled barrier
__global__ __launch_bounds__(256) void k_steps(SArgs a) {
    __shared__ SMem sm;
    const int bid = blockIdx.x, tid = threadIdx.x;
    int gen = 0;
    for (int t = 0; t < TT; ++t) {
        if (bid < 72) phase1(a, bid, tid, sm);
        gbar(a.bar, ++gen);
        phase2(a, t, bid, tid, sm);
        gbar(a.bar, ++gen);
        if (bid < 128) phase3(a, bid, tid, sm);
        gbar(a.bar, ++gen);
        if (bid < 64) phase4(a, t, bid, tid, sm);
        if (t != TT - 1) gbar(a.bar, ++gen);
    }
}

// fallback per-phase kernels (identical math)
__global__ __launch_bounds__(256) void k_p1(SArgs a) {
    __shared__ SMem sm; phase1(a, blockIdx.x, threadIdx.x, sm);
}
__global__ __launch_bounds__(256) void k_p2(SArgs a, int t) {
    __shared__ SMem sm; phase2(a, t, blockIdx.x, threadIdx.x, sm);
}
__global__ __launch_bounds__(256) void k_p3(SArgs a) {
    __shared__ SMem sm; phase3(a, blockIdx.x, threadIdx.x, sm);
}
__global__ __launch_bounds__(256) void k_p4(SArgs a, int t) {
    __shared__ SMem sm; phase4(a, t, blockIdx.x, threadIdx.x, sm);
}

// batched preds: hist(21*64 x 512) @ WfcT^T + bfc, masked. grid (40, 21)
__global__ __launch_bounds__(256) void k_preds_batch(const ushort* __restrict__ histB,
        const ushort* __restrict__ WfcT, const float* __restrict__ bfc,
        const int* __restrict__ lens, float* __restrict__ out) {
    __shared__ alignas(16) ushort As[64 * 64];
    __shared__ alignas(16) ushort Bs[256 * 64];
    const int n0 = blockIdx.x * 256;
    const int t = blockIdx.y;
    const ushort* A = histB + (size_t)t * BB * 512;
    const int tid = threadIdx.x, wid = tid >> 6, lane = tid & 63;
    f32x4 acc[4][4] = {};
    for (int k0 = 0; k0 < 512; k0 += 64) {
        #pragma unroll
        for (int p = 0; p < 2; ++p) {
            int c = p * 256 + tid;
            int r = c >> 3, cc = c & 7;
            float4 v = *(const float4*)(A + r * 512 + k0 + cc * 8);
            *(float4*)(As + r * 64 + ((cc ^ (r & 7)) * 8)) = v;
        }
        #pragma unroll
        for (int p = 0; p < 8; ++p) {
            int c = p * 256 + tid;
            int r = c >> 3, cc = c & 7;
            float4 v = *(const float4*)(WfcT + (size_t)(n0 + r) * 512 + k0 + cc * 8);
            *(float4*)(Bs + r * 64 + ((cc ^ (r & 7)) * 8)) = v;
        }
        __syncthreads();
        #pragma unroll
        for (int kk = 0; kk < 2; ++kk) {
            int ci = kk * 4 + (lane >> 4);
            bf16x8 afrag[4], bfrag[4];
            #pragma unroll
            for (int m = 0; m < 4; ++m) {
                int row = m * 16 + (lane & 15);
                afrag[m] = *(const bf16x8*)(As + row * 64 + ((ci ^ (row & 7)) * 8));
            }
            #pragma unroll
            for (int n = 0; n < 4; ++n) {
                int col = wid * 64 + n * 16 + (lane & 15);
                bfrag[n] = *(const bf16x8*)(Bs + col * 64 + ((ci ^ (col & 7)) * 8));
            }
            #pragma unroll
            for (int m = 0; m < 4; ++m)
                #pragma unroll
                for (int n = 0; n < 4; ++n)
                    acc[m][n] = __builtin_amdgcn_mfma_f32_16x16x32_bf16(afrag[m], bfrag[n], acc[m][n], 0, 0, 0);
        }
        __syncthreads();
    }
    #pragma unroll
    for (int m = 0; m < 4; ++m) {
        int rb = m * 16 + (lane >> 4) * 4;
        #pragma unroll
        for (int n = 0; n < 4; ++n) {
            int col = n0 + wid * 64 + n * 16 + (lane & 15);
            if (col < VV) {
                float bv = bfc[col];
                #pragma unroll
                for (int r = 0; r < 4; ++r) {
                    int b = rb + r;
                    bool msk = t < (lens[b] - 1);
                    out[((size_t)b * TT + t) * VV + col] = msk ? (acc[m][n][r] + bv) : 0.f;
                }
            }
        }
    }
}

// ---------------- launch ----------------

extern "C" void kernel_launch(void* const* d_in, const int* in_sizes, int n_in,
                              void* d_out, int out_size, void* d_ws, size_t ws_size,
                              hipStream_t stream) {
    const float* enc     = (const float*)d_in[0];
    const int*   caps    = (const int*)d_in[1];
    const int*   lens    = (const int*)d_in[2];
    const float* emb     = (const float*)d_in[3];
    const float* W_enc   = (const float*)d_in[4];
    const float* b_enc   = (const float*)d_in[5];
    const float* W_dec   = (const float*)d_in[6];
    const float* b_dec   = (const float*)d_in[7];
    const float* W_full  = (const float*)d_in[8];
    const float* W_inith = (const float*)d_in[10];
    const float* b_inith = (const float*)d_in[11];
    const float* W_initc = (const float*)d_in[12];
    const float* b_initc = (const float*)d_in[13];
    const float* W_beta  = (const float*)d_in[14];
    const float* b_beta  = (const float*)d_in[15];
    const float* W_ih    = (const float*)d_in[16];
    const float* b_ih    = (const float*)d_in[17];
    const float* W_hh    = (const float*)d_in[18];
    const float* b_hh    = (const float*)d_in[19];
    const float* memB    = (const float*)d_in[20];
    const float* W_fc    = (const float*)d_in[21];
    const float* b_fc    = (const float*)d_in[22];

    float* out = (float*)d_out;
    float* preds_out  = out;
    float* declen_out = out + (size_t)BB * TT * VV;
    float* alpha_out  = declen_out + BB;

    float* ws    = (float*)d_ws;
    ushort* att1T = (ushort*)ws;  ws += (size_t)64 * 512 * 200 / 2;
    float* h     = ws;  ws += BB * DECD;
    float* c     = ws;  ws += BB * DECD;
    float* att2  = ws;  ws += BB * 512;
    float* gate  = ws;  ws += BB * 2048;
    float* hhp   = ws;  ws += BB * 2048;
    float* pawe  = ws;  ws += (size_t)4 * BB * 2048;
    float* xpre  = ws;  ws += (size_t)TT * BB * 2048;
    ushort* hB   = (ushort*)ws;  ws += BB * DECD / 2;
    uint*  aweB  = (uint*)ws;    ws += BB * 1024;
    ushort* histB = (ushort*)ws; ws += (size_t)TT * BB * DECD / 2;
    ushort* encB  = (ushort*)ws; ws += (size_t)12544 * 2048 / 2;
    ushort* WencT = (ushort*)ws; ws += (size_t)512 * 2048 / 2;
    ushort* WfcT  = (ushort*)ws; ws += (size_t)10240 * 512 / 2;
    ushort* WcatT = (ushort*)ws; ws += (size_t)4608 * 512 / 2;
    ushort* WihT  = (ushort*)ws; ws += (size_t)2048 * KIH / 2;
    int*   bar   = (int*)ws;     ws += 257 * 32;
    // aliases (setup-only, dead before their regions are written)
    float* mean  = (float*)att1T;   // dead before k_att1T
    float* ipart = xpre;            // dead before k_xpre

    hipMemsetAsync(bar, 0, 257 * 32 * sizeof(int), stream);
    k_cvt<<<(12544 * 2048 / 4 + 255) / 256, 256, 0, stream>>>(enc, encB, 12544 * 2048 / 4);
    k_mean16<<<256, 256, 0, stream>>>(encB, mean);
    k_ipart<<<dim3(8, 4, 2), 256, 0, stream>>>(mean, W_inith, W_initc, ipart);
    k_ifin<<<256, 256, 0, stream>>>(ipart, b_inith, b_initc, h, c, hB);
    k_declen<<<1, 64, 0, stream>>>(lens, declen_out);
    k_tcvt_all<<<3392, 256, 0, stream>>>(W_enc, W_dec, W_beta, W_hh, W_ih, W_fc,
                                         WencT, WcatT, WcatT + (size_t)512 * 512,
                                         WcatT + (size_t)2560 * 512, WihT, WfcT);
    k_att1T<<<dim3(2, 196), 256, 0, stream>>>(encB, WencT, b_enc, att1T);
    k_xpre<<<dim3(8, TT), 256, 0, stream>>>(emb, caps, WihT, xpre);

    SArgs sa;
    sa.hB = hB; sa.h = h; sa.c = c;
    sa.WcatT = WcatT; sa.bd = b_dec; sa.bb = b_beta;
    sa.WihT = WihT; sa.xpre = xpre; sa.att1T = att1T;
    sa.Wf = W_full; sa.encB = encB;
    sa.bih = b_ih; sa.bhh = b_hh;
    sa.lens = lens; sa.memB = memB;
    sa.att2 = att2; sa.gate = gate; sa.hhp = hhp;
    sa.aweB = aweB; sa.pawe = pawe;
    sa.histB = histB; sa.alpha_out = alpha_out;
    sa.bar = bar;

    void* kargs[] = { (void*)&sa };
    hipError_t ce = hipLaunchCooperativeKernel((const void*)k_steps, dim3(256), dim3(256),
                                               kargs, 0, stream);
    if (ce != hipSuccess) {
        (void)hipGetLastError();   // clear sticky error; fall back to per-phase launches
        for (int t = 0; t < TT; ++t) {
            k_p1<<<72,  256, 0, stream>>>(sa);
            k_p2<<<256, 256, 0, stream>>>(sa, t);
            k_p3<<<128, 256, 0, stream>>>(sa);
            k_p4<<<64,  256, 0, stream>>>(sa, t);
        }
    }

    k_preds_batch<<<dim3(40, TT), 256, 0, stream>>>(histB, WfcT, b_fc, lens, preds_out);
}

// Round 11
// 4212.626 us; speedup vs baseline: 1.1721x; 1.0243x over previous
//
#include <hip/hip_runtime.h>

#define BB   64
#define PP   196
#define ENCD 2048
#define DECD 512
#define VV   10000
#define TT   21

typedef __attribute__((ext_vector_type(8))) short bf16x8;
typedef __attribute__((ext_vector_type(4))) float f32x4;
typedef __fp16 f16x2 __attribute__((ext_vector_type(2)));

__device__ __forceinline__ float sigm(float x)   { return 1.f / (1.f + __expf(-x)); }
__device__ __forceinline__ float tanh_f(float x) { return 1.f - 2.f / (1.f + __expf(2.f * x)); }
__device__ __forceinline__ ushort f2bf(float x) {
    unsigned u = __float_as_uint(x);
    unsigned r = (u + 0x7FFFu + ((u >> 16) & 1u)) >> 16;
    return (ushort)r;
}
__device__ __forceinline__ float bf2f(ushort u) {
    return __uint_as_float(((unsigned)u) << 16);
}
__device__ __forceinline__ uint pk2(float a, float b) {
    f16x2 p = __builtin_amdgcn_cvt_pkrtz(a, b);
    return *(uint*)&p;
}
__device__ __forceinline__ float dot2(uint w, uint x, float c) {
#if __has_builtin(__builtin_amdgcn_fdot2)
    return __builtin_amdgcn_fdot2(*(f16x2*)&w, *(f16x2*)&x, c, false);
#else
    f16x2 a = *(f16x2*)&w, b = *(f16x2*)&x;
    return c + (float)a[0] * (float)b[0] + (float)a[1] * (float)b[1];
#endif
}

// ---------------- setup kernels ----------------

__global__ void k_cvt(const float* __restrict__ in, ushort* __restrict__ out, int n4) {
    int i = blockIdx.x * 256 + threadIdx.x;
    if (i >= n4) return;
    float4 v = ((const float4*)in)[i];
    ushort4 o; o.x = f2bf(v.x); o.y = f2bf(v.y); o.z = f2bf(v.z); o.w = f2bf(v.w);
    ((ushort4*)out)[i] = o;
}

__global__ void k_mean16(const ushort* __restrict__ encB, float* __restrict__ mean) {
    int idx = blockIdx.x * 256 + threadIdx.x;
    int b = idx >> 10, e2 = idx & 1023;
    const uint* p = (const uint*)encB + (size_t)b * PP * 1024 + e2;
    float s0 = 0.f, s1 = 0.f;
    #pragma unroll 7
    for (int i = 0; i < PP; ++i) {
        uint v = p[(size_t)i * 1024];
        s0 += __uint_as_float(v << 16);
        s1 += __uint_as_float(v & 0xffff0000u);
    }
    mean[b * 2048 + e2 * 2]     = s0 * (1.f / 196.f);
    mean[b * 2048 + e2 * 2 + 1] = s1 * (1.f / 196.f);
}

__global__ __launch_bounds__(256) void k_ipart(const float* __restrict__ mean,
        const float* __restrict__ Wh, const float* __restrict__ Wc,
        float* __restrict__ ipart) {
    __shared__ alignas(16) float As[32][68];
    __shared__ alignas(16) float Bs[32][68];
    const int n0 = blockIdx.x * 64;
    const int kc = blockIdx.y;
    const int mat = blockIdx.z;
    const float* Bp = mat ? Wc : Wh;
    const int tid = threadIdx.x, tx = tid & 15, ty = tid >> 4;
    float acc[4][4] = {};
    for (int k0 = 0; k0 < 512; k0 += 32) {
        #pragma unroll
        for (int p = 0; p < 2; ++p) {
            int c = p * 256 + tid;
            int m = c >> 3, k4 = (c & 7) * 4;
            float4 v = *(const float4*)(mean + m * 2048 + kc * 512 + k0 + k4);
            As[k4 + 0][m] = v.x; As[k4 + 1][m] = v.y; As[k4 + 2][m] = v.z; As[k4 + 3][m] = v.w;
            int kb = c >> 4, n4 = (c & 15) * 4;
            float4 w = *(const float4*)(Bp + (size_t)(kc * 512 + k0 + kb) * 512 + n0 + n4);
            *(float4*)&Bs[kb][n4] = w;
        }
        __syncthreads();
        #pragma unroll 8
        for (int k = 0; k < 32; ++k) {
            float4 a = *(const float4*)&As[k][ty * 4];
            float4 b = *(const float4*)&Bs[k][tx * 4];
            float av[4] = {a.x, a.y, a.z, a.w}, bv[4] = {b.x, b.y, b.z, b.w};
            #pragma unroll
            for (int i = 0; i < 4; ++i)
                #pragma unroll
                for (int j = 0; j < 4; ++j) acc[i][j] += av[i] * bv[j];
        }
        __syncthreads();
    }
    #pragma unroll
    for (int i = 0; i < 4; ++i) {
        int m = ty * 4 + i;
        #pragma unroll
        for (int j = 0; j < 4; ++j) {
            int n = n0 + tx * 4 + j;
            ipart[((size_t)(mat * 4 + kc) * BB + m) * 512 + n] = acc[i][j];
        }
    }
}

__global__ void k_ifin(const float* __restrict__ ipart,
                       const float* __restrict__ bh, const float* __restrict__ bc,
                       float* __restrict__ h0, float* __restrict__ c0) {
    int idx = blockIdx.x * 256 + threadIdx.x;
    int mat = idx >> 15, rem = idx & 32767;
    int b = rem >> 9, d = rem & 511;
    float s = 0.f;
    #pragma unroll
    for (int kc = 0; kc < 4; ++kc) s += ipart[((size_t)(mat * 4 + kc) * BB + b) * 512 + d];
    if (mat) c0[rem] = s + bc[d];
    else     h0[rem] = s + bh[d];
}

// transposes: Wenc -> WencT[512][2048]; Wih rows 0..511 -> WihT0[2048][512]; Wfc -> WfcT[10240][512]
__global__ __launch_bounds__(256) void k_tcvt_all(
        const float* __restrict__ Wenc, const float* __restrict__ Wih,
        const float* __restrict__ Wfc,
        ushort* __restrict__ WencT, ushort* __restrict__ WihT0,
        ushort* __restrict__ WfcT) {
    __shared__ float lds[64 * 65];
    int l = blockIdx.x;
    const float* in; ushort* out; int K, N, KT;
    if (l < 256)      { in = Wenc; out = WencT; K = 2048; N = 512;   KT = 32; }
    else if (l < 512) { l -= 256; in = Wih;  out = WihT0; K = 512; N = 2048;  KT = 8; }
    else              { l -= 512; in = Wfc;  out = WfcT;  K = 512; N = 10000; KT = 8; }
    const int k0 = (l % KT) * 64, n0 = (l / KT) * 64;
    const int tid = threadIdx.x;
    for (int i = tid; i < 4096; i += 256) {
        int kk = i >> 6, nn = i & 63;
        float v = 0.f;
        if (n0 + nn < N) v = in[(size_t)(k0 + kk) * N + n0 + nn];
        lds[nn * 65 + kk] = v;
    }
    __syncthreads();
    for (int i = tid; i < 4096; i += 256) {
        int nn = i >> 6, kk = i & 63;
        out[(size_t)(n0 + nn) * K + k0 + kk] = f2bf(lds[nn * 65 + kk]);
    }
}

// WcatPK[k2][n] f16-pair pack of [W_dec | W_beta | W_hh] cols (n<512|<2560|<4608), pad to 5120
__global__ void k_packcat(const float* __restrict__ Wd, const float* __restrict__ Wb,
                          const float* __restrict__ Wh, uint* __restrict__ out) {
    int idx = blockIdx.x * 256 + threadIdx.x;   // 256*5120
    int k2 = idx / 5120, n = idx % 5120;
    int k = k2 * 2;
    float a = 0.f, b2 = 0.f;
    if (n < 512)       { a = Wd[(size_t)k * 512 + n];           b2 = Wd[(size_t)(k + 1) * 512 + n]; }
    else if (n < 2560) { int nn = n - 512;  a = Wb[(size_t)k * 2048 + nn]; b2 = Wb[(size_t)(k + 1) * 2048 + nn]; }
    else if (n < 4608) { int nn = n - 2560; a = Wh[(size_t)k * 2048 + nn]; b2 = Wh[(size_t)(k + 1) * 2048 + nn]; }
    out[idx] = pk2(a, b2);
}

// WihPK[k2][n]: rows 512..2559 of W_ih as f16 pairs: [1024][2048]
__global__ void k_packih(const float* __restrict__ Wih, uint* __restrict__ out) {
    int idx = blockIdx.x * 256 + threadIdx.x;   // 1024*2048
    int k2 = idx >> 11, n = idx & 2047;
    int r0 = 512 + k2 * 2;
    out[idx] = pk2(Wih[(size_t)r0 * 2048 + n], Wih[(size_t)(r0 + 1) * 2048 + n]);
}

// att1B[12544][512] bf16 = bf16(encB @ WencT^T + bias). grid (2, 196)
__global__ __launch_bounds__(256) void k_att1n(const ushort* __restrict__ A,
        const ushort* __restrict__ Bt, const float* __restrict__ bias,
        ushort* __restrict__ C) {
    __shared__ alignas(16) ushort As[64 * 64];
    __shared__ alignas(16) ushort Bs[256 * 64];
    const int n0 = blockIdx.x * 256;
    const int m0 = blockIdx.y * 64;
    const int tid = threadIdx.x, wid = tid >> 6, lane = tid & 63;
    f32x4 acc[4][4] = {};
    for (int k0 = 0; k0 < 2048; k0 += 64) {
        #pragma unroll
        for (int p = 0; p < 2; ++p) {
            int c = p * 256 + tid;
            int r = c >> 3, cc = c & 7;
            float4 v = *(const float4*)(A + (size_t)(m0 + r) * 2048 + k0 + cc * 8);
            *(float4*)(As + r * 64 + ((cc ^ (r & 7)) * 8)) = v;
        }
        #pragma unroll
        for (int p = 0; p < 8; ++p) {
            int c = p * 256 + tid;
            int r = c >> 3, cc = c & 7;
            float4 v = *(const float4*)(Bt + (size_t)(n0 + r) * 2048 + k0 + cc * 8);
            *(float4*)(Bs + r * 64 + ((cc ^ (r & 7)) * 8)) = v;
        }
        __syncthreads();
        #pragma unroll
        for (int kk = 0; kk < 2; ++kk) {
            int ci = kk * 4 + (lane >> 4);
            bf16x8 afrag[4], bfrag[4];
            #pragma unroll
            for (int m = 0; m < 4; ++m) {
                int row = m * 16 + (lane & 15);
                afrag[m] = *(const bf16x8*)(As + row * 64 + ((ci ^ (row & 7)) * 8));
            }
            #pragma unroll
            for (int n = 0; n < 4; ++n) {
                int col = wid * 64 + n * 16 + (lane & 15);
                bfrag[n] = *(const bf16x8*)(Bs + col * 64 + ((ci ^ (col & 7)) * 8));
            }
            #pragma unroll
            for (int m = 0; m < 4; ++m)
                #pragma unroll
                for (int n = 0; n < 4; ++n)
                    acc[m][n] = __builtin_amdgcn_mfma_f32_16x16x32_bf16(afrag[m], bfrag[n], acc[m][n], 0, 0, 0);
        }
        __syncthreads();
    }
    #pragma unroll
    for (int m = 0; m < 4; ++m) {
        int rb = m0 + m * 16 + (lane >> 4) * 4;
        #pragma unroll
        for (int n = 0; n < 4; ++n) {
            int col = n0 + wid * 64 + n * 16 + (lane & 15);
            float bv = bias[col];
            #pragma unroll
            for (int r = 0; r < 4; ++r)
                C[(size_t)(rb + r) * 512 + col] = f2bf(acc[m][n][r] + bv);
        }
    }
}

// xpre[t][b][2048] = emb[caps[b,t]] @ W_ih[0:512]. grid (8, 21). B = WihT0 [2048][512]
__global__ __launch_bounds__(256) void k_xpre(const float* __restrict__ emb,
        const int* __restrict__ caps, const ushort* __restrict__ WihT0,
        float* __restrict__ xpre) {
    __shared__ alignas(16) ushort As[64 * 64];
    __shared__ alignas(16) ushort Bs[256 * 64];
    __shared__ int capsh[64];
    const int n0 = blockIdx.x * 256;
    const int t = blockIdx.y;
    const int tid = threadIdx.x, wid = tid >> 6, lane = tid & 63;
    if (tid < 64) capsh[tid] = caps[tid * 22 + t];
    __syncthreads();
    f32x4 acc[4][4] = {};
    for (int k0 = 0; k0 < 512; k0 += 64) {
        #pragma unroll
        for (int p = 0; p < 2; ++p) {
            int c = p * 256 + tid;
            int r = c >> 3, cc = c & 7;
            const float* er = emb + (size_t)capsh[r] * 512 + k0 + cc * 8;
            float4 v0 = *(const float4*)er;
            float4 v1 = *(const float4*)(er + 4);
            union { float4 f4; ushort u[8]; } pk;
            pk.u[0] = f2bf(v0.x); pk.u[1] = f2bf(v0.y); pk.u[2] = f2bf(v0.z); pk.u[3] = f2bf(v0.w);
            pk.u[4] = f2bf(v1.x); pk.u[5] = f2bf(v1.y); pk.u[6] = f2bf(v1.z); pk.u[7] = f2bf(v1.w);
            *(float4*)(As + r * 64 + ((cc ^ (r & 7)) * 8)) = pk.f4;
        }
        #pragma unroll
        for (int p = 0; p < 8; ++p) {
            int c = p * 256 + tid;
            int r = c >> 3, cc = c & 7;
            float4 v = *(const float4*)(WihT0 + (size_t)(n0 + r) * 512 + k0 + cc * 8);
            *(float4*)(Bs + r * 64 + ((cc ^ (r & 7)) * 8)) = v;
        }
        __syncthreads();
        #pragma unroll
        for (int kk = 0; kk < 2; ++kk) {
            int ci = kk * 4 + (lane >> 4);
            bf16x8 afrag[4], bfrag[4];
            #pragma unroll
            for (int m = 0; m < 4; ++m) {
                int row = m * 16 + (lane & 15);
                afrag[m] = *(const bf16x8*)(As + row * 64 + ((ci ^ (row & 7)) * 8));
            }
            #pragma unroll
            for (int n = 0; n < 4; ++n) {
                int col = wid * 64 + n * 16 + (lane & 15);
                bfrag[n] = *(const bf16x8*)(Bs + col * 64 + ((ci ^ (col & 7)) * 8));
            }
            #pragma unroll
            for (int m = 0; m < 4; ++m)
                #pragma unroll
                for (int n = 0; n < 4; ++n)
                    acc[m][n] = __builtin_amdgcn_mfma_f32_16x16x32_bf16(afrag[m], bfrag[n], acc[m][n], 0, 0, 0);
        }
        __syncthreads();
    }
    #pragma unroll
    for (int m = 0; m < 4; ++m) {
        int rb = m * 16 + (lane >> 4) * 4;
        #pragma unroll
        for (int n = 0; n < 4; ++n) {
            int col = n0 + wid * 64 + n * 16 + (lane & 15);
            #pragma unroll
            for (int r = 0; r < 4; ++r)
                xpre[((size_t)t * BB + rb + r) * 2048 + col] = acc[m][n][r];
        }
    }
}

__global__ void k_declen(const int* __restrict__ lens, float* __restrict__ out) {
    int b = threadIdx.x;
    if (b < BB) out[b] = (float)(lens[b] - 1);
}

// ---------------- persistent per-batch megakernel: zero cross-block deps ----------------

struct MArgs {
    const int* lens; const float* h0; const float* c0;
    const uint* WcatPK; const float* bd; const float* bb;
    const ushort* att1B; const float* Wf; const uint* encU;
    const uint* WihPK; const float* xpre;
    const float* bih; const float* bhh; const float* memB;
    ushort* histB; float* alpha_out;
};

__global__ __launch_bounds__(1024) void k_mega(MArgs a) {
    __shared__ uint hpk[256];
    __shared__ float att2F[512];        // reused as hs[] after escore
    __shared__ float gateF[2048];
    __shared__ float hhpF[2048];
    __shared__ float xg[2048];
    __shared__ uint awepk[1024];
    __shared__ float cF[512], hF[512];
    __shared__ float esS[200], alphaS[200], wfS[512], red[256], simsS[128], psS[128];
    const int b = blockIdx.x, tid = threadIdx.x;
    const int lenb = a.lens[b];

    if (tid < 512) {
        hF[tid]  = a.h0[b * 512 + tid];
        cF[tid]  = a.c0[b * 512 + tid];
        wfS[tid] = a.Wf[tid];
    }
    __syncthreads();
    if (tid < 256) hpk[tid] = pk2(hF[2 * tid], hF[2 * tid + 1]);
    __syncthreads();

    for (int t = 0; t < TT; ++t) {
        const bool msk = t < lenb - 1;
        // (b) fused GEMV: [att2|gate|hhp] = h @ [W_dec|W_beta|W_hh]
        {
            float a0 = 0.f, a1 = 0.f, a2 = 0.f, a3 = 0.f, a4 = 0.f;
            #pragma unroll 4
            for (int k2 = 0; k2 < 256; ++k2) {
                uint xp = hpk[k2];
                const uint* wr = a.WcatPK + (size_t)k2 * 5120 + tid;
                a0 = dot2(wr[0],    xp, a0);
                a1 = dot2(wr[1024], xp, a1);
                a2 = dot2(wr[2048], xp, a2);
                a3 = dot2(wr[3072], xp, a3);
                a4 = dot2(wr[4096], xp, a4);
            }
            float av[5] = {a0, a1, a2, a3, a4};
            #pragma unroll
            for (int i = 0; i < 5; ++i) {
                int n = tid + i * 1024;
                if (n < 512)        att2F[n] = av[i] + a.bd[n];
                else if (n < 2560)  gateF[n - 512] = sigm(av[i] + a.bb[n - 512]);
                else if (n < 4608)  hhpF[n - 2560] = av[i];
            }
        }
        __syncthreads();
        // (c) e-scores: 4 threads per p
        if (tid < 784) {
            int p = tid >> 2, q = tid & 3;
            const ushort* row = a.att1B + ((size_t)(b * PP + p)) * 512 + q * 128;
            float e = 0.f;
            for (int kk = 0; kk < 16; ++kk) {
                bf16x8 rv = *(const bf16x8*)(row + kk * 8);
                int kb = q * 128 + kk * 8;
                #pragma unroll
                for (int j = 0; j < 8; ++j) {
                    float v = bf2f((ushort)rv[j]) + att2F[kb + j];
                    e += (v > 0.f ? v : 0.f) * wfS[kb + j];
                }
            }
            e += __shfl_xor(e, 1); e += __shfl_xor(e, 2);
            if (q == 0) esS[p] = e;
        }
        __syncthreads();
        // (d) softmax over 196
        if (tid < 256) red[tid] = (tid < PP) ? esS[tid] : -3.4e38f;
        __syncthreads();
        for (int s = 128; s; s >>= 1) { if (tid < s) red[tid] = fmaxf(red[tid], red[tid + s]); __syncthreads(); }
        float smx = red[0];
        __syncthreads();
        float sev = 0.f;
        if (tid < 256) { sev = (tid < PP) ? __expf(esS[tid] - smx) : 0.f; red[tid] = sev; }
        __syncthreads();
        for (int s = 128; s; s >>= 1) { if (tid < s) red[tid] += red[tid + s]; __syncthreads(); }
        float sinv = 1.f / red[0];
        if (tid < PP) {
            float al = sev * sinv;
            alphaS[tid] = al;
            a.alpha_out[((size_t)b * TT + t) * PP + tid] = msk ? al : 0.f;
        }
        __syncthreads();
        // (e) awe = gate * (alpha @ enc_b), packed f16 pairs
        {
            const uint* pp = a.encU + ((size_t)b * PP) * 1024 + tid;
            float s0 = 0.f, s1 = 0.f;
            #pragma unroll 7
            for (int p = 0; p < PP; ++p) {
                uint vv = pp[(size_t)p * 1024];
                float al = alphaS[p];
                s0 += al * __uint_as_float(vv << 16);
                s1 += al * __uint_as_float(vv & 0xffff0000u);
            }
            float g0 = s0 * gateF[2 * tid], g1 = s1 * gateF[2 * tid + 1];
            awepk[tid] = pk2(g0, g1);
        }
        __syncthreads();
        // (f) gates GEMV: awe @ W_ih[512:2560] + bih + bhh + hhp + xpre
        {
            float g0 = 0.f, g1 = 0.f;
            #pragma unroll 4
            for (int k2 = 0; k2 < 1024; ++k2) {
                uint xp = awepk[k2];
                const uint* wr = a.WihPK + (size_t)k2 * 2048 + tid;
                g0 = dot2(wr[0],    xp, g0);
                g1 = dot2(wr[1024], xp, g1);
            }
            const float* xp = a.xpre + ((size_t)t * BB + b) * 2048;
            int n0 = tid, n1 = tid + 1024;
            xg[n0] = g0 + a.bih[n0] + a.bhh[n0] + hhpF[n0] + xp[n0];
            xg[n1] = g1 + a.bih[n1] + a.bhh[n1] + hhpF[n1] + xp[n1];
        }
        __syncthreads();
        // (g) LSTM pointwise
        if (tid < 512) {
            int d = tid;
            float gi = sigm(xg[d]), gf = sigm(xg[512 + d]);
            float gg = tanh_f(xg[1024 + d]), go = sigm(xg[1536 + d]);
            float cn = gf * cF[d] + gi * gg;
            cF[d] = msk ? cn : cF[d];
            att2F[d] = go * tanh_f(cn);   // hs
        }
        __syncthreads();
        // (h) sims = hs @ memB^T : 8 threads per m
        {
            int mm = tid >> 3, q = tid & 7;
            const float* r = a.memB + (size_t)mm * 512 + q * 64;
            const float* hsp = att2F + q * 64;
            float s = 0.f;
            #pragma unroll
            for (int d = 0; d < 64; d += 4) {
                float4 rv = *(const float4*)(r + d);
                s += rv.x * hsp[d] + rv.y * hsp[d + 1] + rv.z * hsp[d + 2] + rv.w * hsp[d + 3];
            }
            s += __shfl_xor(s, 1); s += __shfl_xor(s, 2); s += __shfl_xor(s, 4);
            if (q == 0) simsS[mm] = s;
        }
        __syncthreads();
        // (i) softmax over 128
        if (tid < 256) red[tid] = (tid < 128) ? simsS[tid] : -3.4e38f;
        __syncthreads();
        for (int s = 128; s; s >>= 1) { if (tid < s) red[tid] = fmaxf(red[tid], red[tid + s]); __syncthreads(); }
        float mmx = red[0];
        __syncthreads();
        float mev = 0.f;
        if (tid < 256) { mev = (tid < 128) ? __expf(simsS[tid] - mmx) : 0.f; red[tid] = mev; }
        __syncthreads();
        for (int s = 128; s; s >>= 1) { if (tid < s) red[tid] += red[tid + s]; __syncthreads(); }
        if (tid < 128) psS[tid] = mev / red[0];
        __syncthreads();
        // (j) h_new = hs + ps @ memB ; hist + masked carry
        if (tid < 512) {
            int d = tid;
            float s = 0.f;
            #pragma unroll 4
            for (int m = 0; m < 128; ++m) s += psS[m] * a.memB[(size_t)m * 512 + d];
            float hn = att2F[d] + s;
            a.histB[((size_t)t * BB + b) * 512 + d] = f2bf(hn);
            hF[d] = msk ? hn : hF[d];
        }
        __syncthreads();
        if (tid < 256) hpk[tid] = pk2(hF[2 * tid], hF[2 * tid + 1]);
        __syncthreads();
    }
}

// batched preds: hist(21*64 x 512) @ WfcT^T + bfc, masked. grid (40, 21)
__global__ __launch_bounds__(256) void k_preds_batch(const ushort* __restrict__ histB,
        const ushort* __restrict__ WfcT, const float* __restrict__ bfc,
        const int* __restrict__ lens, float* __restrict__ out) {
    __shared__ alignas(16) ushort As[64 * 64];
    __shared__ alignas(16) ushort Bs[256 * 64];
    const int n0 = blockIdx.x * 256;
    const int t = blockIdx.y;
    const ushort* A = histB + (size_t)t * BB * 512;
    const int tid = threadIdx.x, wid = tid >> 6, lane = tid & 63;
    f32x4 acc[4][4] = {};
    for (int k0 = 0; k0 < 512; k0 += 64) {
        #pragma unroll
        for (int p = 0; p < 2; ++p) {
            int c = p * 256 + tid;
            int r = c >> 3, cc = c & 7;
            float4 v = *(const float4*)(A + r * 512 + k0 + cc * 8);
            *(float4*)(As + r * 64 + ((cc ^ (r & 7)) * 8)) = v;
        }
        #pragma unroll
        for (int p = 0; p < 8; ++p) {
            int c = p * 256 + tid;
            int r = c >> 3, cc = c & 7;
            float4 v = *(const float4*)(WfcT + (size_t)(n0 + r) * 512 + k0 + cc * 8);
            *(float4*)(Bs + r * 64 + ((cc ^ (r & 7)) * 8)) = v;
        }
        __syncthreads();
        #pragma unroll
        for (int kk = 0; kk < 2; ++kk) {
            int ci = kk * 4 + (lane >> 4);
            bf16x8 afrag[4], bfrag[4];
            #pragma unroll
            for (int m = 0; m < 4; ++m) {
                int row = m * 16 + (lane & 15);
                afrag[m] = *(const bf16x8*)(As + row * 64 + ((ci ^ (row & 7)) * 8));
            }
            #pragma unroll
            for (int n = 0; n < 4; ++n) {
                int col = wid * 64 + n * 16 + (lane & 15);
                bfrag[n] = *(const bf16x8*)(Bs + col * 64 + ((ci ^ (col & 7)) * 8));
            }
            #pragma unroll
            for (int m = 0; m < 4; ++m)
                #pragma unroll
                for (int n = 0; n < 4; ++n)
                    acc[m][n] = __builtin_amdgcn_mfma_f32_16x16x32_bf16(afrag[m], bfrag[n], acc[m][n], 0, 0, 0);
        }
        __syncthreads();
    }
    #pragma unroll
    for (int m = 0; m < 4; ++m) {
        int rb = m * 16 + (lane >> 4) * 4;
        #pragma unroll
        for (int n = 0; n < 4; ++n) {
            int col = n0 + wid * 64 + n * 16 + (lane & 15);
            if (col < VV) {
                float bv = bfc[col];
                #pragma unroll
                for (int r = 0; r < 4; ++r) {
                    int b = rb + r;
                    bool msk = t < (lens[b] - 1);
                    out[((size_t)b * TT + t) * VV + col] = msk ? (acc[m][n][r] + bv) : 0.f;
                }
            }
        }
    }
}

// ---------------- launch ----------------

extern "C" void kernel_launch(void* const* d_in, const int* in_sizes, int n_in,
                              void* d_out, int out_size, void* d_ws, size_t ws_size,
                              hipStream_t stream) {
    const float* enc     = (const float*)d_in[0];
    const int*   caps    = (const int*)d_in[1];
    const int*   lens    = (const int*)d_in[2];
    const float* emb     = (const float*)d_in[3];
    const float* W_enc   = (const float*)d_in[4];
    const float* b_enc   = (const float*)d_in[5];
    const float* W_dec   = (const float*)d_in[6];
    const float* b_dec   = (const float*)d_in[7];
    const float* W_full  = (const float*)d_in[8];
    const float* W_inith = (const float*)d_in[10];
    const float* b_inith = (const float*)d_in[11];
    const float* W_initc = (const float*)d_in[12];
    const float* b_initc = (const float*)d_in[13];
    const float* W_beta  = (const float*)d_in[14];
    const float* b_beta  = (const float*)d_in[15];
    const float* W_ih    = (const float*)d_in[16];
    const float* b_ih    = (const float*)d_in[17];
    const float* W_hh    = (const float*)d_in[18];
    const float* b_hh    = (const float*)d_in[19];
    const float* memB    = (const float*)d_in[20];
    const float* W_fc    = (const float*)d_in[21];
    const float* b_fc    = (const float*)d_in[22];

    float* out = (float*)d_out;
    float* preds_out  = out;
    float* declen_out = out + (size_t)BB * TT * VV;
    float* alpha_out  = declen_out + BB;

    float* ws    = (float*)d_ws;
    ushort* att1B = (ushort*)ws;  ws += (size_t)12544 * 512 / 2;
    float* h0    = ws;  ws += BB * DECD;
    float* c0    = ws;  ws += BB * DECD;
    float* xpre  = ws;  ws += (size_t)TT * BB * 2048;
    ushort* histB = (ushort*)ws; ws += (size_t)TT * BB * DECD / 2;
    ushort* encB  = (ushort*)ws; ws += (size_t)12544 * 2048 / 2;
    ushort* WencT = (ushort*)ws; ws += (size_t)512 * 2048 / 2;
    ushort* WfcT  = (ushort*)ws; ws += (size_t)10240 * 512 / 2;
    ushort* WihT0 = (ushort*)ws; ws += (size_t)2048 * 512 / 2;
    uint*  WcatPK = (uint*)ws;   ws += (size_t)256 * 5120;
    uint*  WihPK  = (uint*)ws;   ws += (size_t)1024 * 2048;
    // setup-only aliases (dead before their overlapping regions are written)
    float* mean  = (float*)att1B;   // dead before k_att1n writes att1B
    float* ipart = xpre;            // dead before k_xpre writes xpre

    k_cvt<<<(12544 * 2048 / 4 + 255) / 256, 256, 0, stream>>>(enc, encB, 12544 * 2048 / 4);
    k_mean16<<<256, 256, 0, stream>>>(encB, mean);
    k_ipart<<<dim3(8, 4, 2), 256, 0, stream>>>(mean, W_inith, W_initc, ipart);
    k_ifin<<<256, 256, 0, stream>>>(ipart, b_inith, b_initc, h0, c0);
    k_declen<<<1, 64, 0, stream>>>(lens, declen_out);
    k_tcvt_all<<<1768, 256, 0, stream>>>(W_enc, W_ih, W_fc, WencT, WihT0, WfcT);
    k_att1n<<<dim3(2, 196), 256, 0, stream>>>(encB, WencT, b_enc, att1B);
    k_xpre<<<dim3(8, TT), 256, 0, stream>>>(emb, caps, WihT0, xpre);
    k_packcat<<<(256 * 5120) / 256, 256, 0, stream>>>(W_dec, W_beta, W_hh, WcatPK);
    k_packih<<<(1024 * 2048) / 256, 256, 0, stream>>>(W_ih, WihPK);

    MArgs ma;
    ma.lens = lens; ma.h0 = h0; ma.c0 = c0;
    ma.WcatPK = WcatPK; ma.bd = b_dec; ma.bb = b_beta;
    ma.att1B = att1B; ma.Wf = W_full; ma.encU = (const uint*)encB;
    ma.WihPK = WihPK; ma.xpre = xpre;
    ma.bih = b_ih; ma.bhh = b_hh; ma.memB = memB;
    ma.histB = histB; ma.alpha_out = alpha_out;
    k_mega<<<BB, 1024, 0, stream>>>(ma);

    k_preds_batch<<<dim3(40, TT), 256, 0, stream>>>(histB, WfcT, b_fc, lens, preds_out);
}

// Round 12
// 4173.380 us; speedup vs baseline: 1.1831x; 1.0094x over previous
//
#include <hip/hip_runtime.h>

#define BB   64
#define PP   196
#define ENCD 2048
#define DECD 512
#define VV   10000
#define TT   21

typedef __attribute__((ext_vector_type(8))) short bf16x8;
typedef __attribute__((ext_vector_type(4))) float f32x4;
typedef __fp16 f16x2 __attribute__((ext_vector_type(2)));

__device__ __forceinline__ float sigm(float x)   { return 1.f / (1.f + __expf(-x)); }
__device__ __forceinline__ float tanh_f(float x) { return 1.f - 2.f / (1.f + __expf(2.f * x)); }
__device__ __forceinline__ ushort f2bf(float x) {
    unsigned u = __float_as_uint(x);
    unsigned r = (u + 0x7FFFu + ((u >> 16) & 1u)) >> 16;
    return (ushort)r;
}
__device__ __forceinline__ float bf2f(ushort u) {
    return __uint_as_float(((unsigned)u) << 16);
}
__device__ __forceinline__ uint pk2(float a, float b) {
    f16x2 p = __builtin_amdgcn_cvt_pkrtz(a, b);
    return *(uint*)&p;
}
__device__ __forceinline__ float dot2(uint w, uint x, float c) {
#if __has_builtin(__builtin_amdgcn_fdot2)
    return __builtin_amdgcn_fdot2(*(f16x2*)&w, *(f16x2*)&x, c, false);
#else
    f16x2 a = *(f16x2*)&w, b = *(f16x2*)&x;
    return c + (float)a[0] * (float)b[0] + (float)a[1] * (float)b[1];
#endif
}

// ---------------- setup kernels ----------------

__global__ void k_cvt(const float* __restrict__ in, ushort* __restrict__ out, int n4) {
    int i = blockIdx.x * 256 + threadIdx.x;
    if (i >= n4) return;
    float4 v = ((const float4*)in)[i];
    ushort4 o; o.x = f2bf(v.x); o.y = f2bf(v.y); o.z = f2bf(v.z); o.w = f2bf(v.w);
    ((ushort4*)out)[i] = o;
}

__global__ void k_mean16(const ushort* __restrict__ encB, float* __restrict__ mean) {
    int idx = blockIdx.x * 256 + threadIdx.x;
    int b = idx >> 10, e2 = idx & 1023;
    const uint* p = (const uint*)encB + (size_t)b * PP * 1024 + e2;
    float s0 = 0.f, s1 = 0.f;
    #pragma unroll 7
    for (int i = 0; i < PP; ++i) {
        uint v = p[(size_t)i * 1024];
        s0 += __uint_as_float(v << 16);
        s1 += __uint_as_float(v & 0xffff0000u);
    }
    mean[b * 2048 + e2 * 2]     = s0 * (1.f / 196.f);
    mean[b * 2048 + e2 * 2 + 1] = s1 * (1.f / 196.f);
}

__global__ __launch_bounds__(256) void k_ipart(const float* __restrict__ mean,
        const float* __restrict__ Wh, const float* __restrict__ Wc,
        float* __restrict__ ipart) {
    __shared__ alignas(16) float As[32][68];
    __shared__ alignas(16) float Bs[32][68];
    const int n0 = blockIdx.x * 64;
    const int kc = blockIdx.y;
    const int mat = blockIdx.z;
    const float* Bp = mat ? Wc : Wh;
    const int tid = threadIdx.x, tx = tid & 15, ty = tid >> 4;
    float acc[4][4] = {};
    for (int k0 = 0; k0 < 512; k0 += 32) {
        #pragma unroll
        for (int p = 0; p < 2; ++p) {
            int c = p * 256 + tid;
            int m = c >> 3, k4 = (c & 7) * 4;
            float4 v = *(const float4*)(mean + m * 2048 + kc * 512 + k0 + k4);
            As[k4 + 0][m] = v.x; As[k4 + 1][m] = v.y; As[k4 + 2][m] = v.z; As[k4 + 3][m] = v.w;
            int kb = c >> 4, n4 = (c & 15) * 4;
            float4 w = *(const float4*)(Bp + (size_t)(kc * 512 + k0 + kb) * 512 + n0 + n4);
            *(float4*)&Bs[kb][n4] = w;
        }
        __syncthreads();
        #pragma unroll 8
        for (int k = 0; k < 32; ++k) {
            float4 a = *(const float4*)&As[k][ty * 4];
            float4 b = *(const float4*)&Bs[k][tx * 4];
            float av[4] = {a.x, a.y, a.z, a.w}, bv[4] = {b.x, b.y, b.z, b.w};
            #pragma unroll
            for (int i = 0; i < 4; ++i)
                #pragma unroll
                for (int j = 0; j < 4; ++j) acc[i][j] += av[i] * bv[j];
        }
        __syncthreads();
    }
    #pragma unroll
    for (int i = 0; i < 4; ++i) {
        int m = ty * 4 + i;
        #pragma unroll
        for (int j = 0; j < 4; ++j) {
            int n = n0 + tx * 4 + j;
            ipart[((size_t)(mat * 4 + kc) * BB + m) * 512 + n] = acc[i][j];
        }
    }
}

__global__ void k_ifin(const float* __restrict__ ipart,
                       const float* __restrict__ bh, const float* __restrict__ bc,
                       float* __restrict__ h0, float* __restrict__ c0) {
    int idx = blockIdx.x * 256 + threadIdx.x;
    int mat = idx >> 15, rem = idx & 32767;
    int b = rem >> 9, d = rem & 511;
    float s = 0.f;
    #pragma unroll
    for (int kc = 0; kc < 4; ++kc) s += ipart[((size_t)(mat * 4 + kc) * BB + b) * 512 + d];
    if (mat) c0[rem] = s + bc[d];
    else     h0[rem] = s + bh[d];
}

// transposes: Wenc -> WencT[512][2048]; Wih rows 0..511 -> WihT0[2048][512]; Wfc -> WfcT[10240][512]
__global__ __launch_bounds__(256) void k_tcvt_all(
        const float* __restrict__ Wenc, const float* __restrict__ Wih,
        const float* __restrict__ Wfc,
        ushort* __restrict__ WencT, ushort* __restrict__ WihT0,
        ushort* __restrict__ WfcT) {
    __shared__ float lds[64 * 65];
    int l = blockIdx.x;
    const float* in; ushort* out; int K, N, KT;
    if (l < 256)      { in = Wenc; out = WencT; K = 2048; N = 512;   KT = 32; }
    else if (l < 512) { l -= 256; in = Wih;  out = WihT0; K = 512; N = 2048;  KT = 8; }
    else              { l -= 512; in = Wfc;  out = WfcT;  K = 512; N = 10000; KT = 8; }
    const int k0 = (l % KT) * 64, n0 = (l / KT) * 64;
    const int tid = threadIdx.x;
    for (int i = tid; i < 4096; i += 256) {
        int kk = i >> 6, nn = i & 63;
        float v = 0.f;
        if (n0 + nn < N) v = in[(size_t)(k0 + kk) * N + n0 + nn];
        lds[nn * 65 + kk] = v;
    }
    __syncthreads();
    for (int i = tid; i < 4096; i += 256) {
        int nn = i >> 6, kk = i & 63;
        out[(size_t)(n0 + nn) * K + k0 + kk] = f2bf(lds[nn * 65 + kk]);
    }
}

// WcatPK4[k2][q] uint4: quad of f16-pair cols n=4q..4q+3 of [W_dec|W_beta|W_hh], q<1280 (pad)
__global__ void k_packcat(const float* __restrict__ Wd, const float* __restrict__ Wb,
                          const float* __restrict__ Wh, uint4* __restrict__ out) {
    int idx = blockIdx.x * 256 + threadIdx.x;   // 256*1280
    int k2 = idx / 1280, q = idx % 1280;
    int k = k2 * 2;
    uint r[4];
    #pragma unroll
    for (int j = 0; j < 4; ++j) {
        int n = q * 4 + j;
        float a = 0.f, b2 = 0.f;
        if (n < 512)       { a = Wd[(size_t)k * 512 + n];            b2 = Wd[(size_t)(k + 1) * 512 + n]; }
        else if (n < 2560) { int nn = n - 512;  a = Wb[(size_t)k * 2048 + nn]; b2 = Wb[(size_t)(k + 1) * 2048 + nn]; }
        else if (n < 4608) { int nn = n - 2560; a = Wh[(size_t)k * 2048 + nn]; b2 = Wh[(size_t)(k + 1) * 2048 + nn]; }
        r[j] = pk2(a, b2);
    }
    out[idx] = make_uint4(r[0], r[1], r[2], r[3]);
}

// WihPK4[k2][q] uint4: quad of f16-pair cols n=4q..4q+3 of W_ih rows 512..2559; [1024][512]
__global__ void k_packih(const float* __restrict__ Wih, uint4* __restrict__ out) {
    int idx = blockIdx.x * 256 + threadIdx.x;   // 1024*512
    int k2 = idx >> 9, q = idx & 511;
    int r0 = 512 + k2 * 2;
    uint r[4];
    #pragma unroll
    for (int j = 0; j < 4; ++j) {
        int n = q * 4 + j;
        r[j] = pk2(Wih[(size_t)r0 * 2048 + n], Wih[(size_t)(r0 + 1) * 2048 + n]);
    }
    out[idx] = make_uint4(r[0], r[1], r[2], r[3]);
}

// att1B[12544][512] bf16 = bf16(encB @ WencT^T + bias). grid (2, 196)
__global__ __launch_bounds__(256) void k_att1n(const ushort* __restrict__ A,
        const ushort* __restrict__ Bt, const float* __restrict__ bias,
        ushort* __restrict__ C) {
    __shared__ alignas(16) ushort As[64 * 64];
    __shared__ alignas(16) ushort Bs[256 * 64];
    const int n0 = blockIdx.x * 256;
    const int m0 = blockIdx.y * 64;
    const int tid = threadIdx.x, wid = tid >> 6, lane = tid & 63;
    f32x4 acc[4][4] = {};
    for (int k0 = 0; k0 < 2048; k0 += 64) {
        #pragma unroll
        for (int p = 0; p < 2; ++p) {
            int c = p * 256 + tid;
            int r = c >> 3, cc = c & 7;
            float4 v = *(const float4*)(A + (size_t)(m0 + r) * 2048 + k0 + cc * 8);
            *(float4*)(As + r * 64 + ((cc ^ (r & 7)) * 8)) = v;
        }
        #pragma unroll
        for (int p = 0; p < 8; ++p) {
            int c = p * 256 + tid;
            int r = c >> 3, cc = c & 7;
            float4 v = *(const float4*)(Bt + (size_t)(n0 + r) * 2048 + k0 + cc * 8);
            *(float4*)(Bs + r * 64 + ((cc ^ (r & 7)) * 8)) = v;
        }
        __syncthreads();
        #pragma unroll
        for (int kk = 0; kk < 2; ++kk) {
            int ci = kk * 4 + (lane >> 4);
            bf16x8 afrag[4], bfrag[4];
            #pragma unroll
            for (int m = 0; m < 4; ++m) {
                int row = m * 16 + (lane & 15);
                afrag[m] = *(const bf16x8*)(As + row * 64 + ((ci ^ (row & 7)) * 8));
            }
            #pragma unroll
            for (int n = 0; n < 4; ++n) {
                int col = wid * 64 + n * 16 + (lane & 15);
                bfrag[n] = *(const bf16x8*)(Bs + col * 64 + ((ci ^ (col & 7)) * 8));
            }
            #pragma unroll
            for (int m = 0; m < 4; ++m)
                #pragma unroll
                for (int n = 0; n < 4; ++n)
                    acc[m][n] = __builtin_amdgcn_mfma_f32_16x16x32_bf16(afrag[m], bfrag[n], acc[m][n], 0, 0, 0);
        }
        __syncthreads();
    }
    #pragma unroll
    for (int m = 0; m < 4; ++m) {
        int rb = m0 + m * 16 + (lane >> 4) * 4;
        #pragma unroll
        for (int n = 0; n < 4; ++n) {
            int col = n0 + wid * 64 + n * 16 + (lane & 15);
            float bv = bias[col];
            #pragma unroll
            for (int r = 0; r < 4; ++r)
                C[(size_t)(rb + r) * 512 + col] = f2bf(acc[m][n][r] + bv);
        }
    }
}

// xpre[t][b][2048] = emb[caps[b,t]] @ W_ih[0:512]. grid (8, 21). B = WihT0 [2048][512]
__global__ __launch_bounds__(256) void k_xpre(const float* __restrict__ emb,
        const int* __restrict__ caps, const ushort* __restrict__ WihT0,
        float* __restrict__ xpre) {
    __shared__ alignas(16) ushort As[64 * 64];
    __shared__ alignas(16) ushort Bs[256 * 64];
    __shared__ int capsh[64];
    const int n0 = blockIdx.x * 256;
    const int t = blockIdx.y;
    const int tid = threadIdx.x, wid = tid >> 6, lane = tid & 63;
    if (tid < 64) capsh[tid] = caps[tid * 22 + t];
    __syncthreads();
    f32x4 acc[4][4] = {};
    for (int k0 = 0; k0 < 512; k0 += 64) {
        #pragma unroll
        for (int p = 0; p < 2; ++p) {
            int c = p * 256 + tid;
            int r = c >> 3, cc = c & 7;
            const float* er = emb + (size_t)capsh[r] * 512 + k0 + cc * 8;
            float4 v0 = *(const float4*)er;
            float4 v1 = *(const float4*)(er + 4);
            union { float4 f4; ushort u[8]; } pk;
            pk.u[0] = f2bf(v0.x); pk.u[1] = f2bf(v0.y); pk.u[2] = f2bf(v0.z); pk.u[3] = f2bf(v0.w);
            pk.u[4] = f2bf(v1.x); pk.u[5] = f2bf(v1.y); pk.u[6] = f2bf(v1.z); pk.u[7] = f2bf(v1.w);
            *(float4*)(As + r * 64 + ((cc ^ (r & 7)) * 8)) = pk.f4;
        }
        #pragma unroll
        for (int p = 0; p < 8; ++p) {
            int c = p * 256 + tid;
            int r = c >> 3, cc = c & 7;
            float4 v = *(const float4*)(WihT0 + (size_t)(n0 + r) * 512 + k0 + cc * 8);
            *(float4*)(Bs + r * 64 + ((cc ^ (r & 7)) * 8)) = v;
        }
        __syncthreads();
        #pragma unroll
        for (int kk = 0; kk < 2; ++kk) {
            int ci = kk * 4 + (lane >> 4);
            bf16x8 afrag[4], bfrag[4];
            #pragma unroll
            for (int m = 0; m < 4; ++m) {
                int row = m * 16 + (lane & 15);
                afrag[m] = *(const bf16x8*)(As + row * 64 + ((ci ^ (row & 7)) * 8));
            }
            #pragma unroll
            for (int n = 0; n < 4; ++n) {
                int col = wid * 64 + n * 16 + (lane & 15);
                bfrag[n] = *(const bf16x8*)(Bs + col * 64 + ((ci ^ (col & 7)) * 8));
            }
            #pragma unroll
            for (int m = 0; m < 4; ++m)
                #pragma unroll
                for (int n = 0; n < 4; ++n)
                    acc[m][n] = __builtin_amdgcn_mfma_f32_16x16x32_bf16(afrag[m], bfrag[n], acc[m][n], 0, 0, 0);
        }
        __syncthreads();
    }
    #pragma unroll
    for (int m = 0; m < 4; ++m) {
        int rb = m * 16 + (lane >> 4) * 4;
        #pragma unroll
        for (int n = 0; n < 4; ++n) {
            int col = n0 + wid * 64 + n * 16 + (lane & 15);
            #pragma unroll
            for (int r = 0; r < 4; ++r)
                xpre[((size_t)t * BB + rb + r) * 2048 + col] = acc[m][n][r];
        }
    }
}

__global__ void k_declen(const int* __restrict__ lens, float* __restrict__ out) {
    int b = threadIdx.x;
    if (b < BB) out[b] = (float)(lens[b] - 1);
}

// ---------------- persistent per-batch megakernel: zero cross-block deps ----------------

struct MArgs {
    const int* lens; const float* h0; const float* c0;
    const uint4* WcatPK; const float* bd; const float* bb;
    const ushort* att1B; const float* Wf; const uint* encU;
    const uint4* WihPK; const float* xpre;
    const float* bih; const float* bhh; const float* memB;
    ushort* histB; float* alpha_out;
};

__global__ __launch_bounds__(1024) void k_mega(MArgs a) {
    __shared__ uint hpk[256];
    __shared__ float att2F[512];        // reused as hs[] after escore
    __shared__ float gateF[2048];
    __shared__ float hhpF[2048];
    __shared__ float xg[2048];
    __shared__ uint awepk[1024];
    __shared__ float cF[512], hF[512];
    __shared__ float esS[200], alphaS[200], wfS[512], red[256], simsS[128], psS[128];
    const int b = blockIdx.x, tid = threadIdx.x;
    const int lenb = a.lens[b];

    if (tid < 512) {
        hF[tid]  = a.h0[b * 512 + tid];
        cF[tid]  = a.c0[b * 512 + tid];
        wfS[tid] = a.Wf[tid];
    }
    __syncthreads();
    if (tid < 256) hpk[tid] = pk2(hF[2 * tid], hF[2 * tid + 1]);
    __syncthreads();

    for (int t = 0; t < TT; ++t) {
        const bool msk = t < lenb - 1;
        // (b) fused GEMV: [att2|gate|hhp] = h @ [W_dec|W_beta|W_hh], uint4 quads
        {
            float a0 = 0.f, a1 = 0.f, a2 = 0.f, a3 = 0.f;
            float b0 = 0.f, b1 = 0.f, b2 = 0.f, b3 = 0.f;
            #pragma unroll 8
            for (int k2 = 0; k2 < 256; ++k2) {
                uint xp = hpk[k2];
                uint4 w = a.WcatPK[(size_t)k2 * 1280 + tid];
                a0 = dot2(w.x, xp, a0); a1 = dot2(w.y, xp, a1);
                a2 = dot2(w.z, xp, a2); a3 = dot2(w.w, xp, a3);
                if (tid < 256) {   // wave-uniform (waves 0-3)
                    uint4 w2 = a.WcatPK[(size_t)k2 * 1280 + 1024 + tid];
                    b0 = dot2(w2.x, xp, b0); b1 = dot2(w2.y, xp, b1);
                    b2 = dot2(w2.z, xp, b2); b3 = dot2(w2.w, xp, b3);
                }
            }
            float va[4] = {a0, a1, a2, a3};
            float vb[4] = {b0, b1, b2, b3};
            int n = tid * 4;
            #pragma unroll
            for (int j = 0; j < 4; ++j) {
                int nn = n + j;
                if (nn < 512)       att2F[nn] = va[j] + a.bd[nn];
                else if (nn < 2560) gateF[nn - 512] = sigm(va[j] + a.bb[nn - 512]);
                else if (nn < 4608) hhpF[nn - 2560] = va[j];
            }
            if (tid < 256) {
                int n2 = (1024 + tid) * 4;   // 4096..5119 -> all in hhp range (<4608) or pad
                #pragma unroll
                for (int j = 0; j < 4; ++j) {
                    int nn = n2 + j;
                    if (nn < 4608) hhpF[nn - 2560] = vb[j];
                }
            }
        }
        __syncthreads();
        // (c) e-scores: 4 threads per p
        if (tid < 784) {
            int p = tid >> 2, q = tid & 3;
            const ushort* row = a.att1B + ((size_t)(b * PP + p)) * 512 + q * 128;
            float e = 0.f;
            for (int kk = 0; kk < 16; ++kk) {
                bf16x8 rv = *(const bf16x8*)(row + kk * 8);
                int kb = q * 128 + kk * 8;
                #pragma unroll
                for (int j = 0; j < 8; ++j) {
                    float v = bf2f((ushort)rv[j]) + att2F[kb + j];
                    e += (v > 0.f ? v : 0.f) * wfS[kb + j];
                }
            }
            e += __shfl_xor(e, 1); e += __shfl_xor(e, 2);
            if (q == 0) esS[p] = e;
        }
        __syncthreads();
        // (d) softmax over 196
        if (tid < 256) red[tid] = (tid < PP) ? esS[tid] : -3.4e38f;
        __syncthreads();
        for (int s = 128; s; s >>= 1) { if (tid < s) red[tid] = fmaxf(red[tid], red[tid + s]); __syncthreads(); }
        float smx = red[0];
        __syncthreads();
        float sev = 0.f;
        if (tid < 256) { sev = (tid < PP) ? __expf(esS[tid] - smx) : 0.f; red[tid] = sev; }
        __syncthreads();
        for (int s = 128; s; s >>= 1) { if (tid < s) red[tid] += red[tid + s]; __syncthreads(); }
        float sinv = 1.f / red[0];
        if (tid < PP) {
            float al = sev * sinv;
            alphaS[tid] = al;
            a.alpha_out[((size_t)b * TT + t) * PP + tid] = msk ? al : 0.f;
        }
        __syncthreads();
        // (e) awe = gate * (alpha @ enc_b), packed f16 pairs
        {
            const uint* pp = a.encU + ((size_t)b * PP) * 1024 + tid;
            float s0 = 0.f, s1 = 0.f;
            #pragma unroll 14
            for (int p = 0; p < PP; ++p) {
                uint vv = pp[(size_t)p * 1024];
                float al = alphaS[p];
                s0 += al * __uint_as_float(vv << 16);
                s1 += al * __uint_as_float(vv & 0xffff0000u);
            }
            float g0 = s0 * gateF[2 * tid], g1 = s1 * gateF[2 * tid + 1];
            awepk[tid] = pk2(g0, g1);
        }
        __syncthreads();
        // (f) gates GEMV: awe @ W_ih[512:2560], K split in 2 halves across thread groups
        {
            const int kh = tid >> 9;        // 0/1: K-half
            const int q  = tid & 511;       // quad index, n = 4q
            float g0 = 0.f, g1 = 0.f, g2 = 0.f, g3 = 0.f;
            const uint4* W4 = a.WihPK + (size_t)kh * 512 * 512;
            #pragma unroll 8
            for (int i = 0; i < 512; ++i) {
                uint xp = awepk[kh * 512 + i];
                uint4 w = W4[(size_t)i * 512 + q];
                g0 = dot2(w.x, xp, g0); g1 = dot2(w.y, xp, g1);
                g2 = dot2(w.z, xp, g2); g3 = dot2(w.w, xp, g3);
            }
            if (kh == 1) {
                int n = q * 4;
                xg[n] = g0; xg[n + 1] = g1; xg[n + 2] = g2; xg[n + 3] = g3;
            }
            __syncthreads();
            if (kh == 0) {
                const float* xp_ = a.xpre + ((size_t)t * BB + b) * 2048;
                int n = q * 4;
                float gg[4] = {g0, g1, g2, g3};
                #pragma unroll
                for (int j = 0; j < 4; ++j) {
                    int nn = n + j;
                    xg[nn] = gg[j] + xg[nn] + a.bih[nn] + a.bhh[nn] + hhpF[nn] + xp_[nn];
                }
            }
        }
        __syncthreads();
        // (g) LSTM pointwise
        if (tid < 512) {
            int d = tid;
            float gi = sigm(xg[d]), gf = sigm(xg[512 + d]);
            float gg = tanh_f(xg[1024 + d]), go = sigm(xg[1536 + d]);
            float cn = gf * cF[d] + gi * gg;
            cF[d] = msk ? cn : cF[d];
            att2F[d] = go * tanh_f(cn);   // hs
        }
        __syncthreads();
        // (h) sims = hs @ memB^T : 8 threads per m
        {
            int mm = tid >> 3, q = tid & 7;
            const float* r = a.memB + (size_t)mm * 512 + q * 64;
            const float* hsp = att2F + q * 64;
            float s = 0.f;
            #pragma unroll
            for (int d = 0; d < 64; d += 4) {
                float4 rv = *(const float4*)(r + d);
                s += rv.x * hsp[d] + rv.y * hsp[d + 1] + rv.z * hsp[d + 2] + rv.w * hsp[d + 3];
            }
            s += __shfl_xor(s, 1); s += __shfl_xor(s, 2); s += __shfl_xor(s, 4);
            if (q == 0) simsS[mm] = s;
        }
        __syncthreads();
        // (i) softmax over 128
        if (tid < 256) red[tid] = (tid < 128) ? simsS[tid] : -3.4e38f;
        __syncthreads();
        for (int s = 128; s; s >>= 1) { if (tid < s) red[tid] = fmaxf(red[tid], red[tid + s]); __syncthreads(); }
        float mmx = red[0];
        __syncthreads();
        float mev = 0.f;
        if (tid < 256) { mev = (tid < 128) ? __expf(simsS[tid] - mmx) : 0.f; red[tid] = mev; }
        __syncthreads();
        for (int s = 128; s; s >>= 1) { if (tid < s) red[tid] += red[tid + s]; __syncthreads(); }
        if (tid < 128) psS[tid] = mev / red[0];
        __syncthreads();
        // (j) h_new = hs + ps @ memB ; hist + masked carry
        if (tid < 512) {
            int d = tid;
            float s = 0.f;
            #pragma unroll 8
            for (int m = 0; m < 128; ++m) s += psS[m] * a.memB[(size_t)m * 512 + d];
            float hn = att2F[d] + s;
            a.histB[((size_t)t * BB + b) * 512 + d] = f2bf(hn);
            hF[d] = msk ? hn : hF[d];
        }
        __syncthreads();
        if (tid < 256) hpk[tid] = pk2(hF[2 * tid], hF[2 * tid + 1]);
        __syncthreads();
    }
}

// batched preds: hist(21*64 x 512) @ WfcT^T + bfc, masked. grid (40, 21)
__global__ __launch_bounds__(256) void k_preds_batch(const ushort* __restrict__ histB,
        const ushort* __restrict__ WfcT, const float* __restrict__ bfc,
        const int* __restrict__ lens, float* __restrict__ out) {
    __shared__ alignas(16) ushort As[64 * 64];
    __shared__ alignas(16) ushort Bs[256 * 64];
    const int n0 = blockIdx.x * 256;
    const int t = blockIdx.y;
    const ushort* A = histB + (size_t)t * BB * 512;
    const int tid = threadIdx.x, wid = tid >> 6, lane = tid & 63;
    f32x4 acc[4][4] = {};
    for (int k0 = 0; k0 < 512; k0 += 64) {
        #pragma unroll
        for (int p = 0; p < 2; ++p) {
            int c = p * 256 + tid;
            int r = c >> 3, cc = c & 7;
            float4 v = *(const float4*)(A + r * 512 + k0 + cc * 8);
            *(float4*)(As + r * 64 + ((cc ^ (r & 7)) * 8)) = v;
        }
        #pragma unroll
        for (int p = 0; p < 8; ++p) {
            int c = p * 256 + tid;
            int r = c >> 3, cc = c & 7;
            float4 v = *(const float4*)(WfcT + (size_t)(n0 + r) * 512 + k0 + cc * 8);
            *(float4*)(Bs + r * 64 + ((cc ^ (r & 7)) * 8)) = v;
        }
        __syncthreads();
        #pragma unroll
        for (int kk = 0; kk < 2; ++kk) {
            int ci = kk * 4 + (lane >> 4);
            bf16x8 afrag[4], bfrag[4];
            #pragma unroll
            for (int m = 0; m < 4; ++m) {
                int row = m * 16 + (lane & 15);
                afrag[m] = *(const bf16x8*)(As + row * 64 + ((ci ^ (row & 7)) * 8));
            }
            #pragma unroll
            for (int n = 0; n < 4; ++n) {
                int col = wid * 64 + n * 16 + (lane & 15);
                bfrag[n] = *(const bf16x8*)(Bs + col * 64 + ((ci ^ (col & 7)) * 8));
            }
            #pragma unroll
            for (int m = 0; m < 4; ++m)
                #pragma unroll
                for (int n = 0; n < 4; ++n)
                    acc[m][n] = __builtin_amdgcn_mfma_f32_16x16x32_bf16(afrag[m], bfrag[n], acc[m][n], 0, 0, 0);
        }
        __syncthreads();
    }
    #pragma unroll
    for (int m = 0; m < 4; ++m) {
        int rb = m * 16 + (lane >> 4) * 4;
        #pragma unroll
        for (int n = 0; n < 4; ++n) {
            int col = n0 + wid * 64 + n * 16 + (lane & 15);
            if (col < VV) {
                float bv = bfc[col];
                #pragma unroll
                for (int r = 0; r < 4; ++r) {
                    int b = rb + r;
                    bool msk = t < (lens[b] - 1);
                    out[((size_t)b * TT + t) * VV + col] = msk ? (acc[m][n][r] + bv) : 0.f;
                }
            }
        }
    }
}

// ---------------- launch ----------------

extern "C" void kernel_launch(void* const* d_in, const int* in_sizes, int n_in,
                              void* d_out, int out_size, void* d_ws, size_t ws_size,
                              hipStream_t stream) {
    const float* enc     = (const float*)d_in[0];
    const int*   caps    = (const int*)d_in[1];
    const int*   lens    = (const int*)d_in[2];
    const float* emb     = (const float*)d_in[3];
    const float* W_enc   = (const float*)d_in[4];
    const float* b_enc   = (const float*)d_in[5];
    const float* W_dec   = (const float*)d_in[6];
    const float* b_dec   = (const float*)d_in[7];
    const float* W_full  = (const float*)d_in[8];
    const float* W_inith = (const float*)d_in[10];
    const float* b_inith = (const float*)d_in[11];
    const float* W_initc = (const float*)d_in[12];
    const float* b_initc = (const float*)d_in[13];
    const float* W_beta  = (const float*)d_in[14];
    const float* b_beta  = (const float*)d_in[15];
    const float* W_ih    = (const float*)d_in[16];
    const float* b_ih    = (const float*)d_in[17];
    const float* W_hh    = (const float*)d_in[18];
    const float* b_hh    = (const float*)d_in[19];
    const float* memB    = (const float*)d_in[20];
    const float* W_fc    = (const float*)d_in[21];
    const float* b_fc    = (const float*)d_in[22];

    float* out = (float*)d_out;
    float* preds_out  = out;
    float* declen_out = out + (size_t)BB * TT * VV;
    float* alpha_out  = declen_out + BB;

    float* ws    = (float*)d_ws;
    ushort* att1B = (ushort*)ws;  ws += (size_t)12544 * 512 / 2;
    float* h0    = ws;  ws += BB * DECD;
    float* c0    = ws;  ws += BB * DECD;
    float* xpre  = ws;  ws += (size_t)TT * BB * 2048;
    ushort* histB = (ushort*)ws; ws += (size_t)TT * BB * DECD / 2;
    ushort* encB  = (ushort*)ws; ws += (size_t)12544 * 2048 / 2;
    ushort* WencT = (ushort*)ws; ws += (size_t)512 * 2048 / 2;
    ushort* WfcT  = (ushort*)ws; ws += (size_t)10240 * 512 / 2;
    ushort* WihT0 = (ushort*)ws; ws += (size_t)2048 * 512 / 2;
    uint4* WcatPK = (uint4*)ws;  ws += (size_t)256 * 1280 * 4;
    uint4* WihPK  = (uint4*)ws;  ws += (size_t)1024 * 512 * 4;
    // setup-only aliases (dead before their overlapping regions are written)
    float* mean  = (float*)att1B;   // dead before k_att1n writes att1B
    float* ipart = xpre;            // dead before k_xpre writes xpre

    k_cvt<<<(12544 * 2048 / 4 + 255) / 256, 256, 0, stream>>>(enc, encB, 12544 * 2048 / 4);
    k_mean16<<<256, 256, 0, stream>>>(encB, mean);
    k_ipart<<<dim3(8, 4, 2), 256, 0, stream>>>(mean, W_inith, W_initc, ipart);
    k_ifin<<<256, 256, 0, stream>>>(ipart, b_inith, b_initc, h0, c0);
    k_declen<<<1, 64, 0, stream>>>(lens, declen_out);
    k_tcvt_all<<<1768, 256, 0, stream>>>(W_enc, W_ih, W_fc, WencT, WihT0, WfcT);
    k_att1n<<<dim3(2, 196), 256, 0, stream>>>(encB, WencT, b_enc, att1B);
    k_xpre<<<dim3(8, TT), 256, 0, stream>>>(emb, caps, WihT0, xpre);
    k_packcat<<<1280, 256, 0, stream>>>(W_dec, W_beta, W_hh, WcatPK);
    k_packih<<<2048, 256, 0, stream>>>(W_ih, WihPK);

    MArgs ma;
    ma.lens = lens; ma.h0 = h0; ma.c0 = c0;
    ma.WcatPK = WcatPK; ma.bd = b_dec; ma.bb = b_beta;
    ma.att1B = att1B; ma.Wf = W_full; ma.encU = (const uint*)encB;
    ma.WihPK = WihPK; ma.xpre = xpre;
    ma.bih = b_ih; ma.bhh = b_hh; ma.memB = memB;
    ma.histB = histB; ma.alpha_out = alpha_out;
    k_mega<<<BB, 1024, 0, stream>>>(ma);

    k_preds_batch<<<dim3(40, TT), 256, 0, stream>>>(histB, WfcT, b_fc, lens, preds_out);
}

// Round 13
// 2690.746 us; speedup vs baseline: 1.8350x; 1.5510x over previous
//
#include <hip/hip_runtime.h>

#define BB   64
#define PP   196
#define ENCD 2048
#define DECD 512
#define VV   10000
#define TT   21
#define KIH  2560   // (EMB + ENC) rows of W_ih

typedef __attribute__((ext_vector_type(8))) short bf16x8;
typedef __attribute__((ext_vector_type(4))) float f32x4;

__device__ __forceinline__ float sigm(float x)   { return 1.f / (1.f + __expf(-x)); }
__device__ __forceinline__ float tanh_f(float x) { return 1.f - 2.f / (1.f + __expf(2.f * x)); }
__device__ __forceinline__ ushort f2bf(float x) {
    unsigned u = __float_as_uint(x);
    unsigned r = (u + 0x7FFFu + ((u >> 16) & 1u)) >> 16;
    return (ushort)r;
}
__device__ __forceinline__ float bf2f(ushort u) {
    return __uint_as_float(((unsigned)u) << 16);
}
union U8 { float4 f4; ushort u[8]; };

// ---------------- setup kernels ----------------

__global__ void k_cvt(const float* __restrict__ in, ushort* __restrict__ out, int n4) {
    int i = blockIdx.x * 256 + threadIdx.x;
    if (i >= n4) return;
    float4 v = ((const float4*)in)[i];
    ushort4 o; o.x = f2bf(v.x); o.y = f2bf(v.y); o.z = f2bf(v.z); o.w = f2bf(v.w);
    ((ushort4*)out)[i] = o;
}

__global__ void k_mean16(const ushort* __restrict__ encB, float* __restrict__ mean) {
    int idx = blockIdx.x * 256 + threadIdx.x;
    int b = idx >> 10, e2 = idx & 1023;
    const uint* p = (const uint*)encB + (size_t)b * PP * 1024 + e2;
    float s0 = 0.f, s1 = 0.f;
    #pragma unroll 7
    for (int i = 0; i < PP; ++i) {
        uint v = p[(size_t)i * 1024];
        s0 += __uint_as_float(v << 16);
        s1 += __uint_as_float(v & 0xffff0000u);
    }
    mean[b * 2048 + e2 * 2]     = s0 * (1.f / 196.f);
    mean[b * 2048 + e2 * 2 + 1] = s1 * (1.f / 196.f);
}

__global__ __launch_bounds__(256) void k_ipart(const float* __restrict__ mean,
        const float* __restrict__ Wh, const float* __restrict__ Wc,
        float* __restrict__ ipart) {
    __shared__ alignas(16) float As[32][68];
    __shared__ alignas(16) float Bs[32][68];
    const int n0 = blockIdx.x * 64;
    const int kc = blockIdx.y;
    const int mat = blockIdx.z;
    const float* Bp = mat ? Wc : Wh;
    const int tid = threadIdx.x, tx = tid & 15, ty = tid >> 4;
    float acc[4][4] = {};
    for (int k0 = 0; k0 < 512; k0 += 32) {
        #pragma unroll
        for (int p = 0; p < 2; ++p) {
            int c = p * 256 + tid;
            int m = c >> 3, k4 = (c & 7) * 4;
            float4 v = *(const float4*)(mean + m * 2048 + kc * 512 + k0 + k4);
            As[k4 + 0][m] = v.x; As[k4 + 1][m] = v.y; As[k4 + 2][m] = v.z; As[k4 + 3][m] = v.w;
            int kb = c >> 4, n4 = (c & 15) * 4;
            float4 w = *(const float4*)(Bp + (size_t)(kc * 512 + k0 + kb) * 512 + n0 + n4);
            *(float4*)&Bs[kb][n4] = w;
        }
        __syncthreads();
        #pragma unroll 8
        for (int k = 0; k < 32; ++k) {
            float4 a = *(const float4*)&As[k][ty * 4];
            float4 b = *(const float4*)&Bs[k][tx * 4];
            float av[4] = {a.x, a.y, a.z, a.w}, bv[4] = {b.x, b.y, b.z, b.w};
            #pragma unroll
            for (int i = 0; i < 4; ++i)
                #pragma unroll
                for (int j = 0; j < 4; ++j) acc[i][j] += av[i] * bv[j];
        }
        __syncthreads();
    }
    #pragma unroll
    for (int i = 0; i < 4; ++i) {
        int m = ty * 4 + i;
        #pragma unroll
        for (int j = 0; j < 4; ++j) {
            int n = n0 + tx * 4 + j;
            ipart[((size_t)(mat * 4 + kc) * BB + m) * 512 + n] = acc[i][j];
        }
    }
}

__global__ void k_ifin(const float* __restrict__ ipart,
                       const float* __restrict__ bh, const float* __restrict__ bc,
                       float* __restrict__ h, float* __restrict__ c, ushort* __restrict__ hB) {
    int idx = blockIdx.x * 256 + threadIdx.x;
    int mat = idx >> 15, rem = idx & 32767;
    int b = rem >> 9, d = rem & 511;
    float s = 0.f;
    #pragma unroll
    for (int kc = 0; kc < 4; ++kc) s += ipart[((size_t)(mat * 4 + kc) * BB + b) * 512 + d];
    if (mat) c[rem] = s + bc[d];
    else { float v = s + bh[d]; h[rem] = v; hB[rem] = f2bf(v); }
}

__global__ __launch_bounds__(256) void k_tcvt_all(
        const float* __restrict__ Wenc, const float* __restrict__ Wdec,
        const float* __restrict__ Wbeta, const float* __restrict__ Whh,
        const float* __restrict__ Wih, const float* __restrict__ Wfc,
        ushort* __restrict__ WencT, ushort* __restrict__ WdecT,
        ushort* __restrict__ WbetaT, ushort* __restrict__ WhhT,
        ushort* __restrict__ WihT, ushort* __restrict__ WfcT) {
    __shared__ float lds[64 * 65];
    int l = blockIdx.x;
    const float* in; ushort* out; int K, N, KT;
    if (l < 256)       { in = Wenc;  out = WencT;  K = 2048; N = 512;   KT = 32; }
    else if (l < 320)  { l -= 256;  in = Wdec;  out = WdecT;  K = 512;  N = 512;   KT = 8; }
    else if (l < 576)  { l -= 320;  in = Wbeta; out = WbetaT; K = 512;  N = 2048;  KT = 8; }
    else if (l < 832)  { l -= 576;  in = Whh;   out = WhhT;   K = 512;  N = 2048;  KT = 8; }
    else if (l < 2112) { l -= 832;  in = Wih;   out = WihT;   K = KIH;  N = 2048;  KT = 40; }
    else               { l -= 2112; in = Wfc;   out = WfcT;   K = 512;  N = 10000; KT = 8; }
    const int k0 = (l % KT) * 64, n0 = (l / KT) * 64;
    const int tid = threadIdx.x;
    for (int i = tid; i < 4096; i += 256) {
        int kk = i >> 6, nn = i & 63;
        float v = 0.f;
        if (n0 + nn < N) v = in[(size_t)(k0 + kk) * N + n0 + nn];
        lds[nn * 65 + kk] = v;
    }
    __syncthreads();
    for (int i = tid; i < 4096; i += 256) {
        int nn = i >> 6, kk = i & 63;
        out[(size_t)(n0 + nn) * K + k0 + kk] = f2bf(lds[nn * 65 + kk]);
    }
}

// att1T[b][col][p] bf16 = bf16(enc @ W_enc + b_enc) transposed per b. grid (2, 196)
__global__ __launch_bounds__(256) void k_att1T(const ushort* __restrict__ A,
        const ushort* __restrict__ Bt, const float* __restrict__ bias,
        ushort* __restrict__ att1T) {
    __shared__ alignas(16) ushort As[64 * 64];
    __shared__ alignas(16) ushort Bs[256 * 64];
    const int n0 = blockIdx.x * 256;
    const int m0 = blockIdx.y * 64;
    const int tid = threadIdx.x, wid = tid >> 6, lane = tid & 63;
    f32x4 acc[4][4] = {};
    for (int k0 = 0; k0 < 2048; k0 += 64) {
        #pragma unroll
        for (int p = 0; p < 2; ++p) {
            int c = p * 256 + tid;
            int r = c >> 3, cc = c & 7;
            float4 v = *(const float4*)(A + (size_t)(m0 + r) * 2048 + k0 + cc * 8);
            *(float4*)(As + r * 64 + ((cc ^ (r & 7)) * 8)) = v;
        }
        #pragma unroll
        for (int p = 0; p < 8; ++p) {
            int c = p * 256 + tid;
            int r = c >> 3, cc = c & 7;
            float4 v = *(const float4*)(Bt + (size_t)(n0 + r) * 2048 + k0 + cc * 8);
            *(float4*)(Bs + r * 64 + ((cc ^ (r & 7)) * 8)) = v;
        }
        __syncthreads();
        #pragma unroll
        for (int kk = 0; kk < 2; ++kk) {
            int ci = kk * 4 + (lane >> 4);
            bf16x8 afrag[4], bfrag[4];
            #pragma unroll
            for (int m = 0; m < 4; ++m) {
                int row = m * 16 + (lane & 15);
                afrag[m] = *(const bf16x8*)(As + row * 64 + ((ci ^ (row & 7)) * 8));
            }
            #pragma unroll
            for (int n = 0; n < 4; ++n) {
                int col = wid * 64 + n * 16 + (lane & 15);
                bfrag[n] = *(const bf16x8*)(Bs + col * 64 + ((ci ^ (col & 7)) * 8));
            }
            #pragma unroll
            for (int m = 0; m < 4; ++m)
                #pragma unroll
                for (int n = 0; n < 4; ++n)
                    acc[m][n] = __builtin_amdgcn_mfma_f32_16x16x32_bf16(afrag[m], bfrag[n], acc[m][n], 0, 0, 0);
        }
        __syncthreads();
    }
    #pragma unroll
    for (int m = 0; m < 4; ++m) {
        int rb = m0 + m * 16 + (lane >> 4) * 4;   // mult of 4; 196%4==0 so no b straddle
        int b = rb / 196;
        int p = rb - b * 196;
        #pragma unroll
        for (int n = 0; n < 4; ++n) {
            int col = n0 + wid * 64 + n * 16 + (lane & 15);
            float bv = bias[col];
            ushort4 o;
            o.x = f2bf(acc[m][n][0] + bv);
            o.y = f2bf(acc[m][n][1] + bv);
            o.z = f2bf(acc[m][n][2] + bv);
            o.w = f2bf(acc[m][n][3] + bv);
            *(ushort4*)(att1T + ((size_t)(b * 512 + col)) * 200 + p) = o;
        }
    }
}

// xpre[t][b][2048] = emb[caps[b,t]] @ W_ih[0:512]. grid (8, 21)
__global__ __launch_bounds__(256) void k_xpre(const float* __restrict__ emb,
        const int* __restrict__ caps, const ushort* __restrict__ WihT,
        float* __restrict__ xpre) {
    __shared__ alignas(16) ushort As[64 * 64];
    __shared__ alignas(16) ushort Bs[256 * 64];
    __shared__ int capsh[64];
    const int n0 = blockIdx.x * 256;
    const int t = blockIdx.y;
    const int tid = threadIdx.x, wid = tid >> 6, lane = tid & 63;
    if (tid < 64) capsh[tid] = caps[tid * 22 + t];
    __syncthreads();
    f32x4 acc[4][4] = {};
    for (int k0 = 0; k0 < 512; k0 += 64) {
        #pragma unroll
        for (int p = 0; p < 2; ++p) {
            int c = p * 256 + tid;
            int r = c >> 3, cc = c & 7;
            const float* er = emb + (size_t)capsh[r] * 512 + k0 + cc * 8;
            float4 v0 = *(const float4*)er;
            float4 v1 = *(const float4*)(er + 4);
            U8 pk;
            pk.u[0] = f2bf(v0.x); pk.u[1] = f2bf(v0.y); pk.u[2] = f2bf(v0.z); pk.u[3] = f2bf(v0.w);
            pk.u[4] = f2bf(v1.x); pk.u[5] = f2bf(v1.y); pk.u[6] = f2bf(v1.z); pk.u[7] = f2bf(v1.w);
            *(float4*)(As + r * 64 + ((cc ^ (r & 7)) * 8)) = pk.f4;
        }
        #pragma unroll
        for (int p = 0; p < 8; ++p) {
            int c = p * 256 + tid;
            int r = c >> 3, cc = c & 7;
            float4 v = *(const float4*)(WihT + (size_t)(n0 + r) * KIH + k0 + cc * 8);
            *(float4*)(Bs + r * 64 + ((cc ^ (r & 7)) * 8)) = v;
        }
        __syncthreads();
        #pragma unroll
        for (int kk = 0; kk < 2; ++kk) {
            int ci = kk * 4 + (lane >> 4);
            bf16x8 afrag[4], bfrag[4];
            #pragma unroll
            for (int m = 0; m < 4; ++m) {
                int row = m * 16 + (lane & 15);
                afrag[m] = *(const bf16x8*)(As + row * 64 + ((ci ^ (row & 7)) * 8));
            }
            #pragma unroll
            for (int n = 0; n < 4; ++n) {
                int col = wid * 64 + n * 16 + (lane & 15);
                bfrag[n] = *(const bf16x8*)(Bs + col * 64 + ((ci ^ (col & 7)) * 8));
            }
            #pragma unroll
            for (int m = 0; m < 4; ++m)
                #pragma unroll
                for (int n = 0; n < 4; ++n)
                    acc[m][n] = __builtin_amdgcn_mfma_f32_16x16x32_bf16(afrag[m], bfrag[n], acc[m][n], 0, 0, 0);
        }
        __syncthreads();
    }
    #pragma unroll
    for (int m = 0; m < 4; ++m) {
        int rb = m * 16 + (lane >> 4) * 4;
        #pragma unroll
        for (int n = 0; n < 4; ++n) {
            int col = n0 + wid * 64 + n * 16 + (lane & 15);
            #pragma unroll
            for (int r = 0; r < 4; ++r)
                xpre[((size_t)t * BB + rb + r) * 2048 + col] = acc[m][n][r];
        }
    }
}

__global__ void k_declen(const int* __restrict__ lens, float* __restrict__ out) {
    int b = threadIdx.x;
    if (b < BB) out[b] = (float)(lens[b] - 1);
}

// ---------------- per-step phase kernels (verified in R8/R9) ----------------

struct SArgs {
    ushort* hB; float* h; float* c;
    const ushort* WcatT; const float* bd; const float* bb;
    const ushort* WihT; const float* xpre; const ushort* att1T;
    const float* Wf; const ushort* encB;
    const float* bih; const float* bhh;
    const int* lens; const float* memB;
    float* att2; float* gate; float* hhp;
    uint* aweB; float* pawe;
    ushort* histB; float* alpha_out;
};

struct SMem {
    ushort As[64 * 64];
    ushort Bs[64 * 64];
    float a2s[512], wfs[512], reds[256], als[224];
    float hss[512], simss[128], pss[128];
};

// P1: att2|gate|hhp = hB @ WcatT (72 tiles of 64 cols, K=512)
__device__ __forceinline__ void phase1(const SArgs& a, int bid, int tid, SMem& sm) {
    const int lane = tid & 63, wid = tid >> 6;
    const int n0 = bid * 64;
    f32x4 acc[4] = {};
    for (int k0 = 0; k0 < 512; k0 += 64) {
        #pragma unroll
        for (int p = 0; p < 2; ++p) {
            int c8 = p * 256 + tid;
            int r = c8 >> 3, cc = c8 & 7;
            float4 v = *(const float4*)(a.hB + r * 512 + k0 + cc * 8);
            *(float4*)(sm.As + r * 64 + ((cc ^ (r & 7)) * 8)) = v;
            float4 w = *(const float4*)(a.WcatT + (size_t)(n0 + r) * 512 + k0 + cc * 8);
            *(float4*)(sm.Bs + r * 64 + ((cc ^ (r & 7)) * 8)) = w;
        }
        __syncthreads();
        #pragma unroll
        for (int kk = 0; kk < 2; ++kk) {
            int ci = kk * 4 + (lane >> 4);
            int colL = wid * 16 + (lane & 15);
            bf16x8 bfrag = *(const bf16x8*)(sm.Bs + colL * 64 + ((ci ^ (colL & 7)) * 8));
            #pragma unroll
            for (int m = 0; m < 4; ++m) {
                int row = m * 16 + (lane & 15);
                bf16x8 afrag = *(const bf16x8*)(sm.As + row * 64 + ((ci ^ (row & 7)) * 8));
                acc[m] = __builtin_amdgcn_mfma_f32_16x16x32_bf16(afrag, bfrag, acc[m], 0, 0, 0);
            }
        }
        __syncthreads();
    }
    int col = n0 + wid * 16 + (lane & 15);
    #pragma unroll
    for (int m = 0; m < 4; ++m) {
        int rb = m * 16 + (lane >> 4) * 4;
        #pragma unroll
        for (int r = 0; r < 4; ++r) {
            int row = rb + r;
            float v = acc[m][r];
            if (col < 512)       a.att2[row * 512 + col] = v + a.bd[col];
            else if (col < 2560) a.gate[row * 2048 + (col - 512)] = sigm(v + a.bb[col - 512]);
            else                 a.hhp[(size_t)row * 2048 + (col - 2560)] = v;
        }
    }
}

// P2: e-scores + softmax + awe; bid in [0,256): b=bid>>2, pc=bid&3
__device__ __forceinline__ void phase2(const SArgs& a, int t, int bid, int tid, SMem& sm) {
    const int b = bid >> 2, pc = bid & 3;
    for (int i = tid; i < 512; i += 256) { sm.a2s[i] = a.att2[b * 512 + i]; sm.wfs[i] = a.Wf[i]; }
    __syncthreads();
    float es = -3.4e38f;
    if (tid < PP) {
        const ushort* rp = a.att1T + (size_t)b * 512 * 200 + tid;
        float s = 0.f;
        #pragma unroll 4
        for (int k = 0; k < 512; ++k) {
            float v = bf2f(rp[(size_t)k * 200]) + sm.a2s[k];
            s += (v > 0.f ? v : 0.f) * sm.wfs[k];
        }
        es = s;
    }
    sm.reds[tid] = es; __syncthreads();
    for (int s = 128; s; s >>= 1) { if (tid < s) sm.reds[tid] = fmaxf(sm.reds[tid], sm.reds[tid + s]); __syncthreads(); }
    float mx = sm.reds[0]; __syncthreads();
    float ev = (tid < PP) ? __expf(es - mx) : 0.f;
    sm.reds[tid] = ev; __syncthreads();
    for (int s = 128; s; s >>= 1) { if (tid < s) sm.reds[tid] += sm.reds[tid + s]; __syncthreads(); }
    float inv = 1.f / sm.reds[0];
    if (tid < PP) {
        float al = ev * inv;
        sm.als[tid] = al;
        if (pc == 0) {
            bool m = t < (a.lens[b] - 1);
            a.alpha_out[((size_t)b * TT + t) * PP + tid] = m ? al : 0.f;
        }
    }
    __syncthreads();
    int pair = pc * 256 + tid;
    const uint* pp = (const uint*)a.encB + (size_t)b * PP * 1024 + pair;
    float s0 = 0.f, s1 = 0.f;
    #pragma unroll 4
    for (int i = 0; i < PP; ++i) {
        uint vv = pp[(size_t)i * 1024];
        float al = sm.als[i];
        s0 += al * __uint_as_float(vv << 16);
        s1 += al * __uint_as_float(vv & 0xffff0000u);
    }
    int e = pair * 2;
    float g0 = s0 * a.gate[b * 2048 + e];
    float g1 = s1 * a.gate[b * 2048 + e + 1];
    a.aweB[b * 1024 + pair] = (uint)f2bf(g0) | ((uint)f2bf(g1) << 16);
}

// P3: pawe[kc] = aweB slice @ W_ih slice; bid in [0,128)
__device__ __forceinline__ void phase3(const SArgs& a, int bid, int tid, SMem& sm) {
    const int lane = tid & 63, wid = tid >> 6;
    const int n0 = (bid & 31) * 64, kc = bid >> 5;
    const ushort* aweU = (const ushort*)a.aweB;
    f32x4 acc[4] = {};
    for (int k0 = 0; k0 < 512; k0 += 64) {
        #pragma unroll
        for (int p = 0; p < 2; ++p) {
            int c8 = p * 256 + tid;
            int r = c8 >> 3, cc = c8 & 7;
            float4 v = *(const float4*)(aweU + r * 2048 + kc * 512 + k0 + cc * 8);
            *(float4*)(sm.As + r * 64 + ((cc ^ (r & 7)) * 8)) = v;
            float4 w = *(const float4*)(a.WihT + (size_t)(n0 + r) * KIH + 512 + kc * 512 + k0 + cc * 8);
            *(float4*)(sm.Bs + r * 64 + ((cc ^ (r & 7)) * 8)) = w;
        }
        __syncthreads();
        #pragma unroll
        for (int kk = 0; kk < 2; ++kk) {
            int ci = kk * 4 + (lane >> 4);
            int colL = wid * 16 + (lane & 15);
            bf16x8 bfrag = *(const bf16x8*)(sm.Bs + colL * 64 + ((ci ^ (colL & 7)) * 8));
            #pragma unroll
            for (int m = 0; m < 4; ++m) {
                int row = m * 16 + (lane & 15);
                bf16x8 afrag = *(const bf16x8*)(sm.As + row * 64 + ((ci ^ (row & 7)) * 8));
                acc[m] = __builtin_amdgcn_mfma_f32_16x16x32_bf16(afrag, bfrag, acc[m], 0, 0, 0);
            }
        }
        __syncthreads();
    }
    int col = n0 + wid * 16 + (lane & 15);
    #pragma unroll
    for (int m = 0; m < 4; ++m) {
        int rb = m * 16 + (lane >> 4) * 4;
        #pragma unroll
        for (int r = 0; r < 4; ++r)
            a.pawe[((size_t)kc * BB + rb + r) * 2048 + col] = acc[m][r];
    }
}

// P4: LSTM pointwise + memory attention + carry; bid in [0,64)
__device__ __forceinline__ void phase4(const SArgs& a, int t, int bid, int tid, SMem& sm) {
    const int lane = tid & 63, wid = tid >> 6;
    const int b = bid;
    bool msk = t < (a.lens[b] - 1);
    for (int j = tid; j < 512; j += 256) {
        float g[4];
        #pragma unroll
        for (int q = 0; q < 4; ++q) {
            int col = q * 512 + j;
            float s = a.bih[col] + a.bhh[col]
                    + a.hhp[(size_t)b * 2048 + col]
                    + a.xpre[((size_t)t * BB + b) * 2048 + col];
            #pragma unroll
            for (int kc = 0; kc < 4; ++kc) s += a.pawe[((size_t)kc * BB + b) * 2048 + col];
            g[q] = s;
        }
        float gi = sigm(g[0]), gf = sigm(g[1]), gg = tanh_f(g[2]), go = sigm(g[3]);
        float cold = a.c[b * 512 + j];
        float cn = gf * cold + gi * gg;
        a.c[b * 512 + j] = msk ? cn : cold;
        sm.hss[j] = go * tanh_f(cn);
    }
    __syncthreads();
    for (int m = wid * 32; m < wid * 32 + 32; ++m) {
        const float* r = a.memB + (size_t)m * 512 + lane * 8;
        float4 r0 = *(const float4*)(r);
        float4 r1 = *(const float4*)(r + 4);
        float4 h0 = *(const float4*)(&sm.hss[lane * 8]);
        float4 h1 = *(const float4*)(&sm.hss[lane * 8 + 4]);
        float s = r0.x * h0.x + r0.y * h0.y + r0.z * h0.z + r0.w * h0.w
                + r1.x * h1.x + r1.y * h1.y + r1.z * h1.z + r1.w * h1.w;
        #pragma unroll
        for (int off = 32; off; off >>= 1) s += __shfl_down(s, off);
        if (lane == 0) sm.simss[m] = s;
    }
    __syncthreads();
    float v = (tid < 128) ? sm.simss[tid] : -3.4e38f;
    sm.reds[tid] = v; __syncthreads();
    for (int s = 128; s; s >>= 1) { if (tid < s) sm.reds[tid] = fmaxf(sm.reds[tid], sm.reds[tid + s]); __syncthreads(); }
    float mx = sm.reds[0]; __syncthreads();
    float ev = (tid < 128) ? __expf(v - mx) : 0.f;
    sm.reds[tid] = ev; __syncthreads();
    for (int s = 128; s; s >>= 1) { if (tid < s) sm.reds[tid] += sm.reds[tid + s]; __syncthreads(); }
    if (tid < 128) sm.pss[tid] = ev / sm.reds[0];
    __syncthreads();
    for (int d = tid; d < 512; d += 256) {
        float s = 0.f;
        #pragma unroll 4
        for (int m = 0; m < 128; ++m) s += sm.pss[m] * a.memB[(size_t)m * 512 + d];
        float hn = sm.hss[d] + s;
        a.histB[((size_t)t * BB + b) * 512 + d] = f2bf(hn);
        float hold = a.h[b * 512 + d];
        float hv = msk ? hn : hold;
        a.h[b * 512 + d] = hv;
        a.hB[b * 512 + d] = f2bf(hv);
    }
}

__global__ __launch_bounds__(256) void k_p1(SArgs a) {
    __shared__ SMem sm; phase1(a, blockIdx.x, threadIdx.x, sm);
}
__global__ __launch_bounds__(256) void k_p2(SArgs a, int t) {
    __shared__ SMem sm; phase2(a, t, blockIdx.x, threadIdx.x, sm);
}
__global__ __launch_bounds__(256) void k_p3(SArgs a) {
    __shared__ SMem sm; phase3(a, blockIdx.x, threadIdx.x, sm);
}
__global__ __launch_bounds__(256) void k_p4(SArgs a, int t) {
    __shared__ SMem sm; phase4(a, t, blockIdx.x, threadIdx.x, sm);
}

// batched preds: hist(21*64 x 512) @ WfcT^T + bfc, masked. grid (40, 21)
__global__ __launch_bounds__(256) void k_preds_batch(const ushort* __restrict__ histB,
        const ushort* __restrict__ WfcT, const float* __restrict__ bfc,
        const int* __restrict__ lens, float* __restrict__ out) {
    __shared__ alignas(16) ushort As[64 * 64];
    __shared__ alignas(16) ushort Bs[256 * 64];
    const int n0 = blockIdx.x * 256;
    const int t = blockIdx.y;
    const ushort* A = histB + (size_t)t * BB * 512;
    const int tid = threadIdx.x, wid = tid >> 6, lane = tid & 63;
    f32x4 acc[4][4] = {};
    for (int k0 = 0; k0 < 512; k0 += 64) {
        #pragma unroll
        for (int p = 0; p < 2; ++p) {
            int c = p * 256 + tid;
            int r = c >> 3, cc = c & 7;
            float4 v = *(const float4*)(A + r * 512 + k0 + cc * 8);
            *(float4*)(As + r * 64 + ((cc ^ (r & 7)) * 8)) = v;
        }
        #pragma unroll
        for (int p = 0; p < 8; ++p) {
            int c = p * 256 + tid;
            int r = c >> 3, cc = c & 7;
            float4 v = *(const float4*)(WfcT + (size_t)(n0 + r) * 512 + k0 + cc * 8);
            *(float4*)(Bs + r * 64 + ((cc ^ (r & 7)) * 8)) = v;
        }
        __syncthreads();
        #pragma unroll
        for (int kk = 0; kk < 2; ++kk) {
            int ci = kk * 4 + (lane >> 4);
            bf16x8 afrag[4], bfrag[4];
            #pragma unroll
            for (int m = 0; m < 4; ++m) {
                int row = m * 16 + (lane & 15);
                afrag[m] = *(const bf16x8*)(As + row * 64 + ((ci ^ (row & 7)) * 8));
            }
            #pragma unroll
            for (int n = 0; n < 4; ++n) {
                int col = wid * 64 + n * 16 + (lane & 15);
                bfrag[n] = *(const bf16x8*)(Bs + col * 64 + ((ci ^ (col & 7)) * 8));
            }
            #pragma unroll
            for (int m = 0; m < 4; ++m)
                #pragma unroll
                for (int n = 0; n < 4; ++n)
                    acc[m][n] = __builtin_amdgcn_mfma_f32_16x16x32_bf16(afrag[m], bfrag[n], acc[m][n], 0, 0, 0);
        }
        __syncthreads();
    }
    #pragma unroll
    for (int m = 0; m < 4; ++m) {
        int rb = m * 16 + (lane >> 4) * 4;
        #pragma unroll
        for (int n = 0; n < 4; ++n) {
            int col = n0 + wid * 64 + n * 16 + (lane & 15);
            if (col < VV) {
                float bv = bfc[col];
                #pragma unroll
                for (int r = 0; r < 4; ++r) {
                    int b = rb + r;
                    bool msk = t < (lens[b] - 1);
                    out[((size_t)b * TT + t) * VV + col] = msk ? (acc[m][n][r] + bv) : 0.f;
                }
            }
        }
    }
}

// ---------------- launch ----------------

extern "C" void kernel_launch(void* const* d_in, const int* in_sizes, int n_in,
                              void* d_out, int out_size, void* d_ws, size_t ws_size,
                              hipStream_t stream) {
    const float* enc     = (const float*)d_in[0];
    const int*   caps    = (const int*)d_in[1];
    const int*   lens    = (const int*)d_in[2];
    const float* emb     = (const float*)d_in[3];
    const float* W_enc   = (const float*)d_in[4];
    const float* b_enc   = (const float*)d_in[5];
    const float* W_dec   = (const float*)d_in[6];
    const float* b_dec   = (const float*)d_in[7];
    const float* W_full  = (const float*)d_in[8];
    const float* W_inith = (const float*)d_in[10];
    const float* b_inith = (const float*)d_in[11];
    const float* W_initc = (const float*)d_in[12];
    const float* b_initc = (const float*)d_in[13];
    const float* W_beta  = (const float*)d_in[14];
    const float* b_beta  = (const float*)d_in[15];
    const float* W_ih    = (const float*)d_in[16];
    const float* b_ih    = (const float*)d_in[17];
    const float* W_hh    = (const float*)d_in[18];
    const float* b_hh    = (const float*)d_in[19];
    const float* memB    = (const float*)d_in[20];
    const float* W_fc    = (const float*)d_in[21];
    const float* b_fc    = (const float*)d_in[22];

    float* out = (float*)d_out;
    float* preds_out  = out;
    float* declen_out = out + (size_t)BB * TT * VV;
    float* alpha_out  = declen_out + BB;

    float* ws    = (float*)d_ws;
    ushort* att1T = (ushort*)ws;  ws += (size_t)64 * 512 * 200 / 2;
    float* h     = ws;  ws += BB * DECD;
    float* c     = ws;  ws += BB * DECD;
    float* att2  = ws;  ws += BB * 512;
    float* gate  = ws;  ws += BB * 2048;
    float* hhp   = ws;  ws += BB * 2048;
    float* pawe  = ws;  ws += (size_t)4 * BB * 2048;
    float* xpre  = ws;  ws += (size_t)TT * BB * 2048;
    ushort* hB   = (ushort*)ws;  ws += BB * DECD / 2;
    uint*  aweB  = (uint*)ws;    ws += BB * 1024;
    ushort* histB = (ushort*)ws; ws += (size_t)TT * BB * DECD / 2;
    ushort* encB  = (ushort*)ws; ws += (size_t)12544 * 2048 / 2;
    ushort* WencT = (ushort*)ws; ws += (size_t)512 * 2048 / 2;
    ushort* WfcT  = (ushort*)ws; ws += (size_t)10240 * 512 / 2;
    ushort* WcatT = (ushort*)ws; ws += (size_t)4608 * 512 / 2;
    ushort* WihT  = (ushort*)ws; ws += (size_t)2048 * KIH / 2;
    // aliases (setup-only, dead before their regions are written)
    float* mean  = (float*)att1T;   // dead before k_att1T
    float* ipart = xpre;            // dead before k_xpre

    k_cvt<<<(12544 * 2048 / 4 + 255) / 256, 256, 0, stream>>>(enc, encB, 12544 * 2048 / 4);
    k_mean16<<<256, 256, 0, stream>>>(encB, mean);
    k_ipart<<<dim3(8, 4, 2), 256, 0, stream>>>(mean, W_inith, W_initc, ipart);
    k_ifin<<<256, 256, 0, stream>>>(ipart, b_inith, b_initc, h, c, hB);
    k_declen<<<1, 64, 0, stream>>>(lens, declen_out);
    k_tcvt_all<<<3392, 256, 0, stream>>>(W_enc, W_dec, W_beta, W_hh, W_ih, W_fc,
                                         WencT, WcatT, WcatT + (size_t)512 * 512,
                                         WcatT + (size_t)2560 * 512, WihT, WfcT);
    k_att1T<<<dim3(2, 196), 256, 0, stream>>>(encB, WencT, b_enc, att1T);
    k_xpre<<<dim3(8, TT), 256, 0, stream>>>(emb, caps, WihT, xpre);

    SArgs sa;
    sa.hB = hB; sa.h = h; sa.c = c;
    sa.WcatT = WcatT; sa.bd = b_dec; sa.bb = b_beta;
    sa.WihT = WihT; sa.xpre = xpre; sa.att1T = att1T;
    sa.Wf = W_full; sa.encB = encB;
    sa.bih = b_ih; sa.bhh = b_hh;
    sa.lens = lens; sa.memB = memB;
    sa.att2 = att2; sa.gate = gate; sa.hhp = hhp;
    sa.aweB = aweB; sa.pawe = pawe;
    sa.histB = histB; sa.alpha_out = alpha_out;

    for (int t = 0; t < TT; ++t) {
        k_p1<<<72,  256, 0, stream>>>(sa);
        k_p2<<<256, 256, 0, stream>>>(sa, t);
        k_p3<<<128, 256, 0, stream>>>(sa);
        k_p4<<<64,  256, 0, stream>>>(sa, t);
    }

    k_preds_batch<<<dim3(40, TT), 256, 0, stream>>>(histB, WfcT, b_fc, lens, preds_out);
}

// Round 14
// 1687.152 us; speedup vs baseline: 2.9265x; 1.5948x over previous
//
#include <hip/hip_runtime.h>

#define BB   64
#define PP   196
#define ENCD 2048
#define DECD 512
#define VV   10000
#define TT   21
#define KIH  2560   // (EMB + ENC) rows of W_ih

typedef __attribute__((ext_vector_type(8))) short bf16x8;
typedef __attribute__((ext_vector_type(4))) float f32x4;

__device__ __forceinline__ float sigm(float x)   { return 1.f / (1.f + __expf(-x)); }
__device__ __forceinline__ float tanh_f(float x) { return 1.f - 2.f / (1.f + __expf(2.f * x)); }
__device__ __forceinline__ ushort f2bf(float x) {
    unsigned u = __float_as_uint(x);
    unsigned r = (u + 0x7FFFu + ((u >> 16) & 1u)) >> 16;
    return (ushort)r;
}
__device__ __forceinline__ float bf2f(ushort u) {
    return __uint_as_float(((unsigned)u) << 16);
}
union U8 { float4 f4; ushort u[8]; };

// ---------------- setup kernels ----------------

__global__ void k_cvt(const float* __restrict__ in, ushort* __restrict__ out, int n4) {
    int i = blockIdx.x * 256 + threadIdx.x;
    if (i >= n4) return;
    float4 v = ((const float4*)in)[i];
    ushort4 o; o.x = f2bf(v.x); o.y = f2bf(v.y); o.z = f2bf(v.z); o.w = f2bf(v.w);
    ((ushort4*)out)[i] = o;
}

__global__ void k_mean16(const ushort* __restrict__ encB, float* __restrict__ mean) {
    int idx = blockIdx.x * 256 + threadIdx.x;
    int b = idx >> 10, e2 = idx & 1023;
    const uint* p = (const uint*)encB + (size_t)b * PP * 1024 + e2;
    float s0 = 0.f, s1 = 0.f;
    #pragma unroll 7
    for (int i = 0; i < PP; ++i) {
        uint v = p[(size_t)i * 1024];
        s0 += __uint_as_float(v << 16);
        s1 += __uint_as_float(v & 0xffff0000u);
    }
    mean[b * 2048 + e2 * 2]     = s0 * (1.f / 196.f);
    mean[b * 2048 + e2 * 2 + 1] = s1 * (1.f / 196.f);
}

__global__ __launch_bounds__(256) void k_ipart(const float* __restrict__ mean,
        const float* __restrict__ Wh, const float* __restrict__ Wc,
        float* __restrict__ ipart) {
    __shared__ alignas(16) float As[32][68];
    __shared__ alignas(16) float Bs[32][68];
    const int n0 = blockIdx.x * 64;
    const int kc = blockIdx.y;
    const int mat = blockIdx.z;
    const float* Bp = mat ? Wc : Wh;
    const int tid = threadIdx.x, tx = tid & 15, ty = tid >> 4;
    float acc[4][4] = {};
    for (int k0 = 0; k0 < 512; k0 += 32) {
        #pragma unroll
        for (int p = 0; p < 2; ++p) {
            int c = p * 256 + tid;
            int m = c >> 3, k4 = (c & 7) * 4;
            float4 v = *(const float4*)(mean + m * 2048 + kc * 512 + k0 + k4);
            As[k4 + 0][m] = v.x; As[k4 + 1][m] = v.y; As[k4 + 2][m] = v.z; As[k4 + 3][m] = v.w;
            int kb = c >> 4, n4 = (c & 15) * 4;
            float4 w = *(const float4*)(Bp + (size_t)(kc * 512 + k0 + kb) * 512 + n0 + n4);
            *(float4*)&Bs[kb][n4] = w;
        }
        __syncthreads();
        #pragma unroll 8
        for (int k = 0; k < 32; ++k) {
            float4 a = *(const float4*)&As[k][ty * 4];
            float4 b = *(const float4*)&Bs[k][tx * 4];
            float av[4] = {a.x, a.y, a.z, a.w}, bv[4] = {b.x, b.y, b.z, b.w};
            #pragma unroll
            for (int i = 0; i < 4; ++i)
                #pragma unroll
                for (int j = 0; j < 4; ++j) acc[i][j] += av[i] * bv[j];
        }
        __syncthreads();
    }
    #pragma unroll
    for (int i = 0; i < 4; ++i) {
        int m = ty * 4 + i;
        #pragma unroll
        for (int j = 0; j < 4; ++j) {
            int n = n0 + tx * 4 + j;
            ipart[((size_t)(mat * 4 + kc) * BB + m) * 512 + n] = acc[i][j];
        }
    }
}

__global__ void k_ifin(const float* __restrict__ ipart,
                       const float* __restrict__ bh, const float* __restrict__ bc,
                       float* __restrict__ h, float* __restrict__ c, ushort* __restrict__ hB) {
    int idx = blockIdx.x * 256 + threadIdx.x;
    int mat = idx >> 15, rem = idx & 32767;
    int b = rem >> 9, d = rem & 511;
    float s = 0.f;
    #pragma unroll
    for (int kc = 0; kc < 4; ++kc) s += ipart[((size_t)(mat * 4 + kc) * BB + b) * 512 + d];
    if (mat) c[rem] = s + bc[d];
    else { float v = s + bh[d]; h[rem] = v; hB[rem] = f2bf(v); }
}

__global__ __launch_bounds__(256) void k_tcvt_all(
        const float* __restrict__ Wenc, const float* __restrict__ Wdec,
        const float* __restrict__ Wbeta, const float* __restrict__ Whh,
        const float* __restrict__ Wih, const float* __restrict__ Wfc,
        ushort* __restrict__ WencT, ushort* __restrict__ WdecT,
        ushort* __restrict__ WbetaT, ushort* __restrict__ WhhT,
        ushort* __restrict__ WihT, ushort* __restrict__ WfcT) {
    __shared__ float lds[64 * 65];
    int l = blockIdx.x;
    const float* in; ushort* out; int K, N, KT;
    if (l < 256)       { in = Wenc;  out = WencT;  K = 2048; N = 512;   KT = 32; }
    else if (l < 320)  { l -= 256;  in = Wdec;  out = WdecT;  K = 512;  N = 512;   KT = 8; }
    else if (l < 576)  { l -= 320;  in = Wbeta; out = WbetaT; K = 512;  N = 2048;  KT = 8; }
    else if (l < 832)  { l -= 576;  in = Whh;   out = WhhT;   K = 512;  N = 2048;  KT = 8; }
    else if (l < 2112) { l -= 832;  in = Wih;   out = WihT;   K = KIH;  N = 2048;  KT = 40; }
    else               { l -= 2112; in = Wfc;   out = WfcT;   K = 512;  N = 10000; KT = 8; }
    const int k0 = (l % KT) * 64, n0 = (l / KT) * 64;
    const int tid = threadIdx.x;
    for (int i = tid; i < 4096; i += 256) {
        int kk = i >> 6, nn = i & 63;
        float v = 0.f;
        if (n0 + nn < N) v = in[(size_t)(k0 + kk) * N + n0 + nn];
        lds[nn * 65 + kk] = v;
    }
    __syncthreads();
    for (int i = tid; i < 4096; i += 256) {
        int nn = i >> 6, kk = i & 63;
        out[(size_t)(n0 + nn) * K + k0 + kk] = f2bf(lds[nn * 65 + kk]);
    }
}

// att1B[12544][512] bf16 = bf16(encB @ WencT^T + bias). grid (2, 196)
__global__ __launch_bounds__(256) void k_att1n(const ushort* __restrict__ A,
        const ushort* __restrict__ Bt, const float* __restrict__ bias,
        ushort* __restrict__ C) {
    __shared__ alignas(16) ushort As[64 * 64];
    __shared__ alignas(16) ushort Bs[256 * 64];
    const int n0 = blockIdx.x * 256;
    const int m0 = blockIdx.y * 64;
    const int tid = threadIdx.x, wid = tid >> 6, lane = tid & 63;
    f32x4 acc[4][4] = {};
    for (int k0 = 0; k0 < 2048; k0 += 64) {
        #pragma unroll
        for (int p = 0; p < 2; ++p) {
            int c = p * 256 + tid;
            int r = c >> 3, cc = c & 7;
            float4 v = *(const float4*)(A + (size_t)(m0 + r) * 2048 + k0 + cc * 8);
            *(float4*)(As + r * 64 + ((cc ^ (r & 7)) * 8)) = v;
        }
        #pragma unroll
        for (int p = 0; p < 8; ++p) {
            int c = p * 256 + tid;
            int r = c >> 3, cc = c & 7;
            float4 v = *(const float4*)(Bt + (size_t)(n0 + r) * 2048 + k0 + cc * 8);
            *(float4*)(Bs + r * 64 + ((cc ^ (r & 7)) * 8)) = v;
        }
        __syncthreads();
        #pragma unroll
        for (int kk = 0; kk < 2; ++kk) {
            int ci = kk * 4 + (lane >> 4);
            bf16x8 afrag[4], bfrag[4];
            #pragma unroll
            for (int m = 0; m < 4; ++m) {
                int row = m * 16 + (lane & 15);
                afrag[m] = *(const bf16x8*)(As + row * 64 + ((ci ^ (row & 7)) * 8));
            }
            #pragma unroll
            for (int n = 0; n < 4; ++n) {
                int col = wid * 64 + n * 16 + (lane & 15);
                bfrag[n] = *(const bf16x8*)(Bs + col * 64 + ((ci ^ (col & 7)) * 8));
            }
            #pragma unroll
            for (int m = 0; m < 4; ++m)
                #pragma unroll
                for (int n = 0; n < 4; ++n)
                    acc[m][n] = __builtin_amdgcn_mfma_f32_16x16x32_bf16(afrag[m], bfrag[n], acc[m][n], 0, 0, 0);
        }
        __syncthreads();
    }
    #pragma unroll
    for (int m = 0; m < 4; ++m) {
        int rb = m0 + m * 16 + (lane >> 4) * 4;
        #pragma unroll
        for (int n = 0; n < 4; ++n) {
            int col = n0 + wid * 64 + n * 16 + (lane & 15);
            float bv = bias[col];
            #pragma unroll
            for (int r = 0; r < 4; ++r)
                C[(size_t)(rb + r) * 512 + col] = f2bf(acc[m][n][r] + bv);
        }
    }
}

// xpre[t][b][2048] = emb[caps[b,t]] @ W_ih[0:512]. grid (8, 21)
__global__ __launch_bounds__(256) void k_xpre(const float* __restrict__ emb,
        const int* __restrict__ caps, const ushort* __restrict__ WihT,
        float* __restrict__ xpre) {
    __shared__ alignas(16) ushort As[64 * 64];
    __shared__ alignas(16) ushort Bs[256 * 64];
    __shared__ int capsh[64];
    const int n0 = blockIdx.x * 256;
    const int t = blockIdx.y;
    const int tid = threadIdx.x, wid = tid >> 6, lane = tid & 63;
    if (tid < 64) capsh[tid] = caps[tid * 22 + t];
    __syncthreads();
    f32x4 acc[4][4] = {};
    for (int k0 = 0; k0 < 512; k0 += 64) {
        #pragma unroll
        for (int p = 0; p < 2; ++p) {
            int c = p * 256 + tid;
            int r = c >> 3, cc = c & 7;
            const float* er = emb + (size_t)capsh[r] * 512 + k0 + cc * 8;
            float4 v0 = *(const float4*)er;
            float4 v1 = *(const float4*)(er + 4);
            U8 pk;
            pk.u[0] = f2bf(v0.x); pk.u[1] = f2bf(v0.y); pk.u[2] = f2bf(v0.z); pk.u[3] = f2bf(v0.w);
            pk.u[4] = f2bf(v1.x); pk.u[5] = f2bf(v1.y); pk.u[6] = f2bf(v1.z); pk.u[7] = f2bf(v1.w);
            *(float4*)(As + r * 64 + ((cc ^ (r & 7)) * 8)) = pk.f4;
        }
        #pragma unroll
        for (int p = 0; p < 8; ++p) {
            int c = p * 256 + tid;
            int r = c >> 3, cc = c & 7;
            float4 v = *(const float4*)(WihT + (size_t)(n0 + r) * KIH + k0 + cc * 8);
            *(float4*)(Bs + r * 64 + ((cc ^ (r & 7)) * 8)) = v;
        }
        __syncthreads();
        #pragma unroll
        for (int kk = 0; kk < 2; ++kk) {
            int ci = kk * 4 + (lane >> 4);
            bf16x8 afrag[4], bfrag[4];
            #pragma unroll
            for (int m = 0; m < 4; ++m) {
                int row = m * 16 + (lane & 15);
                afrag[m] = *(const bf16x8*)(As + row * 64 + ((ci ^ (row & 7)) * 8));
            }
            #pragma unroll
            for (int n = 0; n < 4; ++n) {
                int col = wid * 64 + n * 16 + (lane & 15);
                bfrag[n] = *(const bf16x8*)(Bs + col * 64 + ((ci ^ (col & 7)) * 8));
            }
            #pragma unroll
            for (int m = 0; m < 4; ++m)
                #pragma unroll
                for (int n = 0; n < 4; ++n)
                    acc[m][n] = __builtin_amdgcn_mfma_f32_16x16x32_bf16(afrag[m], bfrag[n], acc[m][n], 0, 0, 0);
        }
        __syncthreads();
    }
    #pragma unroll
    for (int m = 0; m < 4; ++m) {
        int rb = m * 16 + (lane >> 4) * 4;
        #pragma unroll
        for (int n = 0; n < 4; ++n) {
            int col = n0 + wid * 64 + n * 16 + (lane & 15);
            #pragma unroll
            for (int r = 0; r < 4; ++r)
                xpre[((size_t)t * BB + rb + r) * 2048 + col] = acc[m][n][r];
        }
    }
}

__global__ void k_declen(const int* __restrict__ lens, float* __restrict__ out) {
    int b = threadIdx.x;
    if (b < BB) out[b] = (float)(lens[b] - 1);
}

// ---------------- per-step kernels ----------------

// P1: att2|gate|hhp = hB @ WcatT (72 tiles of 64 cols, K=512)
__global__ __launch_bounds__(256) void k_p1(const ushort* __restrict__ hB,
        const ushort* __restrict__ WcatT, const float* __restrict__ bd,
        const float* __restrict__ bb, float* __restrict__ att2,
        float* __restrict__ gate, float* __restrict__ hhp) {
    __shared__ alignas(16) ushort As[64 * 64];
    __shared__ alignas(16) ushort Bs[64 * 64];
    const int tid = threadIdx.x, lane = tid & 63, wid = tid >> 6;
    const int n0 = blockIdx.x * 64;
    f32x4 acc[4] = {};
    for (int k0 = 0; k0 < 512; k0 += 64) {
        #pragma unroll
        for (int p = 0; p < 2; ++p) {
            int c8 = p * 256 + tid;
            int r = c8 >> 3, cc = c8 & 7;
            float4 v = *(const float4*)(hB + r * 512 + k0 + cc * 8);
            *(float4*)(As + r * 64 + ((cc ^ (r & 7)) * 8)) = v;
            float4 w = *(const float4*)(WcatT + (size_t)(n0 + r) * 512 + k0 + cc * 8);
            *(float4*)(Bs + r * 64 + ((cc ^ (r & 7)) * 8)) = w;
        }
        __syncthreads();
        #pragma unroll
        for (int kk = 0; kk < 2; ++kk) {
            int ci = kk * 4 + (lane >> 4);
            int colL = wid * 16 + (lane & 15);
            bf16x8 bfrag = *(const bf16x8*)(Bs + colL * 64 + ((ci ^ (colL & 7)) * 8));
            #pragma unroll
            for (int m = 0; m < 4; ++m) {
                int row = m * 16 + (lane & 15);
                bf16x8 afrag = *(const bf16x8*)(As + row * 64 + ((ci ^ (row & 7)) * 8));
                acc[m] = __builtin_amdgcn_mfma_f32_16x16x32_bf16(afrag, bfrag, acc[m], 0, 0, 0);
            }
        }
        __syncthreads();
    }
    int col = n0 + wid * 16 + (lane & 15);
    #pragma unroll
    for (int m = 0; m < 4; ++m) {
        int rb = m * 16 + (lane >> 4) * 4;
        #pragma unroll
        for (int r = 0; r < 4; ++r) {
            int row = rb + r;
            float v = acc[m][r];
            if (col < 512)       att2[row * 512 + col] = v + bd[col];
            else if (col < 2560) gate[row * 2048 + (col - 512)] = sigm(v + bb[col - 512]);
            else                 hhp[(size_t)row * 2048 + (col - 2560)] = v;
        }
    }
}

// P2a: e-score partial dot products; grid (4, 64), row-major att1B
__global__ __launch_bounds__(256) void k_escore_p(const ushort* __restrict__ att1B,
        const float* __restrict__ att2, const float* __restrict__ Wf,
        float* __restrict__ es) {
    __shared__ float a2[512], wf[512];
    int b = blockIdx.y, pc = blockIdx.x, tid = threadIdx.x;
    for (int i = tid; i < 512; i += 256) { a2[i] = att2[b * 512 + i]; wf[i] = Wf[i]; }
    __syncthreads();
    int lane = tid & 63, wid = tid >> 6;
    for (int i = wid; i < 49; i += 4) {
        int p = pc * 49 + i;
        bf16x8 rv = *(const bf16x8*)(att1B + ((size_t)(b * PP + p)) * 512 + lane * 8);
        float s = 0.f;
        #pragma unroll
        for (int j = 0; j < 8; ++j) {
            float v = bf2f((ushort)rv[j]) + a2[lane * 8 + j];
            s += (v > 0.f ? v : 0.f) * wf[lane * 8 + j];
        }
        #pragma unroll
        for (int off = 32; off; off >>= 1) s += __shfl_down(s, off);
        if (lane == 0) es[b * 256 + p] = s;
    }
}

// P2b: softmax + awe + gate + pack; grid (16, 64). wave w covers p = w, w+4, ...
__global__ __launch_bounds__(256) void k_awe16s(const ushort* __restrict__ encB,
        const float* __restrict__ es, const float* __restrict__ gate,
        const int* __restrict__ lens, int t,
        uint* __restrict__ aweB, float* __restrict__ alpha_out) {
    __shared__ float al[224], red[256], ps0[4][64], ps1[4][64];
    int b = blockIdx.y, ec = blockIdx.x, tid = threadIdx.x;
    float v = (tid < PP) ? es[b * 256 + tid] : -3.4e38f;
    red[tid] = v; __syncthreads();
    for (int s = 128; s; s >>= 1) { if (tid < s) red[tid] = fmaxf(red[tid], red[tid + s]); __syncthreads(); }
    float mx = red[0]; __syncthreads();
    float ev = (tid < PP) ? __expf(v - mx) : 0.f;
    red[tid] = ev; __syncthreads();
    for (int s = 128; s; s >>= 1) { if (tid < s) red[tid] += red[tid + s]; __syncthreads(); }
    float inv = 1.f / red[0];
    if (tid < PP) {
        float a = ev * inv;
        al[tid] = a;
        if (ec == 0) {
            bool m = t < (lens[b] - 1);
            alpha_out[((size_t)b * TT + t) * PP + tid] = m ? a : 0.f;
        }
    }
    __syncthreads();
    int w = tid >> 6, lane = tid & 63;
    int pair = ec * 64 + lane;
    const uint* pp = (const uint*)encB + (size_t)b * PP * 1024 + pair;
    float s0 = 0.f, s1 = 0.f;
    #pragma unroll 7
    for (int i = w; i < PP; i += 4) {
        uint vv = pp[(size_t)i * 1024];
        float a = al[i];
        s0 += a * __uint_as_float(vv << 16);
        s1 += a * __uint_as_float(vv & 0xffff0000u);
    }
    ps0[w][lane] = s0; ps1[w][lane] = s1;
    __syncthreads();
    if (tid < 64) {
        float t0 = ps0[0][tid] + ps0[1][tid] + ps0[2][tid] + ps0[3][tid];
        float t1 = ps1[0][tid] + ps1[1][tid] + ps1[2][tid] + ps1[3][tid];
        int e = (ec * 64 + tid) * 2;
        float g0 = t0 * gate[b * 2048 + e];
        float g1 = t1 * gate[b * 2048 + e + 1];
        ushort u0 = f2bf(g0), u1 = f2bf(g1);
        aweB[b * 1024 + ec * 64 + tid] = (uint)u0 | ((uint)u1 << 16);
    }
}

// P3: pawe[kc] = aweB slice @ W_ih slice; grid 128
__global__ __launch_bounds__(256) void k_p3(const uint* __restrict__ aweB,
        const ushort* __restrict__ WihT, float* __restrict__ pawe) {
    __shared__ alignas(16) ushort As[64 * 64];
    __shared__ alignas(16) ushort Bs[64 * 64];
    const int tid = threadIdx.x, lane = tid & 63, wid = tid >> 6;
    const int n0 = (blockIdx.x & 31) * 64, kc = blockIdx.x >> 5;
    const ushort* aweU = (const ushort*)aweB;
    f32x4 acc[4] = {};
    for (int k0 = 0; k0 < 512; k0 += 64) {
        #pragma unroll
        for (int p = 0; p < 2; ++p) {
            int c8 = p * 256 + tid;
            int r = c8 >> 3, cc = c8 & 7;
            float4 v = *(const float4*)(aweU + r * 2048 + kc * 512 + k0 + cc * 8);
            *(float4*)(As + r * 64 + ((cc ^ (r & 7)) * 8)) = v;
            float4 w = *(const float4*)(WihT + (size_t)(n0 + r) * KIH + 512 + kc * 512 + k0 + cc * 8);
            *(float4*)(Bs + r * 64 + ((cc ^ (r & 7)) * 8)) = w;
        }
        __syncthreads();
        #pragma unroll
        for (int kk = 0; kk < 2; ++kk) {
            int ci = kk * 4 + (lane >> 4);
            int colL = wid * 16 + (lane & 15);
            bf16x8 bfrag = *(const bf16x8*)(Bs + colL * 64 + ((ci ^ (colL & 7)) * 8));
            #pragma unroll
            for (int m = 0; m < 4; ++m) {
                int row = m * 16 + (lane & 15);
                bf16x8 afrag = *(const bf16x8*)(As + row * 64 + ((ci ^ (row & 7)) * 8));
                acc[m] = __builtin_amdgcn_mfma_f32_16x16x32_bf16(afrag, bfrag, acc[m], 0, 0, 0);
            }
        }
        __syncthreads();
    }
    int col = n0 + wid * 16 + (lane & 15);
    #pragma unroll
    for (int m = 0; m < 4; ++m) {
        int rb = m * 16 + (lane >> 4) * 4;
        #pragma unroll
        for (int r = 0; r < 4; ++r)
            pawe[((size_t)kc * BB + rb + r) * 2048 + col] = acc[m][r];
    }
}

// P4: LSTM pointwise + memory attention + carry; grid 64
__global__ __launch_bounds__(256) void k_p4(const float* __restrict__ hhp,
        const float* __restrict__ pawe, const float* __restrict__ xpre,
        const float* __restrict__ bih, const float* __restrict__ bhh,
        const int* __restrict__ lens, int t, const float* __restrict__ memB,
        float* __restrict__ h, float* __restrict__ c,
        ushort* __restrict__ hB, ushort* __restrict__ histB) {
    __shared__ float hss[512], simss[128], reds[256], pss[128];
    const int b = blockIdx.x, tid = threadIdx.x;
    const int lane = tid & 63, wid = tid >> 6;
    bool msk = t < (lens[b] - 1);
    for (int j = tid; j < 512; j += 256) {
        float g[4];
        #pragma unroll
        for (int q = 0; q < 4; ++q) {
            int col = q * 512 + j;
            float s = bih[col] + bhh[col]
                    + hhp[(size_t)b * 2048 + col]
                    + xpre[((size_t)t * BB + b) * 2048 + col];
            #pragma unroll
            for (int kc = 0; kc < 4; ++kc) s += pawe[((size_t)kc * BB + b) * 2048 + col];
            g[q] = s;
        }
        float gi = sigm(g[0]), gf = sigm(g[1]), gg = tanh_f(g[2]), go = sigm(g[3]);
        float cold = c[b * 512 + j];
        float cn = gf * cold + gi * gg;
        c[b * 512 + j] = msk ? cn : cold;
        hss[j] = go * tanh_f(cn);
    }
    __syncthreads();
    for (int m = wid * 32; m < wid * 32 + 32; ++m) {
        const float* r = memB + (size_t)m * 512 + lane * 8;
        float4 r0 = *(const float4*)(r);
        float4 r1 = *(const float4*)(r + 4);
        float4 h0 = *(const float4*)(&hss[lane * 8]);
        float4 h1 = *(const float4*)(&hss[lane * 8 + 4]);
        float s = r0.x * h0.x + r0.y * h0.y + r0.z * h0.z + r0.w * h0.w
                + r1.x * h1.x + r1.y * h1.y + r1.z * h1.z + r1.w * h1.w;
        #pragma unroll
        for (int off = 32; off; off >>= 1) s += __shfl_down(s, off);
        if (lane == 0) simss[m] = s;
    }
    __syncthreads();
    float v = (tid < 128) ? simss[tid] : -3.4e38f;
    reds[tid] = v; __syncthreads();
    for (int s = 128; s; s >>= 1) { if (tid < s) reds[tid] = fmaxf(reds[tid], reds[tid + s]); __syncthreads(); }
    float mx = reds[0]; __syncthreads();
    float ev = (tid < 128) ? __expf(v - mx) : 0.f;
    reds[tid] = ev; __syncthreads();
    for (int s = 128; s; s >>= 1) { if (tid < s) reds[tid] += reds[tid + s]; __syncthreads(); }
    if (tid < 128) pss[tid] = ev / reds[0];
    __syncthreads();
    for (int d = tid; d < 512; d += 256) {
        float s = 0.f;
        #pragma unroll 4
        for (int m = 0; m < 128; ++m) s += pss[m] * memB[(size_t)m * 512 + d];
        float hn = hss[d] + s;
        histB[((size_t)t * BB + b) * 512 + d] = f2bf(hn);
        float hold = h[b * 512 + d];
        float hv = msk ? hn : hold;
        h[b * 512 + d] = hv;
        hB[b * 512 + d] = f2bf(hv);
    }
}

// batched preds: hist(21*64 x 512) @ WfcT^T + bfc, masked. grid (40, 21)
__global__ __launch_bounds__(256) void k_preds_batch(const ushort* __restrict__ histB,
        const ushort* __restrict__ WfcT, const float* __restrict__ bfc,
        const int* __restrict__ lens, float* __restrict__ out) {
    __shared__ alignas(16) ushort As[64 * 64];
    __shared__ alignas(16) ushort Bs[256 * 64];
    const int n0 = blockIdx.x * 256;
    const int t = blockIdx.y;
    const ushort* A = histB + (size_t)t * BB * 512;
    const int tid = threadIdx.x, wid = tid >> 6, lane = tid & 63;
    f32x4 acc[4][4] = {};
    for (int k0 = 0; k0 < 512; k0 += 64) {
        #pragma unroll
        for (int p = 0; p < 2; ++p) {
            int c = p * 256 + tid;
            int r = c >> 3, cc = c & 7;
            float4 v = *(const float4*)(A + r * 512 + k0 + cc * 8);
            *(float4*)(As + r * 64 + ((cc ^ (r & 7)) * 8)) = v;
        }
        #pragma unroll
        for (int p = 0; p < 8; ++p) {
            int c = p * 256 + tid;
            int r = c >> 3, cc = c & 7;
            float4 v = *(const float4*)(WfcT + (size_t)(n0 + r) * 512 + k0 + cc * 8);
            *(float4*)(Bs + r * 64 + ((cc ^ (r & 7)) * 8)) = v;
        }
        __syncthreads();
        #pragma unroll
        for (int kk = 0; kk < 2; ++kk) {
            int ci = kk * 4 + (lane >> 4);
            bf16x8 afrag[4], bfrag[4];
            #pragma unroll
            for (int m = 0; m < 4; ++m) {
                int row = m * 16 + (lane & 15);
                afrag[m] = *(const bf16x8*)(As + row * 64 + ((ci ^ (row & 7)) * 8));
            }
            #pragma unroll
            for (int n = 0; n < 4; ++n) {
                int col = wid * 64 + n * 16 + (lane & 15);
                bfrag[n] = *(const bf16x8*)(Bs + col * 64 + ((ci ^ (col & 7)) * 8));
            }
            #pragma unroll
            for (int m = 0; m < 4; ++m)
                #pragma unroll
                for (int n = 0; n < 4; ++n)
                    acc[m][n] = __builtin_amdgcn_mfma_f32_16x16x32_bf16(afrag[m], bfrag[n], acc[m][n], 0, 0, 0);
        }
        __syncthreads();
    }
    #pragma unroll
    for (int m = 0; m < 4; ++m) {
        int rb = m * 16 + (lane >> 4) * 4;
        #pragma unroll
        for (int n = 0; n < 4; ++n) {
            int col = n0 + wid * 64 + n * 16 + (lane & 15);
            if (col < VV) {
                float bv = bfc[col];
                #pragma unroll
                for (int r = 0; r < 4; ++r) {
                    int b = rb + r;
                    bool msk = t < (lens[b] - 1);
                    out[((size_t)b * TT + t) * VV + col] = msk ? (acc[m][n][r] + bv) : 0.f;
                }
            }
        }
    }
}

// ---------------- launch ----------------

extern "C" void kernel_launch(void* const* d_in, const int* in_sizes, int n_in,
                              void* d_out, int out_size, void* d_ws, size_t ws_size,
                              hipStream_t stream) {
    const float* enc     = (const float*)d_in[0];
    const int*   caps    = (const int*)d_in[1];
    const int*   lens    = (const int*)d_in[2];
    const float* emb     = (const float*)d_in[3];
    const float* W_enc   = (const float*)d_in[4];
    const float* b_enc   = (const float*)d_in[5];
    const float* W_dec   = (const float*)d_in[6];
    const float* b_dec   = (const float*)d_in[7];
    const float* W_full  = (const float*)d_in[8];
    const float* W_inith = (const float*)d_in[10];
    const float* b_inith = (const float*)d_in[11];
    const float* W_initc = (const float*)d_in[12];
    const float* b_initc = (const float*)d_in[13];
    const float* W_beta  = (const float*)d_in[14];
    const float* b_beta  = (const float*)d_in[15];
    const float* W_ih    = (const float*)d_in[16];
    const float* b_ih    = (const float*)d_in[17];
    const float* W_hh    = (const float*)d_in[18];
    const float* b_hh    = (const float*)d_in[19];
    const float* memB    = (const float*)d_in[20];
    const float* W_fc    = (const float*)d_in[21];
    const float* b_fc    = (const float*)d_in[22];

    float* out = (float*)d_out;
    float* preds_out  = out;
    float* declen_out = out + (size_t)BB * TT * VV;
    float* alpha_out  = declen_out + BB;

    float* ws    = (float*)d_ws;
    ushort* att1B = (ushort*)ws;  ws += (size_t)12544 * 512 / 2;
    float* h     = ws;  ws += BB * DECD;
    float* c     = ws;  ws += BB * DECD;
    float* att2  = ws;  ws += BB * 512;
    float* gate  = ws;  ws += BB * 2048;
    float* hhp   = ws;  ws += BB * 2048;
    float* es    = ws;  ws += BB * 256;
    float* pawe  = ws;  ws += (size_t)4 * BB * 2048;
    float* xpre  = ws;  ws += (size_t)TT * BB * 2048;
    ushort* hB   = (ushort*)ws;  ws += BB * DECD / 2;
    uint*  aweB  = (uint*)ws;    ws += BB * 1024;
    ushort* histB = (ushort*)ws; ws += (size_t)TT * BB * DECD / 2;
    ushort* encB  = (ushort*)ws; ws += (size_t)12544 * 2048 / 2;
    ushort* WencT = (ushort*)ws; ws += (size_t)512 * 2048 / 2;
    ushort* WfcT  = (ushort*)ws; ws += (size_t)10240 * 512 / 2;
    ushort* WcatT = (ushort*)ws; ws += (size_t)4608 * 512 / 2;
    ushort* WihT  = (ushort*)ws; ws += (size_t)2048 * KIH / 2;
    // aliases (setup-only, dead before their regions are written)
    float* mean  = (float*)att1B;   // dead before k_att1n
    float* ipart = xpre;            // dead before k_xpre

    k_cvt<<<(12544 * 2048 / 4 + 255) / 256, 256, 0, stream>>>(enc, encB, 12544 * 2048 / 4);
    k_mean16<<<256, 256, 0, stream>>>(encB, mean);
    k_ipart<<<dim3(8, 4, 2), 256, 0, stream>>>(mean, W_inith, W_initc, ipart);
    k_ifin<<<256, 256, 0, stream>>>(ipart, b_inith, b_initc, h, c, hB);
    k_declen<<<1, 64, 0, stream>>>(lens, declen_out);
    k_tcvt_all<<<3392, 256, 0, stream>>>(W_enc, W_dec, W_beta, W_hh, W_ih, W_fc,
                                         WencT, WcatT, WcatT + (size_t)512 * 512,
                                         WcatT + (size_t)2560 * 512, WihT, WfcT);
    k_att1n<<<dim3(2, 196), 256, 0, stream>>>(encB, WencT, b_enc, att1B);
    k_xpre<<<dim3(8, TT), 256, 0, stream>>>(emb, caps, WihT, xpre);

    for (int t = 0; t < TT; ++t) {
        k_p1<<<72, 256, 0, stream>>>(hB, WcatT, b_dec, b_beta, att2, gate, hhp);
        k_escore_p<<<dim3(4, 64), 256, 0, stream>>>(att1B, att2, W_full, es);
        k_awe16s<<<dim3(16, 64), 256, 0, stream>>>(encB, es, gate, lens, t, aweB, alpha_out);
        k_p3<<<128, 256, 0, stream>>>(aweB, WihT, pawe);
        k_p4<<<64, 256, 0, stream>>>(hhp, pawe, xpre, b_ih, b_hh, lens, t, memB, h, c, hB, histB);
    }

    k_preds_batch<<<dim3(40, TT), 256, 0, stream>>>(histB, WfcT, b_fc, lens, preds_out);
}

// Round 15
// 1664.308 us; speedup vs baseline: 2.9667x; 1.0137x over previous
//
#include <hip/hip_runtime.h>

#define BB   64
#define PP   196
#define ENCD 2048
#define DECD 512
#define VV   10000
#define TT   21
#define KIH  2560   // (EMB + ENC) rows of W_ih

typedef __attribute__((ext_vector_type(8))) short bf16x8;
typedef __attribute__((ext_vector_type(4))) float f32x4;
typedef float f32x2 __attribute__((ext_vector_type(2)));

__device__ __forceinline__ float sigm(float x)   { return 1.f / (1.f + __expf(-x)); }
__device__ __forceinline__ float tanh_f(float x) { return 1.f - 2.f / (1.f + __expf(2.f * x)); }
__device__ __forceinline__ ushort f2bf(float x) {
    unsigned u = __float_as_uint(x);
    unsigned r = (u + 0x7FFFu + ((u >> 16) & 1u)) >> 16;
    return (ushort)r;
}
__device__ __forceinline__ float bf2f(ushort u) {
    return __uint_as_float(((unsigned)u) << 16);
}
union U8 { float4 f4; ushort u[8]; };

// ---- fp8 helpers (HW cvt when available; self-consistent SW fallback) ----
#if __has_builtin(__builtin_amdgcn_cvt_pk_fp8_f32) && __has_builtin(__builtin_amdgcn_cvt_pk_f32_fp8)
#define HAVE_HW_FP8 1
#endif

__device__ uint enc8m(float x) {     // e4m3fn round-to-nearest (fallback only)
    uint s = (__float_as_uint(x) >> 31) << 7;
    float ax = fabsf(x);
    if (!(ax > 0.f)) return s;
    if (ax >= 448.f) return s | 0x7e;
    int e; float m = frexpf(ax, &e);          // ax = m*2^e, m in [0.5,1)
    int E = e - 1 + 7;
    if (E <= 0) { int q = (int)rintf(ax * 512.f); if (q > 7) return s | 0x08; return s | (uint)q; }
    int q = (int)rintf((m * 2.f - 1.f) * 8.f);
    if (q == 8) { q = 0; ++E; if (E > 15) return s | 0x7e; }
    return s | ((uint)E << 3) | (uint)q;
}
__device__ __forceinline__ float dec8m(uint b) {
    uint s = b >> 7, e = (b >> 3) & 15, m = b & 7;
    float v = (e == 0) ? (float)m * (1.f / 512.f) : ldexpf(1.f + (float)m * 0.125f, (int)e - 7);
    return s ? -v : v;
}
__device__ __forceinline__ uint pkfp8x4(float a, float b, float c, float d) {
#ifdef HAVE_HW_FP8
    int v = __builtin_amdgcn_cvt_pk_fp8_f32(a, b, 0, false);
    v = __builtin_amdgcn_cvt_pk_fp8_f32(c, d, v, true);
    return (uint)v;
#else
    return enc8m(a) | (enc8m(b) << 8) | (enc8m(c) << 16) | (enc8m(d) << 24);
#endif
}
__device__ __forceinline__ void dec8x4(uint v, float out[4]) {
#ifdef HAVE_HW_FP8
    f32x2 lo = __builtin_amdgcn_cvt_pk_f32_fp8((int)v, false);
    f32x2 hi = __builtin_amdgcn_cvt_pk_f32_fp8((int)v, true);
    out[0] = lo[0]; out[1] = lo[1]; out[2] = hi[0]; out[3] = hi[1];
#else
    out[0] = dec8m(v & 255); out[1] = dec8m((v >> 8) & 255);
    out[2] = dec8m((v >> 16) & 255); out[3] = dec8m(v >> 24);
#endif
}

// ---------------- setup kernels ----------------

__global__ void k_cvt(const float* __restrict__ in, ushort* __restrict__ out, int n4) {
    int i = blockIdx.x * 256 + threadIdx.x;
    if (i >= n4) return;
    float4 v = ((const float4*)in)[i];
    ushort4 o; o.x = f2bf(v.x); o.y = f2bf(v.y); o.z = f2bf(v.z); o.w = f2bf(v.w);
    ((ushort4*)out)[i] = o;
}

// f32 -> fp8x4 (written over dead encB region after att1n)
__global__ void k_cvt8(const float* __restrict__ in, uint* __restrict__ out, int n4) {
    int i = blockIdx.x * 256 + threadIdx.x;
    if (i >= n4) return;
    float4 v = ((const float4*)in)[i];
    out[i] = pkfp8x4(v.x, v.y, v.z, v.w);
}

__global__ void k_mean16(const ushort* __restrict__ encB, float* __restrict__ mean) {
    int idx = blockIdx.x * 256 + threadIdx.x;
    int b = idx >> 10, e2 = idx & 1023;
    const uint* p = (const uint*)encB + (size_t)b * PP * 1024 + e2;
    float s0 = 0.f, s1 = 0.f;
    #pragma unroll 7
    for (int i = 0; i < PP; ++i) {
        uint v = p[(size_t)i * 1024];
        s0 += __uint_as_float(v << 16);
        s1 += __uint_as_float(v & 0xffff0000u);
    }
    mean[b * 2048 + e2 * 2]     = s0 * (1.f / 196.f);
    mean[b * 2048 + e2 * 2 + 1] = s1 * (1.f / 196.f);
}

__global__ __launch_bounds__(256) void k_ipart(const float* __restrict__ mean,
        const float* __restrict__ Wh, const float* __restrict__ Wc,
        float* __restrict__ ipart) {
    __shared__ alignas(16) float As[32][68];
    __shared__ alignas(16) float Bs[32][68];
    const int n0 = blockIdx.x * 64;
    const int kc = blockIdx.y;
    const int mat = blockIdx.z;
    const float* Bp = mat ? Wc : Wh;
    const int tid = threadIdx.x, tx = tid & 15, ty = tid >> 4;
    float acc[4][4] = {};
    for (int k0 = 0; k0 < 512; k0 += 32) {
        #pragma unroll
        for (int p = 0; p < 2; ++p) {
            int c = p * 256 + tid;
            int m = c >> 3, k4 = (c & 7) * 4;
            float4 v = *(const float4*)(mean + m * 2048 + kc * 512 + k0 + k4);
            As[k4 + 0][m] = v.x; As[k4 + 1][m] = v.y; As[k4 + 2][m] = v.z; As[k4 + 3][m] = v.w;
            int kb = c >> 4, n4 = (c & 15) * 4;
            float4 w = *(const float4*)(Bp + (size_t)(kc * 512 + k0 + kb) * 512 + n0 + n4);
            *(float4*)&Bs[kb][n4] = w;
        }
        __syncthreads();
        #pragma unroll 8
        for (int k = 0; k < 32; ++k) {
            float4 a = *(const float4*)&As[k][ty * 4];
            float4 b = *(const float4*)&Bs[k][tx * 4];
            float av[4] = {a.x, a.y, a.z, a.w}, bv[4] = {b.x, b.y, b.z, b.w};
            #pragma unroll
            for (int i = 0; i < 4; ++i)
                #pragma unroll
                for (int j = 0; j < 4; ++j) acc[i][j] += av[i] * bv[j];
        }
        __syncthreads();
    }
    #pragma unroll
    for (int i = 0; i < 4; ++i) {
        int m = ty * 4 + i;
        #pragma unroll
        for (int j = 0; j < 4; ++j) {
            int n = n0 + tx * 4 + j;
            ipart[((size_t)(mat * 4 + kc) * BB + m) * 512 + n] = acc[i][j];
        }
    }
}

__global__ void k_ifin(const float* __restrict__ ipart,
                       const float* __restrict__ bh, const float* __restrict__ bc,
                       float* __restrict__ h, float* __restrict__ c, ushort* __restrict__ hB) {
    int idx = blockIdx.x * 256 + threadIdx.x;
    int mat = idx >> 15, rem = idx & 32767;
    int b = rem >> 9, d = rem & 511;
    float s = 0.f;
    #pragma unroll
    for (int kc = 0; kc < 4; ++kc) s += ipart[((size_t)(mat * 4 + kc) * BB + b) * 512 + d];
    if (mat) c[rem] = s + bc[d];
    else { float v = s + bh[d]; h[rem] = v; hB[rem] = f2bf(v); }
}

__global__ __launch_bounds__(256) void k_tcvt_all(
        const float* __restrict__ Wenc, const float* __restrict__ Wdec,
        const float* __restrict__ Wbeta, const float* __restrict__ Whh,
        const float* __restrict__ Wih, const float* __restrict__ Wfc,
        ushort* __restrict__ WencT, ushort* __restrict__ WdecT,
        ushort* __restrict__ WbetaT, ushort* __restrict__ WhhT,
        ushort* __restrict__ WihT, ushort* __restrict__ WfcT) {
    __shared__ float lds[64 * 65];
    int l = blockIdx.x;
    const float* in; ushort* out; int K, N, KT;
    if (l < 256)       { in = Wenc;  out = WencT;  K = 2048; N = 512;   KT = 32; }
    else if (l < 320)  { l -= 256;  in = Wdec;  out = WdecT;  K = 512;  N = 512;   KT = 8; }
    else if (l < 576)  { l -= 320;  in = Wbeta; out = WbetaT; K = 512;  N = 2048;  KT = 8; }
    else if (l < 832)  { l -= 576;  in = Whh;   out = WhhT;   K = 512;  N = 2048;  KT = 8; }
    else if (l < 2112) { l -= 832;  in = Wih;   out = WihT;   K = KIH;  N = 2048;  KT = 40; }
    else               { l -= 2112; in = Wfc;   out = WfcT;   K = 512;  N = 10000; KT = 8; }
    const int k0 = (l % KT) * 64, n0 = (l / KT) * 64;
    const int tid = threadIdx.x;
    for (int i = tid; i < 4096; i += 256) {
        int kk = i >> 6, nn = i & 63;
        float v = 0.f;
        if (n0 + nn < N) v = in[(size_t)(k0 + kk) * N + n0 + nn];
        lds[nn * 65 + kk] = v;
    }
    __syncthreads();
    for (int i = tid; i < 4096; i += 256) {
        int nn = i >> 6, kk = i & 63;
        out[(size_t)(n0 + nn) * K + k0 + kk] = f2bf(lds[nn * 65 + kk]);
    }
}

// att1B[12544][512] bf16 = bf16(encB @ WencT^T + bias). grid (2, 196)
__global__ __launch_bounds__(256) void k_att1n(const ushort* __restrict__ A,
        const ushort* __restrict__ Bt, const float* __restrict__ bias,
        ushort* __restrict__ C) {
    __shared__ alignas(16) ushort As[64 * 64];
    __shared__ alignas(16) ushort Bs[256 * 64];
    const int n0 = blockIdx.x * 256;
    const int m0 = blockIdx.y * 64;
    const int tid = threadIdx.x, wid = tid >> 6, lane = tid & 63;
    f32x4 acc[4][4] = {};
    for (int k0 = 0; k0 < 2048; k0 += 64) {
        #pragma unroll
        for (int p = 0; p < 2; ++p) {
            int c = p * 256 + tid;
            int r = c >> 3, cc = c & 7;
            float4 v = *(const float4*)(A + (size_t)(m0 + r) * 2048 + k0 + cc * 8);
            *(float4*)(As + r * 64 + ((cc ^ (r & 7)) * 8)) = v;
        }
        #pragma unroll
        for (int p = 0; p < 8; ++p) {
            int c = p * 256 + tid;
            int r = c >> 3, cc = c & 7;
            float4 v = *(const float4*)(Bt + (size_t)(n0 + r) * 2048 + k0 + cc * 8);
            *(float4*)(Bs + r * 64 + ((cc ^ (r & 7)) * 8)) = v;
        }
        __syncthreads();
        #pragma unroll
        for (int kk = 0; kk < 2; ++kk) {
            int ci = kk * 4 + (lane >> 4);
            bf16x8 afrag[4], bfrag[4];
            #pragma unroll
            for (int m = 0; m < 4; ++m) {
                int row = m * 16 + (lane & 15);
                afrag[m] = *(const bf16x8*)(As + row * 64 + ((ci ^ (row & 7)) * 8));
            }
            #pragma unroll
            for (int n = 0; n < 4; ++n) {
                int col = wid * 64 + n * 16 + (lane & 15);
                bfrag[n] = *(const bf16x8*)(Bs + col * 64 + ((ci ^ (col & 7)) * 8));
            }
            #pragma unroll
            for (int m = 0; m < 4; ++m)
                #pragma unroll
                for (int n = 0; n < 4; ++n)
                    acc[m][n] = __builtin_amdgcn_mfma_f32_16x16x32_bf16(afrag[m], bfrag[n], acc[m][n], 0, 0, 0);
        }
        __syncthreads();
    }
    #pragma unroll
    for (int m = 0; m < 4; ++m) {
        int rb = m0 + m * 16 + (lane >> 4) * 4;
        #pragma unroll
        for (int n = 0; n < 4; ++n) {
            int col = n0 + wid * 64 + n * 16 + (lane & 15);
            float bv = bias[col];
            #pragma unroll
            for (int r = 0; r < 4; ++r)
                C[(size_t)(rb + r) * 512 + col] = f2bf(acc[m][n][r] + bv);
        }
    }
}

// xpre[t][b][2048] = emb[caps[b,t]] @ W_ih[0:512]. grid (8, 21)
__global__ __launch_bounds__(256) void k_xpre(const float* __restrict__ emb,
        const int* __restrict__ caps, const ushort* __restrict__ WihT,
        float* __restrict__ xpre) {
    __shared__ alignas(16) ushort As[64 * 64];
    __shared__ alignas(16) ushort Bs[256 * 64];
    __shared__ int capsh[64];
    const int n0 = blockIdx.x * 256;
    const int t = blockIdx.y;
    const int tid = threadIdx.x, wid = tid >> 6, lane = tid & 63;
    if (tid < 64) capsh[tid] = caps[tid * 22 + t];
    __syncthreads();
    f32x4 acc[4][4] = {};
    for (int k0 = 0; k0 < 512; k0 += 64) {
        #pragma unroll
        for (int p = 0; p < 2; ++p) {
            int c = p * 256 + tid;
            int r = c >> 3, cc = c & 7;
            const float* er = emb + (size_t)capsh[r] * 512 + k0 + cc * 8;
            float4 v0 = *(const float4*)er;
            float4 v1 = *(const float4*)(er + 4);
            U8 pk;
            pk.u[0] = f2bf(v0.x); pk.u[1] = f2bf(v0.y); pk.u[2] = f2bf(v0.z); pk.u[3] = f2bf(v0.w);
            pk.u[4] = f2bf(v1.x); pk.u[5] = f2bf(v1.y); pk.u[6] = f2bf(v1.z); pk.u[7] = f2bf(v1.w);
            *(float4*)(As + r * 64 + ((cc ^ (r & 7)) * 8)) = pk.f4;
        }
        #pragma unroll
        for (int p = 0; p < 8; ++p) {
            int c = p * 256 + tid;
            int r = c >> 3, cc = c & 7;
            float4 v = *(const float4*)(WihT + (size_t)(n0 + r) * KIH + k0 + cc * 8);
            *(float4*)(Bs + r * 64 + ((cc ^ (r & 7)) * 8)) = v;
        }
        __syncthreads();
        #pragma unroll
        for (int kk = 0; kk < 2; ++kk) {
            int ci = kk * 4 + (lane >> 4);
            bf16x8 afrag[4], bfrag[4];
            #pragma unroll
            for (int m = 0; m < 4; ++m) {
                int row = m * 16 + (lane & 15);
                afrag[m] = *(const bf16x8*)(As + row * 64 + ((ci ^ (row & 7)) * 8));
            }
            #pragma unroll
            for (int n = 0; n < 4; ++n) {
                int col = wid * 64 + n * 16 + (lane & 15);
                bfrag[n] = *(const bf16x8*)(Bs + col * 64 + ((ci ^ (col & 7)) * 8));
            }
            #pragma unroll
            for (int m = 0; m < 4; ++m)
                #pragma unroll
                for (int n = 0; n < 4; ++n)
                    acc[m][n] = __builtin_amdgcn_mfma_f32_16x16x32_bf16(afrag[m], bfrag[n], acc[m][n], 0, 0, 0);
        }
        __syncthreads();
    }
    #pragma unroll
    for (int m = 0; m < 4; ++m) {
        int rb = m * 16 + (lane >> 4) * 4;
        #pragma unroll
        for (int n = 0; n < 4; ++n) {
            int col = n0 + wid * 64 + n * 16 + (lane & 15);
            #pragma unroll
            for (int r = 0; r < 4; ++r)
                xpre[((size_t)t * BB + rb + r) * 2048 + col] = acc[m][n][r];
        }
    }
}

__global__ void k_declen(const int* __restrict__ lens, float* __restrict__ out) {
    int b = threadIdx.x;
    if (b < BB) out[b] = (float)(lens[b] - 1);
}

// ---------------- per-step kernels ----------------

// P1: att2|gate|hhp = hB @ WcatT (72 tiles of 64 cols, K=512)
__global__ __launch_bounds__(256) void k_p1(const ushort* __restrict__ hB,
        const ushort* __restrict__ WcatT, const float* __restrict__ bd,
        const float* __restrict__ bb, float* __restrict__ att2,
        float* __restrict__ gate, float* __restrict__ hhp) {
    __shared__ alignas(16) ushort As[64 * 64];
    __shared__ alignas(16) ushort Bs[64 * 64];
    const int tid = threadIdx.x, lane = tid & 63, wid = tid >> 6;
    const int n0 = blockIdx.x * 64;
    f32x4 acc[4] = {};
    for (int k0 = 0; k0 < 512; k0 += 64) {
        #pragma unroll
        for (int p = 0; p < 2; ++p) {
            int c8 = p * 256 + tid;
            int r = c8 >> 3, cc = c8 & 7;
            float4 v = *(const float4*)(hB + r * 512 + k0 + cc * 8);
            *(float4*)(As + r * 64 + ((cc ^ (r & 7)) * 8)) = v;
            float4 w = *(const float4*)(WcatT + (size_t)(n0 + r) * 512 + k0 + cc * 8);
            *(float4*)(Bs + r * 64 + ((cc ^ (r & 7)) * 8)) = w;
        }
        __syncthreads();
        #pragma unroll
        for (int kk = 0; kk < 2; ++kk) {
            int ci = kk * 4 + (lane >> 4);
            int colL = wid * 16 + (lane & 15);
            bf16x8 bfrag = *(const bf16x8*)(Bs + colL * 64 + ((ci ^ (colL & 7)) * 8));
            #pragma unroll
            for (int m = 0; m < 4; ++m) {
                int row = m * 16 + (lane & 15);
                bf16x8 afrag = *(const bf16x8*)(As + row * 64 + ((ci ^ (row & 7)) * 8));
                acc[m] = __builtin_amdgcn_mfma_f32_16x16x32_bf16(afrag, bfrag, acc[m], 0, 0, 0);
            }
        }
        __syncthreads();
    }
    int col = n0 + wid * 16 + (lane & 15);
    #pragma unroll
    for (int m = 0; m < 4; ++m) {
        int rb = m * 16 + (lane >> 4) * 4;
        #pragma unroll
        for (int r = 0; r < 4; ++r) {
            int row = rb + r;
            float v = acc[m][r];
            if (col < 512)       att2[row * 512 + col] = v + bd[col];
            else if (col < 2560) gate[row * 2048 + (col - 512)] = sigm(v + bb[col - 512]);
            else                 hhp[(size_t)row * 2048 + (col - 2560)] = v;
        }
    }
}

// P2a: e-score partial dot products; grid (4, 64), row-major att1B
__global__ __launch_bounds__(256) void k_escore_p(const ushort* __restrict__ att1B,
        const float* __restrict__ att2, const float* __restrict__ Wf,
        float* __restrict__ es) {
    __shared__ float a2[512], wf[512];
    int b = blockIdx.y, pc = blockIdx.x, tid = threadIdx.x;
    for (int i = tid; i < 512; i += 256) { a2[i] = att2[b * 512 + i]; wf[i] = Wf[i]; }
    __syncthreads();
    int lane = tid & 63, wid = tid >> 6;
    for (int i = wid; i < 49; i += 4) {
        int p = pc * 49 + i;
        bf16x8 rv = *(const bf16x8*)(att1B + ((size_t)(b * PP + p)) * 512 + lane * 8);
        float s = 0.f;
        #pragma unroll
        for (int j = 0; j < 8; ++j) {
            float v = bf2f((ushort)rv[j]) + a2[lane * 8 + j];
            s += (v > 0.f ? v : 0.f) * wf[lane * 8 + j];
        }
        #pragma unroll
        for (int off = 32; off; off >>= 1) s += __shfl_down(s, off);
        if (lane == 0) es[b * 256 + p] = s;
    }
}

// P2b: softmax + awe (fp8 enc) + gate + pack; grid (8, 64)
__global__ __launch_bounds__(256) void k_awe8(const uint* __restrict__ enc8,
        const float* __restrict__ es, const float* __restrict__ gate,
        const int* __restrict__ lens, int t,
        uint* __restrict__ aweB, float* __restrict__ alpha_out) {
    __shared__ float al[224], red[256], ps[4][64][4];
    int b = blockIdx.y, ec = blockIdx.x, tid = threadIdx.x;
    float v = (tid < PP) ? es[b * 256 + tid] : -3.4e38f;
    red[tid] = v; __syncthreads();
    for (int s = 128; s; s >>= 1) { if (tid < s) red[tid] = fmaxf(red[tid], red[tid + s]); __syncthreads(); }
    float mx = red[0]; __syncthreads();
    float ev = (tid < PP) ? __expf(v - mx) : 0.f;
    red[tid] = ev; __syncthreads();
    for (int s = 128; s; s >>= 1) { if (tid < s) red[tid] += red[tid + s]; __syncthreads(); }
    float inv = 1.f / red[0];
    if (tid < PP) {
        float a = ev * inv;
        al[tid] = a;
        if (ec == 0) {
            bool m = t < (lens[b] - 1);
            alpha_out[((size_t)b * TT + t) * PP + tid] = m ? a : 0.f;
        }
    }
    __syncthreads();
    int w = tid >> 6, lane = tid & 63;
    int quad = ec * 64 + lane;                       // 0..511, covers 4 elems each
    const uint* pp = enc8 + (size_t)b * PP * 512 + quad;
    float s0 = 0.f, s1 = 0.f, s2 = 0.f, s3 = 0.f;
    #pragma unroll 7
    for (int p = w; p < PP; p += 4) {
        uint vv = pp[(size_t)p * 512];
        float d[4]; dec8x4(vv, d);
        float a = al[p];
        s0 += a * d[0]; s1 += a * d[1]; s2 += a * d[2]; s3 += a * d[3];
    }
    ps[w][lane][0] = s0; ps[w][lane][1] = s1; ps[w][lane][2] = s2; ps[w][lane][3] = s3;
    __syncthreads();
    if (tid < 64) {
        float t0 = ps[0][tid][0] + ps[1][tid][0] + ps[2][tid][0] + ps[3][tid][0];
        float t1 = ps[0][tid][1] + ps[1][tid][1] + ps[2][tid][1] + ps[3][tid][1];
        float t2 = ps[0][tid][2] + ps[1][tid][2] + ps[2][tid][2] + ps[3][tid][2];
        float t3 = ps[0][tid][3] + ps[1][tid][3] + ps[2][tid][3] + ps[3][tid][3];
        int q2 = ec * 64 + tid;
        int e = q2 * 4;
        float g0 = t0 * gate[b * 2048 + e + 0];
        float g1 = t1 * gate[b * 2048 + e + 1];
        float g2 = t2 * gate[b * 2048 + e + 2];
        float g3 = t3 * gate[b * 2048 + e + 3];
        aweB[b * 1024 + q2 * 2]     = (uint)f2bf(g0) | ((uint)f2bf(g1) << 16);
        aweB[b * 1024 + q2 * 2 + 1] = (uint)f2bf(g2) | ((uint)f2bf(g3) << 16);
    }
}

// P3: pawe[kc] = aweB slice @ W_ih slice; grid 128
__global__ __launch_bounds__(256) void k_p3(const uint* __restrict__ aweB,
        const ushort* __restrict__ WihT, float* __restrict__ pawe) {
    __shared__ alignas(16) ushort As[64 * 64];
    __shared__ alignas(16) ushort Bs[64 * 64];
    const int tid = threadIdx.x, lane = tid & 63, wid = tid >> 6;
    const int n0 = (blockIdx.x & 31) * 64, kc = blockIdx.x >> 5;
    const ushort* aweU = (const ushort*)aweB;
    f32x4 acc[4] = {};
    for (int k0 = 0; k0 < 512; k0 += 64) {
        #pragma unroll
        for (int p = 0; p < 2; ++p) {
            int c8 = p * 256 + tid;
            int r = c8 >> 3, cc = c8 & 7;
            float4 v = *(const float4*)(aweU + r * 2048 + kc * 512 + k0 + cc * 8);
            *(float4*)(As + r * 64 + ((cc ^ (r & 7)) * 8)) = v;
            float4 w = *(const float4*)(WihT + (size_t)(n0 + r) * KIH + 512 + kc * 512 + k0 + cc * 8);
            *(float4*)(Bs + r * 64 + ((cc ^ (r & 7)) * 8)) = w;
        }
        __syncthreads();
        #pragma unroll
        for (int kk = 0; kk < 2; ++kk) {
            int ci = kk * 4 + (lane >> 4);
            int colL = wid * 16 + (lane & 15);
            bf16x8 bfrag = *(const bf16x8*)(Bs + colL * 64 + ((ci ^ (colL & 7)) * 8));
            #pragma unroll
            for (int m = 0; m < 4; ++m) {
                int row = m * 16 + (lane & 15);
                bf16x8 afrag = *(const bf16x8*)(As + row * 64 + ((ci ^ (row & 7)) * 8));
                acc[m] = __builtin_amdgcn_mfma_f32_16x16x32_bf16(afrag, bfrag, acc[m], 0, 0, 0);
            }
        }
        __syncthreads();
    }
    int col = n0 + wid * 16 + (lane & 15);
    #pragma unroll
    for (int m = 0; m < 4; ++m) {
        int rb = m * 16 + (lane >> 4) * 4;
        #pragma unroll
        for (int r = 0; r < 4; ++r)
            pawe[((size_t)kc * BB + rb + r) * 2048 + col] = acc[m][r];
    }
}

// P4: LSTM pointwise + memory attention + carry; grid 64
__global__ __launch_bounds__(256) void k_p4(const float* __restrict__ hhp,
        const float* __restrict__ pawe, const float* __restrict__ xpre,
        const float* __restrict__ bih, const float* __restrict__ bhh,
        const int* __restrict__ lens, int t, const float* __restrict__ memB,
        float* __restrict__ h, float* __restrict__ c,
        ushort* __restrict__ hB, ushort* __restrict__ histB) {
    __shared__ float hss[512], simss[128], reds[256], pss[128];
    const int b = blockIdx.x, tid = threadIdx.x;
    const int lane = tid & 63, wid = tid >> 6;
    bool msk = t < (lens[b] - 1);
    for (int j = tid; j < 512; j += 256) {
        float g[4];
        #pragma unroll
        for (int q = 0; q < 4; ++q) {
            int col = q * 512 + j;
            float s = bih[col] + bhh[col]
                    + hhp[(size_t)b * 2048 + col]
                    + xpre[((size_t)t * BB + b) * 2048 + col];
            #pragma unroll
            for (int kc = 0; kc < 4; ++kc) s += pawe[((size_t)kc * BB + b) * 2048 + col];
            g[q] = s;
        }
        float gi = sigm(g[0]), gf = sigm(g[1]), gg = tanh_f(g[2]), go = sigm(g[3]);
        float cold = c[b * 512 + j];
        float cn = gf * cold + gi * gg;
        c[b * 512 + j] = msk ? cn : cold;
        hss[j] = go * tanh_f(cn);
    }
    __syncthreads();
    for (int m = wid * 32; m < wid * 32 + 32; ++m) {
        const float* r = memB + (size_t)m * 512 + lane * 8;
        float4 r0 = *(const float4*)(r);
        float4 r1 = *(const float4*)(r + 4);
        float4 h0 = *(const float4*)(&hss[lane * 8]);
        float4 h1 = *(const float4*)(&hss[lane * 8 + 4]);
        float s = r0.x * h0.x + r0.y * h0.y + r0.z * h0.z + r0.w * h0.w
                + r1.x * h1.x + r1.y * h1.y + r1.z * h1.z + r1.w * h1.w;
        #pragma unroll
        for (int off = 32; off; off >>= 1) s += __shfl_down(s, off);
        if (lane == 0) simss[m] = s;
    }
    __syncthreads();
    float v = (tid < 128) ? simss[tid] : -3.4e38f;
    reds[tid] = v; __syncthreads();
    for (int s = 128; s; s >>= 1) { if (tid < s) reds[tid] = fmaxf(reds[tid], reds[tid + s]); __syncthreads(); }
    float mx = reds[0]; __syncthreads();
    float ev = (tid < 128) ? __expf(v - mx) : 0.f;
    reds[tid] = ev; __syncthreads();
    for (int s = 128; s; s >>= 1) { if (tid < s) reds[tid] += reds[tid + s]; __syncthreads(); }
    if (tid < 128) pss[tid] = ev / reds[0];
    __syncthreads();
    for (int d = tid; d < 512; d += 256) {
        float s = 0.f;
        #pragma unroll 4
        for (int m = 0; m < 128; ++m) s += pss[m] * memB[(size_t)m * 512 + d];
        float hn = hss[d] + s;
        histB[((size_t)t * BB + b) * 512 + d] = f2bf(hn);
        float hold = h[b * 512 + d];
        float hv = msk ? hn : hold;
        h[b * 512 + d] = hv;
        hB[b * 512 + d] = f2bf(hv);
    }
}

// batched preds: hist(21*64 x 512) @ WfcT^T + bfc, masked. grid (40, 21)
__global__ __launch_bounds__(256) void k_preds_batch(const ushort* __restrict__ histB,
        const ushort* __restrict__ WfcT, const float* __restrict__ bfc,
        const int* __restrict__ lens, float* __restrict__ out) {
    __shared__ alignas(16) ushort As[64 * 64];
    __shared__ alignas(16) ushort Bs[256 * 64];
    const int n0 = blockIdx.x * 256;
    const int t = blockIdx.y;
    const ushort* A = histB + (size_t)t * BB * 512;
    const int tid = threadIdx.x, wid = tid >> 6, lane = tid & 63;
    f32x4 acc[4][4] = {};
    for (int k0 = 0; k0 < 512; k0 += 64) {
        #pragma unroll
        for (int p = 0; p < 2; ++p) {
            int c = p * 256 + tid;
            int r = c >> 3, cc = c & 7;
            float4 v = *(const float4*)(A + r * 512 + k0 + cc * 8);
            *(float4*)(As + r * 64 + ((cc ^ (r & 7)) * 8)) = v;
        }
        #pragma unroll
        for (int p = 0; p < 8; ++p) {
            int c = p * 256 + tid;
            int r = c >> 3, cc = c & 7;
            float4 v = *(const float4*)(WfcT + (size_t)(n0 + r) * 512 + k0 + cc * 8);
            *(float4*)(Bs + r * 64 + ((cc ^ (r & 7)) * 8)) = v;
        }
        __syncthreads();
        #pragma unroll
        for (int kk = 0; kk < 2; ++kk) {
            int ci = kk * 4 + (lane >> 4);
            bf16x8 afrag[4], bfrag[4];
            #pragma unroll
            for (int m = 0; m < 4; ++m) {
                int row = m * 16 + (lane & 15);
                afrag[m] = *(const bf16x8*)(As + row * 64 + ((ci ^ (row & 7)) * 8));
            }
            #pragma unroll
            for (int n = 0; n < 4; ++n) {
                int col = wid * 64 + n * 16 + (lane & 15);
                bfrag[n] = *(const bf16x8*)(Bs + col * 64 + ((ci ^ (col & 7)) * 8));
            }
            #pragma unroll
            for (int m = 0; m < 4; ++m)
                #pragma unroll
                for (int n = 0; n < 4; ++n)
                    acc[m][n] = __builtin_amdgcn_mfma_f32_16x16x32_bf16(afrag[m], bfrag[n], acc[m][n], 0, 0, 0);
        }
        __syncthreads();
    }
    #pragma unroll
    for (int m = 0; m < 4; ++m) {
        int rb = m * 16 + (lane >> 4) * 4;
        #pragma unroll
        for (int n = 0; n < 4; ++n) {
            int col = n0 + wid * 64 + n * 16 + (lane & 15);
            if (col < VV) {
                float bv = bfc[col];
                #pragma unroll
                for (int r = 0; r < 4; ++r) {
                    int b = rb + r;
                    bool msk = t < (lens[b] - 1);
                    out[((size_t)b * TT + t) * VV + col] = msk ? (acc[m][n][r] + bv) : 0.f;
                }
            }
        }
    }
}

// ---------------- launch ----------------

extern "C" void kernel_launch(void* const* d_in, const int* in_sizes, int n_in,
                              void* d_out, int out_size, void* d_ws, size_t ws_size,
                              hipStream_t stream) {
    const float* enc     = (const float*)d_in[0];
    const int*   caps    = (const int*)d_in[1];
    const int*   lens    = (const int*)d_in[2];
    const float* emb     = (const float*)d_in[3];
    const float* W_enc   = (const float*)d_in[4];
    const float* b_enc   = (const float*)d_in[5];
    const float* W_dec   = (const float*)d_in[6];
    const float* b_dec   = (const float*)d_in[7];
    const float* W_full  = (const float*)d_in[8];
    const float* W_inith = (const float*)d_in[10];
    const float* b_inith = (const float*)d_in[11];
    const float* W_initc = (const float*)d_in[12];
    const float* b_initc = (const float*)d_in[13];
    const float* W_beta  = (const float*)d_in[14];
    const float* b_beta  = (const float*)d_in[15];
    const float* W_ih    = (const float*)d_in[16];
    const float* b_ih    = (const float*)d_in[17];
    const float* W_hh    = (const float*)d_in[18];
    const float* b_hh    = (const float*)d_in[19];
    const float* memB    = (const float*)d_in[20];
    const float* W_fc    = (const float*)d_in[21];
    const float* b_fc    = (const float*)d_in[22];

    float* out = (float*)d_out;
    float* preds_out  = out;
    float* declen_out = out + (size_t)BB * TT * VV;
    float* alpha_out  = declen_out + BB;

    float* ws    = (float*)d_ws;
    ushort* att1B = (ushort*)ws;  ws += (size_t)12544 * 512 / 2;
    float* h     = ws;  ws += BB * DECD;
    float* c     = ws;  ws += BB * DECD;
    float* att2  = ws;  ws += BB * 512;
    float* gate  = ws;  ws += BB * 2048;
    float* hhp   = ws;  ws += BB * 2048;
    float* es    = ws;  ws += BB * 256;
    float* pawe  = ws;  ws += (size_t)4 * BB * 2048;
    float* xpre  = ws;  ws += (size_t)TT * BB * 2048;
    ushort* hB   = (ushort*)ws;  ws += BB * DECD / 2;
    uint*  aweB  = (uint*)ws;    ws += BB * 1024;
    ushort* histB = (ushort*)ws; ws += (size_t)TT * BB * DECD / 2;
    ushort* encB  = (ushort*)ws; ws += (size_t)12544 * 2048 / 2;
    ushort* WencT = (ushort*)ws; ws += (size_t)512 * 2048 / 2;
    ushort* WfcT  = (ushort*)ws; ws += (size_t)10240 * 512 / 2;
    ushort* WcatT = (ushort*)ws; ws += (size_t)4608 * 512 / 2;
    ushort* WihT  = (ushort*)ws; ws += (size_t)2048 * KIH / 2;
    // aliases (dead before their regions are (re)written)
    float* mean  = (float*)att1B;   // dead before k_att1n
    float* ipart = xpre;            // dead before k_xpre
    uint*  enc8  = (uint*)encB;     // encB (bf16) dead after k_att1n; fp8 copy written over it

    k_cvt<<<(12544 * 2048 / 4 + 255) / 256, 256, 0, stream>>>(enc, encB, 12544 * 2048 / 4);
    k_mean16<<<256, 256, 0, stream>>>(encB, mean);
    k_ipart<<<dim3(8, 4, 2), 256, 0, stream>>>(mean, W_inith, W_initc, ipart);
    k_ifin<<<256, 256, 0, stream>>>(ipart, b_inith, b_initc, h, c, hB);
    k_declen<<<1, 64, 0, stream>>>(lens, declen_out);
    k_tcvt_all<<<3392, 256, 0, stream>>>(W_enc, W_dec, W_beta, W_hh, W_ih, W_fc,
                                         WencT, WcatT, WcatT + (size_t)512 * 512,
                                         WcatT + (size_t)2560 * 512, WihT, WfcT);
    k_att1n<<<dim3(2, 196), 256, 0, stream>>>(encB, WencT, b_enc, att1B);
    k_cvt8<<<(12544 * 2048 / 4 + 255) / 256, 256, 0, stream>>>(enc, enc8, 12544 * 2048 / 4);
    k_xpre<<<dim3(8, TT), 256, 0, stream>>>(emb, caps, WihT, xpre);

    for (int t = 0; t < TT; ++t) {
        k_p1<<<72, 256, 0, stream>>>(hB, WcatT, b_dec, b_beta, att2, gate, hhp);
        k_escore_p<<<dim3(4, 64), 256, 0, stream>>>(att1B, att2, W_full, es);
        k_awe8<<<dim3(8, 64), 256, 0, stream>>>(enc8, es, gate, lens, t, aweB, alpha_out);
        k_p3<<<128, 256, 0, stream>>>(aweB, WihT, pawe);
        k_p4<<<64, 256, 0, stream>>>(hhp, pawe, xpre, b_ih, b_hh, lens, t, memB, h, c, hB, histB);
    }

    k_preds_batch<<<dim3(40, TT), 256, 0, stream>>>(histB, WfcT, b_fc, lens, preds_out);
}